// Round 1
// baseline (1102.776 us; speedup 1.0000x reference)
//
#include <hip/hip_runtime.h>
#include <math.h>

#define D_N 4096
#define D_CS 512
#define D_CZ 128
#define D_CH 64
#define D_H 16
#define D_PQ 4
#define D_PV 8
#define D_BQ 32
#define D_BK 128
#define D_NB 128
#define D_CZ4 32

#define PROJW 3840
#define OFFK 1024
#define OFFV 2048
#define OFFQP 3072
#define OFFKVP 3264
#define CATW 2048

// ---------------------------------------------------------------- Wcat build
__global__ __launch_bounds__(256) void k_wcat(const float* __restrict__ Wq, const float* __restrict__ Wk,
    const float* __restrict__ Wv, const float* __restrict__ Wqp, const float* __restrict__ Wkvp,
    float* __restrict__ wcat)
{
    int r = blockIdx.y;
    int c = blockIdx.x * 256 + threadIdx.x;
    float v;
    if (c < 1024)       v = Wq[r * 1024 + c];
    else if (c < 2048)  v = Wk[r * 1024 + (c - 1024)];
    else if (c < 3072)  v = Wv[r * 1024 + (c - 2048)];
    else if (c < 3264)  v = Wqp[r * 192 + (c - 3072)];
    else                v = Wkvp[r * 576 + (c - 3264)];
    wcat[(size_t)r * PROJW + c] = v;
}

// ---------------------------------------------------------------- LN of s
__global__ __launch_bounds__(64) void k_ln_s(const float* __restrict__ s, const float* __restrict__ g,
    const float* __restrict__ b, float* __restrict__ out)
{
    int row = blockIdx.x;
    int lane = threadIdx.x;
    const float4* p = (const float4*)(s + (size_t)row * D_CS);
    float4 v0 = p[lane];
    float4 v1 = p[lane + 64];
    float sum = v0.x + v0.y + v0.z + v0.w + v1.x + v1.y + v1.z + v1.w;
    float sq  = v0.x*v0.x + v0.y*v0.y + v0.z*v0.z + v0.w*v0.w
              + v1.x*v1.x + v1.y*v1.y + v1.z*v1.z + v1.w*v1.w;
    #pragma unroll
    for (int off = 1; off < 64; off <<= 1) {
        sum += __shfl_xor(sum, off);
        sq  += __shfl_xor(sq, off);
    }
    float m = sum * (1.0f / D_CS);
    float var = sq * (1.0f / D_CS) - m * m;
    float rs = rsqrtf(var + 1e-5f);
    float4* o = (float4*)(out + (size_t)row * D_CS);
    int c = lane * 4;
    float4 r0, r1;
    r0.x = (v0.x - m) * rs * g[c+0] + b[c+0];
    r0.y = (v0.y - m) * rs * g[c+1] + b[c+1];
    r0.z = (v0.z - m) * rs * g[c+2] + b[c+2];
    r0.w = (v0.w - m) * rs * g[c+3] + b[c+3];
    int c2 = 256 + lane * 4;
    r1.x = (v1.x - m) * rs * g[c2+0] + b[c2+0];
    r1.y = (v1.y - m) * rs * g[c2+1] + b[c2+1];
    r1.z = (v1.z - m) * rs * g[c2+2] + b[c2+2];
    r1.w = (v1.w - m) * rs * g[c2+3] + b[c2+3];
    o[lane] = r0;
    o[lane + 64] = r1;
}

// ---------------------------------------------------------------- 128x128 f32 GEMM (C = A[MxK] * B[KxN]), K%8==0, N%128==0, M%128==0
__global__ __launch_bounds__(256) void gemm128(const float* __restrict__ A, const float* __restrict__ B,
    float* __restrict__ C, int K, int Nc)
{
    __shared__ float As[8][128];
    __shared__ float Bs[8][128];
    const int tid = threadIdx.x;
    const int tx = tid & 15, ty = tid >> 4;
    const int row0 = blockIdx.y * 128, col0 = blockIdx.x * 128;
    const int r_a = tid >> 1, c4_a = (tid & 1) * 4;
    const int r_b = tid >> 5, c4_b = (tid & 31) * 4;
    float acc[8][8];
    #pragma unroll
    for (int i = 0; i < 8; ++i)
        #pragma unroll
        for (int j = 0; j < 8; ++j) acc[i][j] = 0.f;
    const float* Ap = A + (size_t)(row0 + r_a) * K + c4_a;
    const float* Bp = B + (size_t)r_b * Nc + col0 + c4_b;
    for (int k0 = 0; k0 < K; k0 += 8) {
        float4 av = *(const float4*)(Ap + k0);
        float4 bv = *(const float4*)(Bp + (size_t)k0 * Nc);
        __syncthreads();
        As[c4_a + 0][r_a] = av.x;
        As[c4_a + 1][r_a] = av.y;
        As[c4_a + 2][r_a] = av.z;
        As[c4_a + 3][r_a] = av.w;
        *(float4*)(&Bs[r_b][c4_b]) = bv;
        __syncthreads();
        #pragma unroll
        for (int kk = 0; kk < 8; ++kk) {
            float a[8], b[8];
            *(float4*)(&a[0]) = *(const float4*)(&As[kk][ty * 4]);
            *(float4*)(&a[4]) = *(const float4*)(&As[kk][64 + ty * 4]);
            *(float4*)(&b[0]) = *(const float4*)(&Bs[kk][tx * 4]);
            *(float4*)(&b[4]) = *(const float4*)(&Bs[kk][64 + tx * 4]);
            #pragma unroll
            for (int i = 0; i < 8; ++i)
                #pragma unroll
                for (int j = 0; j < 8; ++j)
                    acc[i][j] += a[i] * b[j];
        }
    }
    #pragma unroll
    for (int i = 0; i < 8; ++i) {
        int row = row0 + (i < 4 ? ty * 4 + i : 64 + ty * 4 + (i - 4));
        float* cp = C + (size_t)row * Nc + col0;
        float4 v0 = {acc[i][0], acc[i][1], acc[i][2], acc[i][3]};
        float4 v1 = {acc[i][4], acc[i][5], acc[i][6], acc[i][7]};
        *(float4*)(cp + tx * 4) = v0;
        *(float4*)(cp + 64 + tx * 4) = v1;
    }
}

// ---------------------------------------------------------------- 64x64 f32 GEMM, K%16==0, N%64==0, M%64==0
__global__ __launch_bounds__(256) void gemm64(const float* __restrict__ A, const float* __restrict__ B,
    float* __restrict__ C, int K, int Nc)
{
    __shared__ float As[16][64];
    __shared__ float Bs[16][64];
    const int tid = threadIdx.x;
    const int tx = tid & 15, ty = tid >> 4;
    const int row0 = blockIdx.y * 64, col0 = blockIdx.x * 64;
    const int r_a = tid >> 2, c4_a = (tid & 3) * 4;
    const int r_b = tid >> 4, c4_b = (tid & 15) * 4;
    float acc[4][4];
    #pragma unroll
    for (int i = 0; i < 4; ++i)
        #pragma unroll
        for (int j = 0; j < 4; ++j) acc[i][j] = 0.f;
    const float* Ap = A + (size_t)(row0 + r_a) * K + c4_a;
    const float* Bp = B + (size_t)r_b * Nc + col0 + c4_b;
    for (int k0 = 0; k0 < K; k0 += 16) {
        float4 av = *(const float4*)(Ap + k0);
        float4 bv = *(const float4*)(Bp + (size_t)k0 * Nc);
        __syncthreads();
        As[c4_a + 0][r_a] = av.x;
        As[c4_a + 1][r_a] = av.y;
        As[c4_a + 2][r_a] = av.z;
        As[c4_a + 3][r_a] = av.w;
        *(float4*)(&Bs[r_b][c4_b]) = bv;
        __syncthreads();
        #pragma unroll
        for (int kk = 0; kk < 16; ++kk) {
            float4 a = *(const float4*)(&As[kk][ty * 4]);
            float4 b = *(const float4*)(&Bs[kk][tx * 4]);
            acc[0][0] += a.x * b.x; acc[0][1] += a.x * b.y; acc[0][2] += a.x * b.z; acc[0][3] += a.x * b.w;
            acc[1][0] += a.y * b.x; acc[1][1] += a.y * b.y; acc[1][2] += a.y * b.z; acc[1][3] += a.y * b.w;
            acc[2][0] += a.z * b.x; acc[2][1] += a.z * b.y; acc[2][2] += a.z * b.z; acc[2][3] += a.z * b.w;
            acc[3][0] += a.w * b.x; acc[3][1] += a.w * b.y; acc[3][2] += a.w * b.z; acc[3][3] += a.w * b.w;
        }
    }
    #pragma unroll
    for (int i = 0; i < 4; ++i) {
        int row = row0 + ty * 4 + i;
        float4 v = {acc[i][0], acc[i][1], acc[i][2], acc[i][3]};
        *(float4*)(C + (size_t)row * Nc + col0 + tx * 4) = v;
    }
}

// ---------------------------------------------------------------- rotate+translate projected points (in place)
__global__ __launch_bounds__(256) void k_rot(float* __restrict__ proj, const float* __restrict__ rots,
    const float* __restrict__ trans)
{
    int row = blockIdx.x;
    int tid = threadIdx.x;
    const float* R = rots + (size_t)row * 9;
    const float* t = trans + (size_t)row * 3;
    float* base;
    if (tid < 64) base = proj + (size_t)row * PROJW + OFFQP + tid * 3;
    else          base = proj + (size_t)row * PROJW + OFFKVP + (tid - 64) * 3;
    float x = base[0], y = base[1], z = base[2];
    base[0] = R[0] * x + R[1] * y + R[2] * z + t[0];
    base[1] = R[3] * x + R[4] * y + R[5] * z + t[1];
    base[2] = R[6] * x + R[7] * y + R[8] * z + t[2];
}

// ---------------------------------------------------------------- z LayerNorm + bias/pair_z projection
// one workgroup per (pair, half): 64 z-rows of 128, outputs bias[64][16] and pz[64][32]
__global__ __launch_bounds__(256) void k_zbias(const float* __restrict__ z, const float* __restrict__ gz,
    const float* __restrict__ bz, const float* __restrict__ Wb, const float* __restrict__ Wdz,
    float* __restrict__ bias, float* __restrict__ pz)
{
    __shared__ float zs[64][132];
    __shared__ float WT[48][132];
    int bid = blockIdx.x;
    int pair = bid >> 1;
    int half = bid & 1;
    int tid = threadIdx.x;
    const float* zp = z + ((size_t)pair * D_BK + (size_t)half * 64) * D_CZ;
    #pragma unroll
    for (int i = 0; i < 8; ++i) {
        int v = tid + i * 256;
        int r = v >> 5;
        int c4 = (v & 31) * 4;
        float4 val = *(const float4*)(zp + (size_t)r * D_CZ + c4);
        *(float4*)(&zs[r][c4]) = val;
    }
    for (int i = tid; i < 2048; i += 256) {
        WT[i & 15][i >> 4] = Wb[i];
    }
    for (int i = tid; i < 4096; i += 256) {
        WT[16 + (i & 31)][i >> 5] = Wdz[i];
    }
    __syncthreads();
    {   // LayerNorm: 4 threads per row
        int r = tid >> 2, l4 = tid & 3;
        float sum = 0.f, sq = 0.f;
        #pragma unroll
        for (int i = 0; i < 8; ++i) {
            float4 v = *(const float4*)(&zs[r][l4 * 32 + i * 4]);
            sum += v.x + v.y + v.z + v.w;
            sq  += v.x*v.x + v.y*v.y + v.z*v.z + v.w*v.w;
        }
        sum += __shfl_xor(sum, 1); sq += __shfl_xor(sq, 1);
        sum += __shfl_xor(sum, 2); sq += __shfl_xor(sq, 2);
        float m = sum * (1.0f / D_CZ);
        float var = sq * (1.0f / D_CZ) - m * m;
        float rs = rsqrtf(var + 1e-5f);
        #pragma unroll
        for (int i = 0; i < 8; ++i) {
            int c = l4 * 32 + i * 4;
            float4 v = *(const float4*)(&zs[r][c]);
            float4 gv = *(const float4*)(gz + c);
            float4 bv = *(const float4*)(bz + c);
            v.x = (v.x - m) * rs * gv.x + bv.x;
            v.y = (v.y - m) * rs * gv.y + bv.y;
            v.z = (v.z - m) * rs * gv.z + bv.z;
            v.w = (v.w - m) * rs * gv.w + bv.w;
            *(float4*)(&zs[r][c]) = v;
        }
    }
    __syncthreads();
    {   // matvec: thread tile 4 rows x 3 cols over 64x48 outputs
        int rg = tid & 15;
        int jg = tid >> 4;
        int j0 = jg * 3;
        float acc[4][3];
        #pragma unroll
        for (int i = 0; i < 4; ++i) { acc[i][0] = 0.f; acc[i][1] = 0.f; acc[i][2] = 0.f; }
        for (int c4 = 0; c4 < D_CZ; c4 += 4) {
            float4 w0 = *(const float4*)(&WT[j0 + 0][c4]);
            float4 w1 = *(const float4*)(&WT[j0 + 1][c4]);
            float4 w2 = *(const float4*)(&WT[j0 + 2][c4]);
            #pragma unroll
            for (int i = 0; i < 4; ++i) {
                float4 zv = *(const float4*)(&zs[rg + 16 * i][c4]);
                acc[i][0] += zv.x*w0.x + zv.y*w0.y + zv.z*w0.z + zv.w*w0.w;
                acc[i][1] += zv.x*w1.x + zv.y*w1.y + zv.z*w1.z + zv.w*w1.w;
                acc[i][2] += zv.x*w2.x + zv.y*w2.y + zv.z*w2.z + zv.w*w2.w;
            }
        }
        #pragma unroll
        for (int i = 0; i < 4; ++i) {
            int k = half * 64 + rg + 16 * i;
            size_t rb = (size_t)pair * D_BK + k;
            #pragma unroll
            for (int jj = 0; jj < 3; ++jj) {
                int j = j0 + jj;
                if (j < 16) bias[rb * 16 + j] = acc[i][jj];
                else        pz[rb * 32 + (j - 16)] = acc[i][jj];
            }
        }
    }
}

// ---------------------------------------------------------------- attention: one workgroup per query row
__global__ __launch_bounds__(256) void k_attn(const float* __restrict__ proj, const float* __restrict__ bias,
    const float* __restrict__ pz, const float* __restrict__ rots, const float* __restrict__ trans,
    const float* __restrict__ smask, const int* __restrict__ kidx, const float* __restrict__ hwraw,
    float* __restrict__ cat)
{
    __shared__ float qv[D_H * D_CH];        // 1024 f
    __shared__ float qp[D_H * D_PQ * 3];    // 192 f
    __shared__ float kpz[D_BK][D_CZ4 + 1];  // 128 x 33
    __shared__ float att[D_H][D_BK + 1];    // 16 x 129
    __shared__ int   rows_s[D_BK];
    __shared__ float km_s[D_BK];
    __shared__ float hws[D_H];
    int rowq = blockIdx.x;
    int nblk = rowq >> 5;
    int tid = threadIdx.x;

    {
        float4 v = ((const float4*)(proj + (size_t)rowq * PROJW))[tid];
        ((float4*)qv)[tid] = v;
    }
    if (tid < 192) qp[tid] = proj[(size_t)rowq * PROJW + OFFQP + tid];
    if (tid < D_BK) {
        int ki = kidx[nblk * D_BK + tid];
        int valid = (ki >= 0 && ki < D_N) ? 1 : 0;
        int rr = ki < 0 ? 0 : (ki > D_N - 1 ? D_N - 1 : ki);
        rows_s[tid] = rr;
        km_s[tid] = valid ? smask[rr] : 0.0f;
    }
    if (tid < D_H) hws[tid] = log1pf(expf(hwraw[tid])) * 0.13608276348795434f; // softplus * sqrt(1/54)
    {
        const float4* src = (const float4*)(pz + (size_t)rowq * D_BK * D_CZ4);
        #pragma unroll
        for (int i = 0; i < 4; ++i) {
            int v = tid + i * 256;
            int k = v >> 3;
            int c4 = (v & 7) * 4;
            float4 val = src[v];
            kpz[k][c4 + 0] = val.x; kpz[k][c4 + 1] = val.y;
            kpz[k][c4 + 2] = val.z; kpz[k][c4 + 3] = val.w;
        }
    }
    __syncthreads();

    int h = tid >> 4;
    int k16 = tid & 15;
    float qmv = smask[rowq];
    float hw = hws[h];
    const float4* q4 = (const float4*)(qv + h * D_CH);
    for (int it = 0; it < 8; ++it) {
        int k = k16 + it * 16;
        int row = rows_s[k];
        const float* base = proj + (size_t)row * PROJW;
        const float4* k4 = (const float4*)(base + OFFK + h * D_CH);
        float dot = 0.f;
        #pragma unroll
        for (int c = 0; c < 16; ++c) {
            float4 a = q4[c], bb = k4[c];
            dot += a.x*bb.x + a.y*bb.y + a.z*bb.z + a.w*bb.w;
        }
        const float* kp = base + OFFKVP + h * 36;
        float d2 = 0.f;
        #pragma unroll
        for (int p = 0; p < 4; ++p) {
            float dx = qp[(h * 4 + p) * 3 + 0] - kp[p * 3 + 0];
            float dy = qp[(h * 4 + p) * 3 + 1] - kp[p * 3 + 1];
            float dz = qp[(h * 4 + p) * 3 + 2] - kp[p * 3 + 2];
            d2 += dx*dx + dy*dy + dz*dz;
        }
        float bv = bias[((size_t)rowq * D_BK + k) * D_H + h];
        float am = 100000.0f * (qmv * km_s[k] - 1.0f);
        att[h][k] = dot * 0.07216878364870323f + 0.5773502691896258f * bv - 0.5f * hw * d2 + am;
    }
    __syncthreads();
    {   // softmax over k per h: 16 threads per h, 8 consecutive k each
        int kb = k16 * 8;
        float l[8];
        #pragma unroll
        for (int i = 0; i < 8; ++i) l[i] = att[h][kb + i];
        float mx = l[0];
        #pragma unroll
        for (int i = 1; i < 8; ++i) mx = fmaxf(mx, l[i]);
        #pragma unroll
        for (int off = 1; off < 16; off <<= 1) mx = fmaxf(mx, __shfl_xor(mx, off));
        float se = 0.f;
        #pragma unroll
        for (int i = 0; i < 8; ++i) { l[i] = expf(l[i] - mx); se += l[i]; }
        #pragma unroll
        for (int off = 1; off < 16; off <<= 1) se += __shfl_xor(se, off);
        float inv = 1.0f / se;
        #pragma unroll
        for (int i = 0; i < 8; ++i) att[h][kb + i] = l[i] * inv;
    }
    __syncthreads();
    float* catp = cat + (size_t)rowq * CATW;
    {   // o: thread (h, k16) -> cols k16*4..+4
        float4 acc = {0.f, 0.f, 0.f, 0.f};
        for (int k = 0; k < D_BK; ++k) {
            float a = att[h][k];
            float4 v = *(const float4*)(proj + (size_t)rows_s[k] * PROJW + OFFV + h * D_CH + k16 * 4);
            acc.x += a * v.x; acc.y += a * v.y; acc.z += a * v.z; acc.w += a * v.w;
        }
        *(float4*)(catp + h * D_CH + k16 * 4) = acc;
    }
    for (int oi = tid; oi < D_H * D_CZ4; oi += 256) {   // o_pair
        int hh = oi >> 5, c = oi & 31;
        float acc = 0.f;
        for (int k = 0; k < D_BK; ++k) acc += att[hh][k] * kpz[k][c];
        catp[1536 + oi] = acc;
    }
    if (tid < D_H * D_PV) {   // o_pt + norm
        int hh = tid >> 3, p = tid & 7;
        float ax = 0.f, ay = 0.f, az = 0.f;
        for (int k = 0; k < D_BK; ++k) {
            float a = att[hh][k];
            const float* vp = proj + (size_t)rows_s[k] * PROJW + OFFKVP + (hh * 12 + 4 + p) * 3;
            ax += a * vp[0]; ay += a * vp[1]; az += a * vp[2];
        }
        const float* R = rots + (size_t)rowq * 9;
        const float* t = trans + (size_t)rowq * 3;
        float x = ax - t[0], y = ay - t[1], z2 = az - t[2];
        float ox = R[0] * x + R[3] * y + R[6] * z2;   // R^T * v
        float oy = R[1] * x + R[4] * y + R[7] * z2;
        float oz = R[2] * x + R[5] * y + R[8] * z2;
        catp[1024 + tid * 3 + 0] = ox;
        catp[1024 + tid * 3 + 1] = oy;
        catp[1024 + tid * 3 + 2] = oz;
        catp[1408 + tid] = sqrtf(ox * ox + oy * oy + oz * oz + 1e-8f);
    }
}

// ---------------------------------------------------------------- launcher
extern "C" void kernel_launch(void* const* d_in, const int* in_sizes, int n_in,
                              void* d_out, int out_size, void* d_ws, size_t ws_size,
                              hipStream_t stream)
{
    (void)in_sizes; (void)n_in; (void)out_size;
    const float* s     = (const float*)d_in[0];
    const float* z     = (const float*)d_in[1];
    const float* trans = (const float*)d_in[2];
    const float* rots  = (const float*)d_in[3];
    const float* smask = (const float*)d_in[4];
    const int*   kidx  = (const int*)d_in[5];
    const float* Wq    = (const float*)d_in[6];
    const float* Wk    = (const float*)d_in[7];
    const float* Wv    = (const float*)d_in[8];
    const float* Wqp   = (const float*)d_in[9];
    const float* Wkvp  = (const float*)d_in[10];
    const float* Wb    = (const float*)d_in[11];
    const float* Wdz   = (const float*)d_in[12];
    const float* hw    = (const float*)d_in[13];
    const float* Wout  = (const float*)d_in[14];
    const float* g_s   = (const float*)d_in[15];
    const float* b_s   = (const float*)d_in[16];
    const float* g_z   = (const float*)d_in[17];
    const float* b_z   = (const float*)d_in[18];

    float* ws   = (float*)d_ws;
    float* wcat = ws;                                     // 512*3840   = 1,966,080
    float* s_n  = wcat + (size_t)512 * 3840;              // 4096*512   = 2,097,152
    float* proj = s_n  + (size_t)4096 * 512;              // 4096*3840  = 15,728,640
    float* bias = proj + (size_t)4096 * 3840;             // 4096*128*16 = 8,388,608
    float* pz   = bias + (size_t)4096 * 128 * 16;         // 4096*128*32 = 16,777,216
    float* cat  = pz   + (size_t)4096 * 128 * 32;         // 4096*2048  = 8,388,608
    size_t need = ((size_t)1966080 + 2097152 + 15728640 + 8388608 + 16777216 + 8388608) * 4;
    if (ws_size < need) return;  // insufficient workspace: fail loudly via poison output
    float* out = (float*)d_out;

    k_wcat<<<dim3(15, 512), 256, 0, stream>>>(Wq, Wk, Wv, Wqp, Wkvp, wcat);
    k_ln_s<<<4096, 64, 0, stream>>>(s, g_s, b_s, s_n);
    gemm128<<<dim3(30, 32), 256, 0, stream>>>(s_n, wcat, proj, 512, 3840);
    k_rot<<<4096, 256, 0, stream>>>(proj, rots, trans);
    k_zbias<<<8192, 256, 0, stream>>>(z, g_z, b_z, Wb, Wdz, bias, pz);
    k_attn<<<4096, 256, 0, stream>>>(proj, bias, pz, rots, trans, smask, kidx, hw, cat);
    gemm64<<<dim3(8, 64), 256, 0, stream>>>(cat, Wout, out, 2048, 512);
}

// Round 2
// 390.773 us; speedup vs baseline: 2.8220x; 2.8220x over previous
//
#include <hip/hip_runtime.h>
#include <math.h>

#define D_N 4096
#define PROJW 3840
#define OFFK 1024
#define OFFV 2048
#define OFFQP 3072
#define OFFKVP 3264
#define CATW 2048

typedef __bf16 bf16_t;
typedef __bf16 bf16x8 __attribute__((ext_vector_type(8)));
typedef __bf16 bf16x4 __attribute__((ext_vector_type(4)));
typedef float f32x4 __attribute__((ext_vector_type(4)));

// ---------------------------------------------------------------- Wcat build (f32)
__global__ __launch_bounds__(256) void k_wcat(const float* __restrict__ Wq, const float* __restrict__ Wk,
    const float* __restrict__ Wv, const float* __restrict__ Wqp, const float* __restrict__ Wkvp,
    float* __restrict__ wcat)
{
    int r = blockIdx.y;
    int c = blockIdx.x * 256 + threadIdx.x;
    float v;
    if (c < 1024)       v = Wq[r * 1024 + c];
    else if (c < 2048)  v = Wk[r * 1024 + (c - 1024)];
    else if (c < 3072)  v = Wv[r * 1024 + (c - 2048)];
    else if (c < 3264)  v = Wqp[r * 192 + (c - 3072)];
    else                v = Wkvp[r * 576 + (c - 3264)];
    wcat[(size_t)r * PROJW + c] = v;
}

// ---------------------------------------------------------------- transpose + cvt: in f32 [R][C] -> out bf16 [C][R]
__global__ __launch_bounds__(256) void t_cvt(const float* __restrict__ in, bf16_t* __restrict__ out,
    int R, int C)
{
    __shared__ float T[64][65];
    int r0 = blockIdx.y * 64, c0 = blockIdx.x * 64;
    int tid = threadIdx.x;
    {
        int rr = tid >> 2;
        int cb = (tid & 3) * 16;
        const float* p = in + (size_t)(r0 + rr) * C + c0 + cb;
        #pragma unroll
        for (int i = 0; i < 4; ++i) {
            float4 v = *(const float4*)(p + i * 4);
            *(float4*)&T[rr][cb + i * 4] = v;
        }
    }
    __syncthreads();
    {
        int cc = tid >> 2;
        int rb = (tid & 3) * 16;
        bf16_t* o = out + (size_t)(c0 + cc) * R + r0 + rb;
        bf16x8 o0, o1;
        #pragma unroll
        for (int j = 0; j < 8; ++j) o0[j] = (bf16_t)T[rb + j][cc];
        #pragma unroll
        for (int j = 0; j < 8; ++j) o1[j] = (bf16_t)T[rb + 8 + j][cc];
        *(bf16x8*)(o) = o0;
        *(bf16x8*)(o + 8) = o1;
    }
}

// ---------------------------------------------------------------- LN of s -> bf16
__global__ __launch_bounds__(64) void k_ln_s(const float* __restrict__ s, const float* __restrict__ g,
    const float* __restrict__ b, bf16_t* __restrict__ out)
{
    int row = blockIdx.x;
    int lane = threadIdx.x;
    const float4* p = (const float4*)(s + (size_t)row * 512);
    float4 v0 = p[lane];
    float4 v1 = p[lane + 64];
    float sum = v0.x + v0.y + v0.z + v0.w + v1.x + v1.y + v1.z + v1.w;
    float sq  = v0.x*v0.x + v0.y*v0.y + v0.z*v0.z + v0.w*v0.w
              + v1.x*v1.x + v1.y*v1.y + v1.z*v1.z + v1.w*v1.w;
    #pragma unroll
    for (int off = 1; off < 64; off <<= 1) {
        sum += __shfl_xor(sum, off);
        sq  += __shfl_xor(sq, off);
    }
    float m = sum * (1.0f / 512.0f);
    float var = sq * (1.0f / 512.0f) - m * m;
    float rs = rsqrtf(var + 1e-5f);
    int c = lane * 4;
    int c2 = 256 + lane * 4;
    bf16x4 r0, r1;
    r0[0] = (bf16_t)((v0.x - m) * rs * g[c+0] + b[c+0]);
    r0[1] = (bf16_t)((v0.y - m) * rs * g[c+1] + b[c+1]);
    r0[2] = (bf16_t)((v0.z - m) * rs * g[c+2] + b[c+2]);
    r0[3] = (bf16_t)((v0.w - m) * rs * g[c+3] + b[c+3]);
    r1[0] = (bf16_t)((v1.x - m) * rs * g[c2+0] + b[c2+0]);
    r1[1] = (bf16_t)((v1.y - m) * rs * g[c2+1] + b[c2+1]);
    r1[2] = (bf16_t)((v1.z - m) * rs * g[c2+2] + b[c2+2]);
    r1[3] = (bf16_t)((v1.w - m) * rs * g[c2+3] + b[c2+3]);
    *(bf16x4*)(out + (size_t)row * 512 + c)  = r0;
    *(bf16x4*)(out + (size_t)row * 512 + c2) = r1;
}

// ---------------------------------------------------------------- MFMA GEMM 128x128 tile: C = A[M,K] * BT[N,K]^T
__global__ __launch_bounds__(256) void gemm_bf128(const bf16_t* __restrict__ A, const bf16_t* __restrict__ BT,
    float* __restrict__ C, int M, int N, int K)
{
    __shared__ bf16_t As[128][40];
    __shared__ bf16_t Bs[128][40];
    const int tid = threadIdx.x, lane = tid & 63, w = tid >> 6;
    const int row0 = blockIdx.y * 128, col0 = blockIdx.x * 128;
    const int wr = (w >> 1) * 64, wc = (w & 1) * 64;
    const int srow = tid >> 1, skoff = (tid & 1) * 16;
    const bf16_t* Ap = A + (size_t)(row0 + srow) * K + skoff;
    const bf16_t* Bp = BT + (size_t)(col0 + srow) * K + skoff;
    f32x4 acc[4][4];
    #pragma unroll
    for (int m = 0; m < 4; ++m)
        #pragma unroll
        for (int n = 0; n < 4; ++n) acc[m][n] = (f32x4){0.f,0.f,0.f,0.f};
    for (int k0 = 0; k0 < K; k0 += 32) {
        uint4 a0 = *(const uint4*)(Ap + k0);
        uint4 a1 = *(const uint4*)(Ap + k0 + 8);
        uint4 b0 = *(const uint4*)(Bp + k0);
        uint4 b1 = *(const uint4*)(Bp + k0 + 8);
        __syncthreads();
        *(uint4*)&As[srow][skoff]     = a0;
        *(uint4*)&As[srow][skoff + 8] = a1;
        *(uint4*)&Bs[srow][skoff]     = b0;
        *(uint4*)&Bs[srow][skoff + 8] = b1;
        __syncthreads();
        bf16x8 af[4], bfr[4];
        #pragma unroll
        for (int m = 0; m < 4; ++m) af[m]  = *(const bf16x8*)&As[wr + m*16 + (lane & 15)][(lane >> 4) * 8];
        #pragma unroll
        for (int n = 0; n < 4; ++n) bfr[n] = *(const bf16x8*)&Bs[wc + n*16 + (lane & 15)][(lane >> 4) * 8];
        #pragma unroll
        for (int m = 0; m < 4; ++m)
            #pragma unroll
            for (int n = 0; n < 4; ++n)
                acc[m][n] = __builtin_amdgcn_mfma_f32_16x16x32_bf16(af[m], bfr[n], acc[m][n], 0, 0, 0);
    }
    #pragma unroll
    for (int m = 0; m < 4; ++m)
        #pragma unroll
        for (int n = 0; n < 4; ++n)
            #pragma unroll
            for (int i = 0; i < 4; ++i)
                C[(size_t)(row0 + wr + m*16 + (lane >> 4)*4 + i) * N + col0 + wc + n*16 + (lane & 15)] = acc[m][n][i];
}

// ---------------------------------------------------------------- MFMA GEMM 128x64 tile (for out GEMM)
__global__ __launch_bounds__(256) void gemm_bf64(const bf16_t* __restrict__ A, const bf16_t* __restrict__ BT,
    float* __restrict__ C, int M, int N, int K)
{
    __shared__ bf16_t As[128][40];
    __shared__ bf16_t Bs[64][40];
    const int tid = threadIdx.x, lane = tid & 63, w = tid >> 6;
    const int row0 = blockIdx.y * 128, col0 = blockIdx.x * 64;
    const int wr = w * 32;
    const int srow = tid >> 1, skoff = (tid & 1) * 16;
    const int brow = tid >> 2, bkoff = (tid & 3) * 8;
    const bf16_t* Ap = A + (size_t)(row0 + srow) * K + skoff;
    const bf16_t* Bp = BT + (size_t)(col0 + brow) * K + bkoff;
    f32x4 acc[2][4];
    #pragma unroll
    for (int m = 0; m < 2; ++m)
        #pragma unroll
        for (int n = 0; n < 4; ++n) acc[m][n] = (f32x4){0.f,0.f,0.f,0.f};
    for (int k0 = 0; k0 < K; k0 += 32) {
        uint4 a0 = *(const uint4*)(Ap + k0);
        uint4 a1 = *(const uint4*)(Ap + k0 + 8);
        uint4 b0 = *(const uint4*)(Bp + k0);
        __syncthreads();
        *(uint4*)&As[srow][skoff]     = a0;
        *(uint4*)&As[srow][skoff + 8] = a1;
        *(uint4*)&Bs[brow][bkoff]     = b0;
        __syncthreads();
        bf16x8 af[2], bfr[4];
        #pragma unroll
        for (int m = 0; m < 2; ++m) af[m]  = *(const bf16x8*)&As[wr + m*16 + (lane & 15)][(lane >> 4) * 8];
        #pragma unroll
        for (int n = 0; n < 4; ++n) bfr[n] = *(const bf16x8*)&Bs[n*16 + (lane & 15)][(lane >> 4) * 8];
        #pragma unroll
        for (int m = 0; m < 2; ++m)
            #pragma unroll
            for (int n = 0; n < 4; ++n)
                acc[m][n] = __builtin_amdgcn_mfma_f32_16x16x32_bf16(af[m], bfr[n], acc[m][n], 0, 0, 0);
    }
    #pragma unroll
    for (int m = 0; m < 2; ++m)
        #pragma unroll
        for (int n = 0; n < 4; ++n)
            #pragma unroll
            for (int i = 0; i < 4; ++i)
                C[(size_t)(row0 + wr + m*16 + (lane >> 4)*4 + i) * N + col0 + n*16 + (lane & 15)] = acc[m][n][i];
}

// ---------------------------------------------------------------- rotate+translate projected points (in place, f32)
__global__ __launch_bounds__(256) void k_rot(float* __restrict__ proj, const float* __restrict__ rots,
    const float* __restrict__ trans)
{
    int row = blockIdx.x;
    int tid = threadIdx.x;
    const float* R = rots + (size_t)row * 9;
    const float* t = trans + (size_t)row * 3;
    float* base;
    if (tid < 64) base = proj + (size_t)row * PROJW + OFFQP + tid * 3;
    else          base = proj + (size_t)row * PROJW + OFFKVP + (tid - 64) * 3;
    float x = base[0], y = base[1], z = base[2];
    base[0] = R[0] * x + R[1] * y + R[2] * z + t[0];
    base[1] = R[3] * x + R[4] * y + R[5] * z + t[1];
    base[2] = R[6] * x + R[7] * y + R[8] * z + t[2];
}

// ---------------------------------------------------------------- z LayerNorm + bias/pair_z projection
// outputs: biasT f32 [rowq*16 + h][128k], pzT bf16 [rowq*32 + c][128k]
__global__ __launch_bounds__(256) void k_zbias(const float* __restrict__ z, const float* __restrict__ gz,
    const float* __restrict__ bz, const float* __restrict__ Wb, const float* __restrict__ Wdz,
    float* __restrict__ biasT, bf16_t* __restrict__ pzT)
{
    __shared__ float zs[64][132];
    __shared__ float WT[48][132];
    int bid = blockIdx.x;
    int pair = bid >> 1;
    int half = bid & 1;
    int tid = threadIdx.x;
    const float* zp = z + ((size_t)pair * 128 + (size_t)half * 64) * 128;
    #pragma unroll
    for (int i = 0; i < 8; ++i) {
        int v = tid + i * 256;
        int r = v >> 5;
        int c4 = (v & 31) * 4;
        float4 val = *(const float4*)(zp + (size_t)r * 128 + c4);
        *(float4*)(&zs[r][c4]) = val;
    }
    for (int i = tid; i < 2048; i += 256) WT[i & 15][i >> 4] = Wb[i];
    for (int i = tid; i < 4096; i += 256) WT[16 + (i & 31)][i >> 5] = Wdz[i];
    __syncthreads();
    {
        int r = tid >> 2, l4 = tid & 3;
        float sum = 0.f, sq = 0.f;
        #pragma unroll
        for (int i = 0; i < 8; ++i) {
            float4 v = *(const float4*)(&zs[r][l4 * 32 + i * 4]);
            sum += v.x + v.y + v.z + v.w;
            sq  += v.x*v.x + v.y*v.y + v.z*v.z + v.w*v.w;
        }
        sum += __shfl_xor(sum, 1); sq += __shfl_xor(sq, 1);
        sum += __shfl_xor(sum, 2); sq += __shfl_xor(sq, 2);
        float m = sum * (1.0f / 128.0f);
        float var = sq * (1.0f / 128.0f) - m * m;
        float rs = rsqrtf(var + 1e-5f);
        #pragma unroll
        for (int i = 0; i < 8; ++i) {
            int c = l4 * 32 + i * 4;
            float4 v = *(const float4*)(&zs[r][c]);
            float4 gv = *(const float4*)(gz + c);
            float4 bv = *(const float4*)(bz + c);
            v.x = (v.x - m) * rs * gv.x + bv.x;
            v.y = (v.y - m) * rs * gv.y + bv.y;
            v.z = (v.z - m) * rs * gv.z + bv.z;
            v.w = (v.w - m) * rs * gv.w + bv.w;
            *(float4*)(&zs[r][c]) = v;
        }
    }
    __syncthreads();
    {
        int rg = tid & 15;
        int jg = tid >> 4;
        int j0 = jg * 3;
        float acc[4][3];
        #pragma unroll
        for (int i = 0; i < 4; ++i) { acc[i][0] = 0.f; acc[i][1] = 0.f; acc[i][2] = 0.f; }
        for (int c4 = 0; c4 < 128; c4 += 4) {
            float4 w0 = *(const float4*)(&WT[j0 + 0][c4]);
            float4 w1 = *(const float4*)(&WT[j0 + 1][c4]);
            float4 w2 = *(const float4*)(&WT[j0 + 2][c4]);
            #pragma unroll
            for (int i = 0; i < 4; ++i) {
                float4 zv = *(const float4*)(&zs[rg + 16 * i][c4]);
                acc[i][0] += zv.x*w0.x + zv.y*w0.y + zv.z*w0.z + zv.w*w0.w;
                acc[i][1] += zv.x*w1.x + zv.y*w1.y + zv.z*w1.z + zv.w*w1.w;
                acc[i][2] += zv.x*w2.x + zv.y*w2.y + zv.z*w2.z + zv.w*w2.w;
            }
        }
        #pragma unroll
        for (int i = 0; i < 4; ++i) {
            int k = half * 64 + rg + 16 * i;
            #pragma unroll
            for (int jj = 0; jj < 3; ++jj) {
                int j = j0 + jj;
                if (j < 16) biasT[((size_t)pair * 16 + j) * 128 + k] = acc[i][jj];
                else        pzT[((size_t)pair * 32 + (j - 16)) * 128 + k] = (bf16_t)acc[i][jj];
            }
        }
    }
}

// ---------------------------------------------------------------- attention: one wg per (nblk, 4 heads)
__global__ __launch_bounds__(256) void k_attn2(
    const float* __restrict__ proj, const float* __restrict__ biasT,
    const float* __restrict__ rots, const float* __restrict__ trans,
    const float* __restrict__ smask, const int* __restrict__ kidx,
    const float* __restrict__ hwraw, bf16_t* __restrict__ catb,
    bf16_t* __restrict__ Pbf)
{
    __shared__ __align__(16) char uni[26112];          // Qs[32][72]b + Ks[128][72]b  OR  Vt[96][136]b
    __shared__ float att[32][132];
    __shared__ float kp_s[128][12];
    __shared__ float qp_s[32][12];
    __shared__ bf16_t Ps[32][136];
    __shared__ float optmp[32][33];
    __shared__ float km_s[128];
    __shared__ float qm_s[32];
    __shared__ int   rows_s[128];
    __shared__ float hws_s[4];

    bf16_t (*Qs)[72]  = (bf16_t(*)[72])uni;
    bf16_t (*Ks)[72]  = (bf16_t(*)[72])(uni + 32 * 72 * 2);
    bf16_t (*Vt)[136] = (bf16_t(*)[136])uni;

    const int nblk = blockIdx.x;
    const int hg = blockIdx.y;
    const int tid = threadIdx.x;
    const int lane = tid & 63;
    const int w = tid >> 6;
    const int rowq0 = nblk * 32;

    if (tid < 128) {
        int ki = kidx[nblk * 128 + tid];
        int valid = (ki >= 0 && ki < D_N);
        int rr = ki < 0 ? 0 : (ki > D_N - 1 ? D_N - 1 : ki);
        rows_s[tid] = rr;
        km_s[tid] = valid ? smask[rr] : 0.0f;
    } else if (tid < 160) {
        qm_s[tid - 128] = smask[rowq0 + tid - 128];
    } else if (tid < 164) {
        float x = hwraw[hg * 4 + tid - 160];
        hws_s[tid - 160] = log1pf(__expf(x)) * 0.13608276348795434f;
    }

    for (int it = 0; it < 4; ++it) {
        const int h = hg * 4 + it;
        __syncthreads();
        // ---- Phase A: stage Q (bf16), qp (f32), K (bf16), kp (f32)
        {
            int q = tid >> 3, cg = (tid & 7) * 8;
            const float* p = proj + (size_t)(rowq0 + q) * PROJW + h * 64 + cg;
            float4 v0 = *(const float4*)p;
            float4 v1 = *(const float4*)(p + 4);
            bf16x8 o;
            o[0]=(bf16_t)v0.x; o[1]=(bf16_t)v0.y; o[2]=(bf16_t)v0.z; o[3]=(bf16_t)v0.w;
            o[4]=(bf16_t)v1.x; o[5]=(bf16_t)v1.y; o[6]=(bf16_t)v1.z; o[7]=(bf16_t)v1.w;
            *(bf16x8*)&Qs[q][cg] = o;
        }
        if (tid < 128) {
            int q = tid >> 2, dg = (tid & 3) * 3;
            const float* p = proj + (size_t)(rowq0 + q) * PROJW + OFFQP + h * 12 + dg;
            qp_s[q][dg + 0] = p[0]; qp_s[q][dg + 1] = p[1]; qp_s[q][dg + 2] = p[2];
        }
        {
            int krow = tid >> 1, cg = (tid & 1) * 32;
            const float* p = proj + (size_t)rows_s[krow] * PROJW + OFFK + h * 64 + cg;
            #pragma unroll
            for (int u = 0; u < 4; ++u) {
                float4 v0 = *(const float4*)(p + u * 8);
                float4 v1 = *(const float4*)(p + u * 8 + 4);
                bf16x8 o;
                o[0]=(bf16_t)v0.x; o[1]=(bf16_t)v0.y; o[2]=(bf16_t)v0.z; o[3]=(bf16_t)v0.w;
                o[4]=(bf16_t)v1.x; o[5]=(bf16_t)v1.y; o[6]=(bf16_t)v1.z; o[7]=(bf16_t)v1.w;
                *(bf16x8*)&Ks[krow][cg + u * 8] = o;
            }
            const float* pk = proj + (size_t)rows_s[krow] * PROJW + OFFKVP + h * 36 + (tid & 1) * 6;
            int dg = (tid & 1) * 6;
            #pragma unroll
            for (int u = 0; u < 6; ++u) kp_s[krow][dg + u] = pk[u];
        }
        __syncthreads();
        // ---- Phase B: QK^T MFMA -> att (raw dots)
        {
            #pragma unroll
            for (int j = 0; j < 4; ++j) {
                int T = w * 4 + j;
                int m = T & 1, n = T >> 1;
                f32x4 acc = (f32x4){0.f,0.f,0.f,0.f};
                #pragma unroll
                for (int kc = 0; kc < 2; ++kc) {
                    bf16x8 a = *(const bf16x8*)&Qs[m*16 + (lane & 15)][kc*32 + (lane >> 4) * 8];
                    bf16x8 b = *(const bf16x8*)&Ks[n*16 + (lane & 15)][kc*32 + (lane >> 4) * 8];
                    acc = __builtin_amdgcn_mfma_f32_16x16x32_bf16(a, b, acc, 0, 0, 0);
                }
                #pragma unroll
                for (int i = 0; i < 4; ++i)
                    att[m*16 + (lane >> 4)*4 + i][n*16 + (lane & 15)] = acc[i];
            }
        }
        __syncthreads();
        // ---- Phase C: stage V^T + vpts^T (bf16, overwrites Qs/Ks) and f32 logit assembly
        {
            int krow = tid >> 1, cg = (tid & 1) * 32;
            const float* p = proj + (size_t)rows_s[krow] * PROJW + OFFV + h * 64 + cg;
            #pragma unroll
            for (int u = 0; u < 8; ++u) {
                float4 v = *(const float4*)(p + u * 4);
                Vt[cg + u*4 + 0][krow] = (bf16_t)v.x;
                Vt[cg + u*4 + 1][krow] = (bf16_t)v.y;
                Vt[cg + u*4 + 2][krow] = (bf16_t)v.z;
                Vt[cg + u*4 + 3][krow] = (bf16_t)v.w;
            }
            const float* pv = proj + (size_t)rows_s[krow] * PROJW + OFFKVP + h * 36 + 12 + (tid & 1) * 12;
            #pragma unroll
            for (int u = 0; u < 3; ++u) {
                float4 v = *(const float4*)(pv + u * 4);
                int rb = 64 + (tid & 1) * 12 + u * 4;
                Vt[rb + 0][krow] = (bf16_t)v.x;
                Vt[rb + 1][krow] = (bf16_t)v.y;
                Vt[rb + 2][krow] = (bf16_t)v.z;
                Vt[rb + 3][krow] = (bf16_t)v.w;
            }
            {   // zero-pad rows 88..95
                int r = 88 + (tid >> 5), c = (tid & 31) * 4;
                bf16x4 zz; zz[0]=(bf16_t)0.f; zz[1]=(bf16_t)0.f; zz[2]=(bf16_t)0.f; zz[3]=(bf16_t)0.f;
                *(bf16x4*)&Vt[r][c] = zz;
            }
            // logits
            int q = tid >> 3, kg = tid & 7;
            float qp[12];
            #pragma unroll
            for (int e = 0; e < 12; ++e) qp[e] = qp_s[q][e];
            float qm = qm_s[q];
            float hw = hws_s[it];
            const float* bT = biasT + ((size_t)(rowq0 + q) * 16 + h) * 128;
            #pragma unroll
            for (int j2 = 0; j2 < 16; ++j2) {
                int k = kg + j2 * 8;
                float4 k0 = *(const float4*)&kp_s[k][0];
                float4 k1 = *(const float4*)&kp_s[k][4];
                float4 k2 = *(const float4*)&kp_s[k][8];
                float d0 = qp[0]-k0.x, d1 = qp[1]-k0.y, d2_ = qp[2]-k0.z, d3 = qp[3]-k0.w;
                float d4 = qp[4]-k1.x, d5 = qp[5]-k1.y, d6 = qp[6]-k1.z, d7 = qp[7]-k1.w;
                float d8 = qp[8]-k2.x, d9 = qp[9]-k2.y, d10 = qp[10]-k2.z, d11 = qp[11]-k2.w;
                float dd = d0*d0+d1*d1+d2_*d2_+d3*d3+d4*d4+d5*d5+d6*d6+d7*d7+d8*d8+d9*d9+d10*d10+d11*d11;
                float val = att[q][k] * 0.07216878364870323f
                          + 0.5773502691896258f * bT[k]
                          + 100000.0f * (qm * km_s[k] - 1.0f)
                          - 0.5f * hw * dd;
                att[q][k] = val;
            }
        }
        __syncthreads();
        // ---- Phase D: softmax + P -> bf16 (LDS + global)
        {
            int q = tid >> 3, kg = tid & 7;
            float l[16];
            #pragma unroll
            for (int j2 = 0; j2 < 16; ++j2) l[j2] = att[q][kg + j2 * 8];
            float mx = l[0];
            #pragma unroll
            for (int j2 = 1; j2 < 16; ++j2) mx = fmaxf(mx, l[j2]);
            mx = fmaxf(mx, __shfl_xor(mx, 1));
            mx = fmaxf(mx, __shfl_xor(mx, 2));
            mx = fmaxf(mx, __shfl_xor(mx, 4));
            float se = 0.f;
            #pragma unroll
            for (int j2 = 0; j2 < 16; ++j2) { l[j2] = __expf(l[j2] - mx); se += l[j2]; }
            se += __shfl_xor(se, 1);
            se += __shfl_xor(se, 2);
            se += __shfl_xor(se, 4);
            float inv = 1.0f / se;
            bf16_t* pg = Pbf + ((size_t)(rowq0 + q) * 16 + h) * 128;
            #pragma unroll
            for (int j2 = 0; j2 < 16; ++j2) {
                bf16_t pb = (bf16_t)(l[j2] * inv);
                Ps[q][kg + j2 * 8] = pb;
                pg[kg + j2 * 8] = pb;
            }
        }
        __syncthreads();
        // ---- Phase E: PV MFMA (o cols 0..63, o_pt raw cols 64..87)
        {
            #pragma unroll
            for (int j = 0; j < 3; ++j) {
                int T = w * 3 + j;
                int m = T & 1, n = T >> 1;
                f32x4 acc = (f32x4){0.f,0.f,0.f,0.f};
                #pragma unroll
                for (int kc = 0; kc < 4; ++kc) {
                    bf16x8 a = *(const bf16x8*)&Ps[m*16 + (lane & 15)][kc*32 + (lane >> 4) * 8];
                    bf16x8 b = *(const bf16x8*)&Vt[n*16 + (lane & 15)][kc*32 + (lane >> 4) * 8];
                    acc = __builtin_amdgcn_mfma_f32_16x16x32_bf16(a, b, acc, 0, 0, 0);
                }
                int rowb = m * 16 + (lane >> 4) * 4;
                int col = lane & 15;
                if (n < 4) {
                    #pragma unroll
                    for (int i = 0; i < 4; ++i)
                        catb[(size_t)(rowq0 + rowb + i) * CATW + h * 64 + n * 16 + col] = (bf16_t)acc[i];
                } else {
                    #pragma unroll
                    for (int i = 0; i < 4; ++i)
                        optmp[rowb + i][(n - 4) * 16 + col] = acc[i];
                }
            }
        }
        __syncthreads();
        // ---- Phase F: o_pt inverse transform + norm
        {
            int q = tid >> 3, pp = tid & 7;
            float sx = optmp[q][pp * 3 + 0];
            float sy = optmp[q][pp * 3 + 1];
            float sz = optmp[q][pp * 3 + 2];
            const float* R = rots + (size_t)(rowq0 + q) * 9;
            const float* t = trans + (size_t)(rowq0 + q) * 3;
            float x = sx - t[0], y = sy - t[1], z2 = sz - t[2];
            float ox = R[0] * x + R[3] * y + R[6] * z2;
            float oy = R[1] * x + R[4] * y + R[7] * z2;
            float oz = R[2] * x + R[5] * y + R[8] * z2;
            bf16_t* cp = catb + (size_t)(rowq0 + q) * CATW;
            cp[1024 + h * 24 + pp * 3 + 0] = (bf16_t)ox;
            cp[1024 + h * 24 + pp * 3 + 1] = (bf16_t)oy;
            cp[1024 + h * 24 + pp * 3 + 2] = (bf16_t)oz;
            cp[1408 + h * 8 + pp] = (bf16_t)sqrtf(ox * ox + oy * oy + oz * oz + 1e-8f);
        }
    }
}

// ---------------------------------------------------------------- o_pair: per rowq MFMA [16h x 128k] x [128k x 32c]
__global__ __launch_bounds__(256) void k_opair(const bf16_t* __restrict__ Pbf,
    const bf16_t* __restrict__ pzT, bf16_t* __restrict__ catb)
{
    int tid = threadIdx.x, lane = tid & 63, w = tid >> 6;
    size_t rowq = (size_t)blockIdx.x * 4 + w;
    const bf16_t* Pp = Pbf + rowq * 2048;
    const bf16_t* zp = pzT + rowq * 4096;
    bf16x8 pa[4];
    #pragma unroll
    for (int kc = 0; kc < 4; ++kc)
        pa[kc] = *(const bf16x8*)(Pp + (size_t)(lane & 15) * 128 + kc * 32 + (lane >> 4) * 8);
    #pragma unroll
    for (int ct = 0; ct < 2; ++ct) {
        f32x4 acc = (f32x4){0.f,0.f,0.f,0.f};
        #pragma unroll
        for (int kc = 0; kc < 4; ++kc) {
            bf16x8 b = *(const bf16x8*)(zp + (size_t)(ct * 16 + (lane & 15)) * 128 + kc * 32 + (lane >> 4) * 8);
            acc = __builtin_amdgcn_mfma_f32_16x16x32_bf16(pa[kc], b, acc, 0, 0, 0);
        }
        #pragma unroll
        for (int i = 0; i < 4; ++i) {
            int hh = (lane >> 4) * 4 + i;
            catb[rowq * CATW + 1536 + hh * 32 + ct * 16 + (lane & 15)] = (bf16_t)acc[i];
        }
    }
}

// ---------------------------------------------------------------- launcher
extern "C" void kernel_launch(void* const* d_in, const int* in_sizes, int n_in,
                              void* d_out, int out_size, void* d_ws, size_t ws_size,
                              hipStream_t stream)
{
    (void)in_sizes; (void)n_in; (void)out_size;
    const float* s     = (const float*)d_in[0];
    const float* z     = (const float*)d_in[1];
    const float* trans = (const float*)d_in[2];
    const float* rots  = (const float*)d_in[3];
    const float* smask = (const float*)d_in[4];
    const int*   kidx  = (const int*)d_in[5];
    const float* Wq    = (const float*)d_in[6];
    const float* Wk    = (const float*)d_in[7];
    const float* Wv    = (const float*)d_in[8];
    const float* Wqp   = (const float*)d_in[9];
    const float* Wkvp  = (const float*)d_in[10];
    const float* Wb    = (const float*)d_in[11];
    const float* Wdz   = (const float*)d_in[12];
    const float* hw    = (const float*)d_in[13];
    const float* Wout  = (const float*)d_in[14];
    const float* g_s   = (const float*)d_in[15];
    const float* b_s   = (const float*)d_in[16];
    const float* g_z   = (const float*)d_in[17];
    const float* b_z   = (const float*)d_in[18];

    char* ws = (char*)d_ws;
    float*  proj  = (float*)(ws);                                  // 62,914,560 B
    float*  wcat  = (float*)(ws + 62914560);                       //  7,864,320 B
    float*  biasT = (float*)(ws + 70778880);                       // 33,554,432 B
    bf16_t* wcatT = (bf16_t*)(ws + 104333312);                     //  3,932,160 B
    bf16_t* s_nb  = (bf16_t*)(ws + 108265472);                     //  4,194,304 B
    bf16_t* pzT   = (bf16_t*)(ws + 112459776);                     // 33,554,432 B
    bf16_t* Pbf   = (bf16_t*)(ws + 146014208);                     // 16,777,216 B
    bf16_t* catb  = (bf16_t*)(ws + 162791424);                     // 16,777,216 B
    bf16_t* WoutT = (bf16_t*)(ws + 179568640);                     //  2,097,152 B
    if (ws_size < (size_t)181665792) return;
    float* out = (float*)d_out;

    k_wcat<<<dim3(15, 512), 256, 0, stream>>>(Wq, Wk, Wv, Wqp, Wkvp, wcat);
    t_cvt<<<dim3(60, 8), 256, 0, stream>>>(wcat, wcatT, 512, 3840);
    t_cvt<<<dim3(8, 32), 256, 0, stream>>>(Wout, WoutT, 2048, 512);
    k_ln_s<<<4096, 64, 0, stream>>>(s, g_s, b_s, s_nb);
    gemm_bf128<<<dim3(30, 32), 256, 0, stream>>>(s_nb, wcatT, proj, 4096, 3840, 512);
    k_rot<<<4096, 256, 0, stream>>>(proj, rots, trans);
    k_zbias<<<8192, 256, 0, stream>>>(z, g_z, b_z, Wb, Wdz, biasT, pzT);
    k_attn2<<<dim3(128, 4), 256, 0, stream>>>(proj, biasT, rots, trans, smask, kidx, hw, catb, Pbf);
    k_opair<<<1024, 256, 0, stream>>>(Pbf, pzT, catb);
    gemm_bf64<<<dim3(8, 32), 256, 0, stream>>>(catb, WoutT, out, 4096, 512, 2048);
}

// Round 3
// 249.950 us; speedup vs baseline: 4.4120x; 1.5634x over previous
//
#include <hip/hip_runtime.h>
#include <math.h>

#define D_N 4096
#define PROJW 3840
#define OFFK 1024
#define OFFV 2048
#define OFFQP 3072
#define OFFKVP 3264
#define CATW 2048

typedef __bf16 bf16_t;
typedef __bf16 bf16x8 __attribute__((ext_vector_type(8)));
typedef __bf16 bf16x4 __attribute__((ext_vector_type(4)));
typedef float f32x4 __attribute__((ext_vector_type(4)));

// ---------------------------------------------------------------- Wcat^T build: out bf16 [3840][512] from 5 weights
__global__ __launch_bounds__(256) void k_wcatT(const float* __restrict__ Wq, const float* __restrict__ Wk,
    const float* __restrict__ Wv, const float* __restrict__ Wqp, const float* __restrict__ Wkvp,
    bf16_t* __restrict__ out)
{
    __shared__ float T[64][65];
    int c0 = blockIdx.x * 64;
    int r0 = blockIdx.y * 64;
    const float* src; int ld, coff;
    if (c0 < 1024)      { src = Wq;   ld = 1024; coff = c0; }
    else if (c0 < 2048) { src = Wk;   ld = 1024; coff = c0 - 1024; }
    else if (c0 < 3072) { src = Wv;   ld = 1024; coff = c0 - 2048; }
    else if (c0 < 3264) { src = Wqp;  ld = 192;  coff = c0 - 3072; }
    else                { src = Wkvp; ld = 576;  coff = c0 - 3264; }
    int tid = threadIdx.x;
    {
        int rr = tid >> 2, cb = (tid & 3) * 16;
        const float* p = src + (size_t)(r0 + rr) * ld + coff + cb;
        #pragma unroll
        for (int i = 0; i < 4; ++i)
            *(float4*)&T[rr][cb + i * 4] = *(const float4*)(p + i * 4);
    }
    __syncthreads();
    {
        int cc = tid >> 2, rb = (tid & 3) * 16;
        bf16_t* o = out + (size_t)(c0 + cc) * 512 + r0 + rb;
        bf16x8 o0, o1;
        #pragma unroll
        for (int j = 0; j < 8; ++j) o0[j] = (bf16_t)T[rb + j][cc];
        #pragma unroll
        for (int j = 0; j < 8; ++j) o1[j] = (bf16_t)T[rb + 8 + j][cc];
        *(bf16x8*)(o) = o0;
        *(bf16x8*)(o + 8) = o1;
    }
}

// ---------------------------------------------------------------- transpose + cvt: in f32 [R][C] -> out bf16 [C][R]
__global__ __launch_bounds__(256) void t_cvt(const float* __restrict__ in, bf16_t* __restrict__ out,
    int R, int C)
{
    __shared__ float T[64][65];
    int r0 = blockIdx.y * 64, c0 = blockIdx.x * 64;
    int tid = threadIdx.x;
    {
        int rr = tid >> 2;
        int cb = (tid & 3) * 16;
        const float* p = in + (size_t)(r0 + rr) * C + c0 + cb;
        #pragma unroll
        for (int i = 0; i < 4; ++i) {
            float4 v = *(const float4*)(p + i * 4);
            *(float4*)&T[rr][cb + i * 4] = v;
        }
    }
    __syncthreads();
    {
        int cc = tid >> 2;
        int rb = (tid & 3) * 16;
        bf16_t* o = out + (size_t)(c0 + cc) * R + r0 + rb;
        bf16x8 o0, o1;
        #pragma unroll
        for (int j = 0; j < 8; ++j) o0[j] = (bf16_t)T[rb + j][cc];
        #pragma unroll
        for (int j = 0; j < 8; ++j) o1[j] = (bf16_t)T[rb + 8 + j][cc];
        *(bf16x8*)(o) = o0;
        *(bf16x8*)(o + 8) = o1;
    }
}

// ---------------------------------------------------------------- WzT build: bf16 [48][128]; rows 0..15 = Wb^T, 16..47 = Wdz^T
__global__ __launch_bounds__(256) void k_wz(const float* __restrict__ Wb, const float* __restrict__ Wdz,
    bf16_t* __restrict__ WzT)
{
    int i = blockIdx.x * 256 + threadIdx.x;   // 6144 total
    if (i >= 6144) return;
    int j = i >> 7, k = i & 127;
    float v = (j < 16) ? Wb[k * 16 + j] : Wdz[k * 32 + (j - 16)];
    WzT[i] = (bf16_t)v;
}

// ---------------------------------------------------------------- LN of s -> bf16
__global__ __launch_bounds__(64) void k_ln_s(const float* __restrict__ s, const float* __restrict__ g,
    const float* __restrict__ b, bf16_t* __restrict__ out)
{
    int row = blockIdx.x;
    int lane = threadIdx.x;
    const float4* p = (const float4*)(s + (size_t)row * 512);
    float4 v0 = p[lane];
    float4 v1 = p[lane + 64];
    float sum = v0.x + v0.y + v0.z + v0.w + v1.x + v1.y + v1.z + v1.w;
    float sq  = v0.x*v0.x + v0.y*v0.y + v0.z*v0.z + v0.w*v0.w
              + v1.x*v1.x + v1.y*v1.y + v1.z*v1.z + v1.w*v1.w;
    #pragma unroll
    for (int off = 1; off < 64; off <<= 1) {
        sum += __shfl_xor(sum, off);
        sq  += __shfl_xor(sq, off);
    }
    float m = sum * (1.0f / 512.0f);
    float var = sq * (1.0f / 512.0f) - m * m;
    float rs = rsqrtf(var + 1e-5f);
    int c = lane * 4;
    int c2 = 256 + lane * 4;
    bf16x4 r0, r1;
    r0[0] = (bf16_t)((v0.x - m) * rs * g[c+0] + b[c+0]);
    r0[1] = (bf16_t)((v0.y - m) * rs * g[c+1] + b[c+1]);
    r0[2] = (bf16_t)((v0.z - m) * rs * g[c+2] + b[c+2]);
    r0[3] = (bf16_t)((v0.w - m) * rs * g[c+3] + b[c+3]);
    r1[0] = (bf16_t)((v1.x - m) * rs * g[c2+0] + b[c2+0]);
    r1[1] = (bf16_t)((v1.y - m) * rs * g[c2+1] + b[c2+1]);
    r1[2] = (bf16_t)((v1.z - m) * rs * g[c2+2] + b[c2+2]);
    r1[3] = (bf16_t)((v1.w - m) * rs * g[c2+3] + b[c2+3]);
    *(bf16x4*)(out + (size_t)row * 512 + c)  = r0;
    *(bf16x4*)(out + (size_t)row * 512 + c2) = r1;
}

// ---------------------------------------------------------------- MFMA GEMM 128x128 tile: C = A[M,K] * BT[N,K]^T
__global__ __launch_bounds__(256) void gemm_bf128(const bf16_t* __restrict__ A, const bf16_t* __restrict__ BT,
    float* __restrict__ C, int M, int N, int K)
{
    __shared__ bf16_t As[128][40];
    __shared__ bf16_t Bs[128][40];
    const int tid = threadIdx.x, lane = tid & 63, w = tid >> 6;
    const int row0 = blockIdx.y * 128, col0 = blockIdx.x * 128;
    const int wr = (w >> 1) * 64, wc = (w & 1) * 64;
    const int srow = tid >> 1, skoff = (tid & 1) * 16;
    const bf16_t* Ap = A + (size_t)(row0 + srow) * K + skoff;
    const bf16_t* Bp = BT + (size_t)(col0 + srow) * K + skoff;
    f32x4 acc[4][4];
    #pragma unroll
    for (int m = 0; m < 4; ++m)
        #pragma unroll
        for (int n = 0; n < 4; ++n) acc[m][n] = (f32x4){0.f,0.f,0.f,0.f};
    for (int k0 = 0; k0 < K; k0 += 32) {
        uint4 a0 = *(const uint4*)(Ap + k0);
        uint4 a1 = *(const uint4*)(Ap + k0 + 8);
        uint4 b0 = *(const uint4*)(Bp + k0);
        uint4 b1 = *(const uint4*)(Bp + k0 + 8);
        __syncthreads();
        *(uint4*)&As[srow][skoff]     = a0;
        *(uint4*)&As[srow][skoff + 8] = a1;
        *(uint4*)&Bs[srow][skoff]     = b0;
        *(uint4*)&Bs[srow][skoff + 8] = b1;
        __syncthreads();
        bf16x8 af[4], bfr[4];
        #pragma unroll
        for (int m = 0; m < 4; ++m) af[m]  = *(const bf16x8*)&As[wr + m*16 + (lane & 15)][(lane >> 4) * 8];
        #pragma unroll
        for (int n = 0; n < 4; ++n) bfr[n] = *(const bf16x8*)&Bs[wc + n*16 + (lane & 15)][(lane >> 4) * 8];
        #pragma unroll
        for (int m = 0; m < 4; ++m)
            #pragma unroll
            for (int n = 0; n < 4; ++n)
                acc[m][n] = __builtin_amdgcn_mfma_f32_16x16x32_bf16(af[m], bfr[n], acc[m][n], 0, 0, 0);
    }
    #pragma unroll
    for (int m = 0; m < 4; ++m)
        #pragma unroll
        for (int n = 0; n < 4; ++n)
            #pragma unroll
            for (int i = 0; i < 4; ++i)
                C[(size_t)(row0 + wr + m*16 + (lane >> 4)*4 + i) * N + col0 + wc + n*16 + (lane & 15)] = acc[m][n][i];
}

// ---------------------------------------------------------------- MFMA GEMM 128x64 tile (for out GEMM)
__global__ __launch_bounds__(256) void gemm_bf64(const bf16_t* __restrict__ A, const bf16_t* __restrict__ BT,
    float* __restrict__ C, int M, int N, int K)
{
    __shared__ bf16_t As[128][40];
    __shared__ bf16_t Bs[64][40];
    const int tid = threadIdx.x, lane = tid & 63, w = tid >> 6;
    const int row0 = blockIdx.y * 128, col0 = blockIdx.x * 64;
    const int wr = w * 32;
    const int srow = tid >> 1, skoff = (tid & 1) * 16;
    const int brow = tid >> 2, bkoff = (tid & 3) * 8;
    const bf16_t* Ap = A + (size_t)(row0 + srow) * K + skoff;
    const bf16_t* Bp = BT + (size_t)(col0 + brow) * K + bkoff;
    f32x4 acc[2][4];
    #pragma unroll
    for (int m = 0; m < 2; ++m)
        #pragma unroll
        for (int n = 0; n < 4; ++n) acc[m][n] = (f32x4){0.f,0.f,0.f,0.f};
    for (int k0 = 0; k0 < K; k0 += 32) {
        uint4 a0 = *(const uint4*)(Ap + k0);
        uint4 a1 = *(const uint4*)(Ap + k0 + 8);
        uint4 b0 = *(const uint4*)(Bp + k0);
        __syncthreads();
        *(uint4*)&As[srow][skoff]     = a0;
        *(uint4*)&As[srow][skoff + 8] = a1;
        *(uint4*)&Bs[brow][bkoff]     = b0;
        __syncthreads();
        bf16x8 af[2], bfr[4];
        #pragma unroll
        for (int m = 0; m < 2; ++m) af[m]  = *(const bf16x8*)&As[wr + m*16 + (lane & 15)][(lane >> 4) * 8];
        #pragma unroll
        for (int n = 0; n < 4; ++n) bfr[n] = *(const bf16x8*)&Bs[n*16 + (lane & 15)][(lane >> 4) * 8];
        #pragma unroll
        for (int m = 0; m < 2; ++m)
            #pragma unroll
            for (int n = 0; n < 4; ++n)
                acc[m][n] = __builtin_amdgcn_mfma_f32_16x16x32_bf16(af[m], bfr[n], acc[m][n], 0, 0, 0);
    }
    #pragma unroll
    for (int m = 0; m < 2; ++m)
        #pragma unroll
        for (int n = 0; n < 4; ++n)
            #pragma unroll
            for (int i = 0; i < 4; ++i)
                C[(size_t)(row0 + wr + m*16 + (lane >> 4)*4 + i) * N + col0 + n*16 + (lane & 15)] = acc[m][n][i];
}

// ---------------------------------------------------------------- rotate+translate projected points (in place, f32)
__global__ __launch_bounds__(256) void k_rot(float* __restrict__ proj, const float* __restrict__ rots,
    const float* __restrict__ trans)
{
    int row = blockIdx.x;
    int tid = threadIdx.x;
    const float* R = rots + (size_t)row * 9;
    const float* t = trans + (size_t)row * 3;
    float* base;
    if (tid < 64) base = proj + (size_t)row * PROJW + OFFQP + tid * 3;
    else          base = proj + (size_t)row * PROJW + OFFKVP + (tid - 64) * 3;
    float x = base[0], y = base[1], z = base[2];
    base[0] = R[0] * x + R[1] * y + R[2] * z + t[0];
    base[1] = R[3] * x + R[4] * y + R[5] * z + t[1];
    base[2] = R[6] * x + R[7] * y + R[8] * z + t[2];
}

// ---------------------------------------------------------------- z LN + projection, register-resident MFMA version
// grid: 2048 blocks x 256 thr; each wave does 4 tiles of 16 z-rows
__global__ __launch_bounds__(256) void k_zbias2(const float* __restrict__ z,
    const float* __restrict__ gz, const float* __restrict__ bz,
    const bf16_t* __restrict__ WzT, float* __restrict__ biasT, bf16_t* __restrict__ pzT)
{
    __shared__ float gb_s[256];
    const int tid = threadIdx.x;
    if (tid < 128) gb_s[tid] = gz[tid];
    else           gb_s[tid] = bz[tid - 128];
    const int lane = tid & 63, w = tid >> 6;
    const int r16 = lane & 15, kg = lane >> 4;
    // B fragments: WzT[nt*16 + r16][kc*32 + kg*8 ..+8]
    bf16x8 bfz[3][4];
    #pragma unroll
    for (int nt = 0; nt < 3; ++nt)
        #pragma unroll
        for (int kc = 0; kc < 4; ++kc)
            bfz[nt][kc] = *(const bf16x8*)(WzT + (size_t)(nt * 16 + r16) * 128 + kc * 32 + kg * 8);
    __syncthreads();
    const int gw = blockIdx.x * 4 + w;
    const int totw = 2048 * 4;
    for (int it = 0; it < 4; ++it) {
        const int tile = gw + it * totw;         // 0..32767
        const int z0 = tile * 16;
        const float* zp = z + (size_t)z0 * 128 + (size_t)r16 * 128 + kg * 8;
        float4 zr[4][2];
        float sum = 0.f, sq = 0.f;
        #pragma unroll
        for (int kc = 0; kc < 4; ++kc) {
            float4 a = *(const float4*)(zp + kc * 32);
            float4 b = *(const float4*)(zp + kc * 32 + 4);
            zr[kc][0] = a; zr[kc][1] = b;
            sum += a.x + a.y + a.z + a.w + b.x + b.y + b.z + b.w;
            sq  += a.x*a.x + a.y*a.y + a.z*a.z + a.w*a.w + b.x*b.x + b.y*b.y + b.z*b.z + b.w*b.w;
        }
        sum += __shfl_xor(sum, 16); sq += __shfl_xor(sq, 16);
        sum += __shfl_xor(sum, 32); sq += __shfl_xor(sq, 32);
        float m = sum * (1.0f / 128.0f);
        float var = sq * (1.0f / 128.0f) - m * m;
        float rs = rsqrtf(var + 1e-5f);
        bf16x8 af[4];
        #pragma unroll
        for (int kc = 0; kc < 4; ++kc) {
            const float* gp = &gb_s[kc * 32 + kg * 8];
            const float* bp = &gb_s[128 + kc * 32 + kg * 8];
            float4 g0 = *(const float4*)gp,     g1 = *(const float4*)(gp + 4);
            float4 b0 = *(const float4*)bp,     b1 = *(const float4*)(bp + 4);
            af[kc][0] = (bf16_t)((zr[kc][0].x - m) * rs * g0.x + b0.x);
            af[kc][1] = (bf16_t)((zr[kc][0].y - m) * rs * g0.y + b0.y);
            af[kc][2] = (bf16_t)((zr[kc][0].z - m) * rs * g0.z + b0.z);
            af[kc][3] = (bf16_t)((zr[kc][0].w - m) * rs * g0.w + b0.w);
            af[kc][4] = (bf16_t)((zr[kc][1].x - m) * rs * g1.x + b1.x);
            af[kc][5] = (bf16_t)((zr[kc][1].y - m) * rs * g1.y + b1.y);
            af[kc][6] = (bf16_t)((zr[kc][1].z - m) * rs * g1.z + b1.z);
            af[kc][7] = (bf16_t)((zr[kc][1].w - m) * rs * g1.w + b1.w);
        }
        f32x4 acc0 = (f32x4){0.f,0.f,0.f,0.f};
        f32x4 acc1 = (f32x4){0.f,0.f,0.f,0.f};
        f32x4 acc2 = (f32x4){0.f,0.f,0.f,0.f};
        #pragma unroll
        for (int kc = 0; kc < 4; ++kc) {
            acc0 = __builtin_amdgcn_mfma_f32_16x16x32_bf16(af[kc], bfz[0][kc], acc0, 0, 0, 0);
            acc1 = __builtin_amdgcn_mfma_f32_16x16x32_bf16(af[kc], bfz[1][kc], acc1, 0, 0, 0);
            acc2 = __builtin_amdgcn_mfma_f32_16x16x32_bf16(af[kc], bfz[2][kc], acc2, 0, 0, 0);
        }
        const int rowq = z0 >> 7;
        const int k0 = (z0 & 127) + kg * 4;
        // D layout: col = lane&15 (=r16) = output col, row = kg*4+i = k within tile
        float4 bw = {acc0[0], acc0[1], acc0[2], acc0[3]};
        *(float4*)&biasT[((size_t)rowq * 16 + r16) * 128 + k0] = bw;
        bf16x4 p1, p2;
        #pragma unroll
        for (int i = 0; i < 4; ++i) { p1[i] = (bf16_t)acc1[i]; p2[i] = (bf16_t)acc2[i]; }
        *(bf16x4*)&pzT[((size_t)rowq * 32 + r16) * 128 + k0] = p1;
        *(bf16x4*)&pzT[((size_t)rowq * 32 + 16 + r16) * 128 + k0] = p2;
    }
}

// ---------------------------------------------------------------- attention: one wg per (nblk, 4 heads)
__global__ __launch_bounds__(256) void k_attn2(
    const float* __restrict__ proj, const float* __restrict__ biasT,
    const float* __restrict__ rots, const float* __restrict__ trans,
    const float* __restrict__ smask, const int* __restrict__ kidx,
    const float* __restrict__ hwraw, bf16_t* __restrict__ catb,
    bf16_t* __restrict__ Pbf)
{
    __shared__ __align__(16) char uni[26112];          // Qs[32][72]b + Ks[128][72]b  OR  Vt[96][136]b
    __shared__ float att[32][132];
    __shared__ float kp_s[128][12];
    __shared__ float qp_s[32][12];
    __shared__ bf16_t Ps[32][136];
    __shared__ float optmp[32][33];
    __shared__ float km_s[128];
    __shared__ float qm_s[32];
    __shared__ int   rows_s[128];
    __shared__ float hws_s[4];

    bf16_t (*Qs)[72]  = (bf16_t(*)[72])uni;
    bf16_t (*Ks)[72]  = (bf16_t(*)[72])(uni + 32 * 72 * 2);
    bf16_t (*Vt)[136] = (bf16_t(*)[136])uni;

    const int nblk = blockIdx.x;
    const int hg = blockIdx.y;
    const int tid = threadIdx.x;
    const int lane = tid & 63;
    const int w = tid >> 6;
    const int rowq0 = nblk * 32;

    if (tid < 128) {
        int ki = kidx[nblk * 128 + tid];
        int valid = (ki >= 0 && ki < D_N);
        int rr = ki < 0 ? 0 : (ki > D_N - 1 ? D_N - 1 : ki);
        rows_s[tid] = rr;
        km_s[tid] = valid ? smask[rr] : 0.0f;
    } else if (tid < 160) {
        qm_s[tid - 128] = smask[rowq0 + tid - 128];
    } else if (tid < 164) {
        float x = hwraw[hg * 4 + tid - 160];
        hws_s[tid - 160] = log1pf(__expf(x)) * 0.13608276348795434f;
    }

    for (int it = 0; it < 4; ++it) {
        const int h = hg * 4 + it;
        __syncthreads();
        // ---- Phase A: stage Q (bf16), qp (f32), K (bf16), kp (f32)
        {
            int q = tid >> 3, cg = (tid & 7) * 8;
            const float* p = proj + (size_t)(rowq0 + q) * PROJW + h * 64 + cg;
            float4 v0 = *(const float4*)p;
            float4 v1 = *(const float4*)(p + 4);
            bf16x8 o;
            o[0]=(bf16_t)v0.x; o[1]=(bf16_t)v0.y; o[2]=(bf16_t)v0.z; o[3]=(bf16_t)v0.w;
            o[4]=(bf16_t)v1.x; o[5]=(bf16_t)v1.y; o[6]=(bf16_t)v1.z; o[7]=(bf16_t)v1.w;
            *(bf16x8*)&Qs[q][cg] = o;
        }
        if (tid < 128) {
            int q = tid >> 2, dg = (tid & 3) * 3;
            const float* p = proj + (size_t)(rowq0 + q) * PROJW + OFFQP + h * 12 + dg;
            qp_s[q][dg + 0] = p[0]; qp_s[q][dg + 1] = p[1]; qp_s[q][dg + 2] = p[2];
        }
        {
            int krow = tid >> 1, cg = (tid & 1) * 32;
            const float* p = proj + (size_t)rows_s[krow] * PROJW + OFFK + h * 64 + cg;
            #pragma unroll
            for (int u = 0; u < 4; ++u) {
                float4 v0 = *(const float4*)(p + u * 8);
                float4 v1 = *(const float4*)(p + u * 8 + 4);
                bf16x8 o;
                o[0]=(bf16_t)v0.x; o[1]=(bf16_t)v0.y; o[2]=(bf16_t)v0.z; o[3]=(bf16_t)v0.w;
                o[4]=(bf16_t)v1.x; o[5]=(bf16_t)v1.y; o[6]=(bf16_t)v1.z; o[7]=(bf16_t)v1.w;
                *(bf16x8*)&Ks[krow][cg + u * 8] = o;
            }
            const float* pk = proj + (size_t)rows_s[krow] * PROJW + OFFKVP + h * 36 + (tid & 1) * 6;
            int dg = (tid & 1) * 6;
            #pragma unroll
            for (int u = 0; u < 6; ++u) kp_s[krow][dg + u] = pk[u];
        }
        __syncthreads();
        // ---- Phase B: QK^T MFMA -> att (raw dots)
        {
            #pragma unroll
            for (int j = 0; j < 4; ++j) {
                int T = w * 4 + j;
                int m = T & 1, n = T >> 1;
                f32x4 acc = (f32x4){0.f,0.f,0.f,0.f};
                #pragma unroll
                for (int kc = 0; kc < 2; ++kc) {
                    bf16x8 a = *(const bf16x8*)&Qs[m*16 + (lane & 15)][kc*32 + (lane >> 4) * 8];
                    bf16x8 b = *(const bf16x8*)&Ks[n*16 + (lane & 15)][kc*32 + (lane >> 4) * 8];
                    acc = __builtin_amdgcn_mfma_f32_16x16x32_bf16(a, b, acc, 0, 0, 0);
                }
                #pragma unroll
                for (int i = 0; i < 4; ++i)
                    att[m*16 + (lane >> 4)*4 + i][n*16 + (lane & 15)] = acc[i];
            }
        }
        __syncthreads();
        // ---- Phase C: stage V^T + vpts^T (bf16, overwrites Qs/Ks) and f32 logit assembly
        {
            int krow = tid >> 1, cg = (tid & 1) * 32;
            const float* p = proj + (size_t)rows_s[krow] * PROJW + OFFV + h * 64 + cg;
            #pragma unroll
            for (int u = 0; u < 8; ++u) {
                float4 v = *(const float4*)(p + u * 4);
                Vt[cg + u*4 + 0][krow] = (bf16_t)v.x;
                Vt[cg + u*4 + 1][krow] = (bf16_t)v.y;
                Vt[cg + u*4 + 2][krow] = (bf16_t)v.z;
                Vt[cg + u*4 + 3][krow] = (bf16_t)v.w;
            }
            const float* pv = proj + (size_t)rows_s[krow] * PROJW + OFFKVP + h * 36 + 12 + (tid & 1) * 12;
            #pragma unroll
            for (int u = 0; u < 3; ++u) {
                float4 v = *(const float4*)(pv + u * 4);
                int rb = 64 + (tid & 1) * 12 + u * 4;
                Vt[rb + 0][krow] = (bf16_t)v.x;
                Vt[rb + 1][krow] = (bf16_t)v.y;
                Vt[rb + 2][krow] = (bf16_t)v.z;
                Vt[rb + 3][krow] = (bf16_t)v.w;
            }
            {   // zero-pad rows 88..95
                int r = 88 + (tid >> 5), c = (tid & 31) * 4;
                bf16x4 zz; zz[0]=(bf16_t)0.f; zz[1]=(bf16_t)0.f; zz[2]=(bf16_t)0.f; zz[3]=(bf16_t)0.f;
                *(bf16x4*)&Vt[r][c] = zz;
            }
            // logits
            int q = tid >> 3, kg = tid & 7;
            float qp[12];
            #pragma unroll
            for (int e = 0; e < 12; ++e) qp[e] = qp_s[q][e];
            float qm = qm_s[q];
            float hw = hws_s[it];
            const float* bT = biasT + ((size_t)(rowq0 + q) * 16 + h) * 128;
            #pragma unroll
            for (int j2 = 0; j2 < 16; ++j2) {
                int k = kg + j2 * 8;
                float4 k0 = *(const float4*)&kp_s[k][0];
                float4 k1 = *(const float4*)&kp_s[k][4];
                float4 k2 = *(const float4*)&kp_s[k][8];
                float d0 = qp[0]-k0.x, d1 = qp[1]-k0.y, d2_ = qp[2]-k0.z, d3 = qp[3]-k0.w;
                float d4 = qp[4]-k1.x, d5 = qp[5]-k1.y, d6 = qp[6]-k1.z, d7 = qp[7]-k1.w;
                float d8 = qp[8]-k2.x, d9 = qp[9]-k2.y, d10 = qp[10]-k2.z, d11 = qp[11]-k2.w;
                float dd = d0*d0+d1*d1+d2_*d2_+d3*d3+d4*d4+d5*d5+d6*d6+d7*d7+d8*d8+d9*d9+d10*d10+d11*d11;
                float val = att[q][k] * 0.07216878364870323f
                          + 0.5773502691896258f * bT[k]
                          + 100000.0f * (qm * km_s[k] - 1.0f)
                          - 0.5f * hw * dd;
                att[q][k] = val;
            }
        }
        __syncthreads();
        // ---- Phase D: softmax + P -> bf16 (LDS + global)
        {
            int q = tid >> 3, kg = tid & 7;
            float l[16];
            #pragma unroll
            for (int j2 = 0; j2 < 16; ++j2) l[j2] = att[q][kg + j2 * 8];
            float mx = l[0];
            #pragma unroll
            for (int j2 = 1; j2 < 16; ++j2) mx = fmaxf(mx, l[j2]);
            mx = fmaxf(mx, __shfl_xor(mx, 1));
            mx = fmaxf(mx, __shfl_xor(mx, 2));
            mx = fmaxf(mx, __shfl_xor(mx, 4));
            float se = 0.f;
            #pragma unroll
            for (int j2 = 0; j2 < 16; ++j2) { l[j2] = __expf(l[j2] - mx); se += l[j2]; }
            se += __shfl_xor(se, 1);
            se += __shfl_xor(se, 2);
            se += __shfl_xor(se, 4);
            float inv = 1.0f / se;
            bf16_t* pg = Pbf + ((size_t)(rowq0 + q) * 16 + h) * 128;
            #pragma unroll
            for (int j2 = 0; j2 < 16; ++j2) {
                bf16_t pb = (bf16_t)(l[j2] * inv);
                Ps[q][kg + j2 * 8] = pb;
                pg[kg + j2 * 8] = pb;
            }
        }
        __syncthreads();
        // ---- Phase E: PV MFMA (o cols 0..63, o_pt raw cols 64..87)
        {
            #pragma unroll
            for (int j = 0; j < 3; ++j) {
                int T = w * 3 + j;
                int m = T & 1, n = T >> 1;
                f32x4 acc = (f32x4){0.f,0.f,0.f,0.f};
                #pragma unroll
                for (int kc = 0; kc < 4; ++kc) {
                    bf16x8 a = *(const bf16x8*)&Ps[m*16 + (lane & 15)][kc*32 + (lane >> 4) * 8];
                    bf16x8 b = *(const bf16x8*)&Vt[n*16 + (lane & 15)][kc*32 + (lane >> 4) * 8];
                    acc = __builtin_amdgcn_mfma_f32_16x16x32_bf16(a, b, acc, 0, 0, 0);
                }
                int rowb = m * 16 + (lane >> 4) * 4;
                int col = lane & 15;
                if (n < 4) {
                    #pragma unroll
                    for (int i = 0; i < 4; ++i)
                        catb[(size_t)(rowq0 + rowb + i) * CATW + h * 64 + n * 16 + col] = (bf16_t)acc[i];
                } else {
                    #pragma unroll
                    for (int i = 0; i < 4; ++i)
                        optmp[rowb + i][(n - 4) * 16 + col] = acc[i];
                }
            }
        }
        __syncthreads();
        // ---- Phase F: o_pt inverse transform + norm
        {
            int q = tid >> 3, pp = tid & 7;
            float sx = optmp[q][pp * 3 + 0];
            float sy = optmp[q][pp * 3 + 1];
            float sz = optmp[q][pp * 3 + 2];
            const float* R = rots + (size_t)(rowq0 + q) * 9;
            const float* t = trans + (size_t)(rowq0 + q) * 3;
            float x = sx - t[0], y = sy - t[1], z2 = sz - t[2];
            float ox = R[0] * x + R[3] * y + R[6] * z2;
            float oy = R[1] * x + R[4] * y + R[7] * z2;
            float oz = R[2] * x + R[5] * y + R[8] * z2;
            bf16_t* cp = catb + (size_t)(rowq0 + q) * CATW;
            cp[1024 + h * 24 + pp * 3 + 0] = (bf16_t)ox;
            cp[1024 + h * 24 + pp * 3 + 1] = (bf16_t)oy;
            cp[1024 + h * 24 + pp * 3 + 2] = (bf16_t)oz;
            cp[1408 + h * 8 + pp] = (bf16_t)sqrtf(ox * ox + oy * oy + oz * oz + 1e-8f);
        }
    }
}

// ---------------------------------------------------------------- o_pair: per rowq MFMA [16h x 128k] x [128k x 32c]
__global__ __launch_bounds__(256) void k_opair(const bf16_t* __restrict__ Pbf,
    const bf16_t* __restrict__ pzT, bf16_t* __restrict__ catb)
{
    int tid = threadIdx.x, lane = tid & 63, w = tid >> 6;
    size_t rowq = (size_t)blockIdx.x * 4 + w;
    const bf16_t* Pp = Pbf + rowq * 2048;
    const bf16_t* zp = pzT + rowq * 4096;
    bf16x8 pa[4];
    #pragma unroll
    for (int kc = 0; kc < 4; ++kc)
        pa[kc] = *(const bf16x8*)(Pp + (size_t)(lane & 15) * 128 + kc * 32 + (lane >> 4) * 8);
    #pragma unroll
    for (int ct = 0; ct < 2; ++ct) {
        f32x4 acc = (f32x4){0.f,0.f,0.f,0.f};
        #pragma unroll
        for (int kc = 0; kc < 4; ++kc) {
            bf16x8 b = *(const bf16x8*)(zp + (size_t)(ct * 16 + (lane & 15)) * 128 + kc * 32 + (lane >> 4) * 8);
            acc = __builtin_amdgcn_mfma_f32_16x16x32_bf16(pa[kc], b, acc, 0, 0, 0);
        }
        #pragma unroll
        for (int i = 0; i < 4; ++i) {
            int hh = (lane >> 4) * 4 + i;
            catb[rowq * CATW + 1536 + hh * 32 + ct * 16 + (lane & 15)] = (bf16_t)acc[i];
        }
    }
}

// ---------------------------------------------------------------- launcher
extern "C" void kernel_launch(void* const* d_in, const int* in_sizes, int n_in,
                              void* d_out, int out_size, void* d_ws, size_t ws_size,
                              hipStream_t stream)
{
    (void)in_sizes; (void)n_in; (void)out_size;
    const float* s     = (const float*)d_in[0];
    const float* z     = (const float*)d_in[1];
    const float* trans = (const float*)d_in[2];
    const float* rots  = (const float*)d_in[3];
    const float* smask = (const float*)d_in[4];
    const int*   kidx  = (const int*)d_in[5];
    const float* Wq    = (const float*)d_in[6];
    const float* Wk    = (const float*)d_in[7];
    const float* Wv    = (const float*)d_in[8];
    const float* Wqp   = (const float*)d_in[9];
    const float* Wkvp  = (const float*)d_in[10];
    const float* Wb    = (const float*)d_in[11];
    const float* Wdz   = (const float*)d_in[12];
    const float* hw    = (const float*)d_in[13];
    const float* Wout  = (const float*)d_in[14];
    const float* g_s   = (const float*)d_in[15];
    const float* b_s   = (const float*)d_in[16];
    const float* g_z   = (const float*)d_in[17];
    const float* b_z   = (const float*)d_in[18];

    char* ws = (char*)d_ws;
    float*  proj  = (float*)(ws);                                  // 62,914,560 B
    float*  biasT = (float*)(ws + 70778880);                       // 33,554,432 B
    bf16_t* wcatT = (bf16_t*)(ws + 104333312);                     //  3,932,160 B
    bf16_t* s_nb  = (bf16_t*)(ws + 108265472);                     //  4,194,304 B
    bf16_t* pzT   = (bf16_t*)(ws + 112459776);                     // 33,554,432 B
    bf16_t* Pbf   = (bf16_t*)(ws + 146014208);                     // 16,777,216 B
    bf16_t* catb  = (bf16_t*)(ws + 162791424);                     // 16,777,216 B
    bf16_t* WoutT = (bf16_t*)(ws + 179568640);                     //  2,097,152 B
    bf16_t* WzT   = (bf16_t*)(ws + 181665792);                     //     12,288 B
    if (ws_size < (size_t)181678080) return;
    float* out = (float*)d_out;

    k_wcatT<<<dim3(60, 8), 256, 0, stream>>>(Wq, Wk, Wv, Wqp, Wkvp, wcatT);
    t_cvt<<<dim3(8, 32), 256, 0, stream>>>(Wout, WoutT, 2048, 512);
    k_wz<<<24, 256, 0, stream>>>(Wb, Wdz, WzT);
    k_ln_s<<<4096, 64, 0, stream>>>(s, g_s, b_s, s_nb);
    gemm_bf128<<<dim3(30, 32), 256, 0, stream>>>(s_nb, wcatT, proj, 4096, 3840, 512);
    k_rot<<<4096, 256, 0, stream>>>(proj, rots, trans);
    k_zbias2<<<2048, 256, 0, stream>>>(z, g_z, b_z, WzT, biasT, pzT);
    k_attn2<<<dim3(128, 4), 256, 0, stream>>>(proj, biasT, rots, trans, smask, kidx, hw, catb, Pbf);
    k_opair<<<1024, 256, 0, stream>>>(Pbf, pzT, catb);
    gemm_bf64<<<dim3(8, 32), 256, 0, stream>>>(catb, WoutT, out, 4096, 512, 2048);
}

// Round 4
// 237.308 us; speedup vs baseline: 4.6470x; 1.0533x over previous
//
#include <hip/hip_runtime.h>
#include <math.h>

#define D_N 4096
#define PBW 3072
#define PPW 768
#define OFFK 1024
#define OFFV 2048
#define CATW 2048

typedef __bf16 bf16_t;
typedef __bf16 bf16x8 __attribute__((ext_vector_type(8)));
typedef __bf16 bf16x4 __attribute__((ext_vector_type(4)));
typedef float f32x4 __attribute__((ext_vector_type(4)));

__device__ __forceinline__ void gld16(const void* g, void* l) {
    __builtin_amdgcn_global_load_lds((const __attribute__((address_space(1))) unsigned int*)g,
                                     (__attribute__((address_space(3))) unsigned int*)l, 16, 0, 0);
}

// ---------------------------------------------------------------- Wcat^T build: out bf16 [3840][512]
__global__ __launch_bounds__(256) void k_wcatT(const float* __restrict__ Wq, const float* __restrict__ Wk,
    const float* __restrict__ Wv, const float* __restrict__ Wqp, const float* __restrict__ Wkvp,
    bf16_t* __restrict__ out)
{
    __shared__ float T[64][65];
    int c0 = blockIdx.x * 64;
    int r0 = blockIdx.y * 64;
    const float* src; int ld, coff;
    if (c0 < 1024)      { src = Wq;   ld = 1024; coff = c0; }
    else if (c0 < 2048) { src = Wk;   ld = 1024; coff = c0 - 1024; }
    else if (c0 < 3072) { src = Wv;   ld = 1024; coff = c0 - 2048; }
    else if (c0 < 3264) { src = Wqp;  ld = 192;  coff = c0 - 3072; }
    else                { src = Wkvp; ld = 576;  coff = c0 - 3264; }
    int tid = threadIdx.x;
    {
        int rr = tid >> 2, cb = (tid & 3) * 16;
        const float* p = src + (size_t)(r0 + rr) * ld + coff + cb;
        #pragma unroll
        for (int i = 0; i < 4; ++i)
            *(float4*)&T[rr][cb + i * 4] = *(const float4*)(p + i * 4);
    }
    __syncthreads();
    {
        int cc = tid >> 2, rb = (tid & 3) * 16;
        bf16_t* o = out + (size_t)(c0 + cc) * 512 + r0 + rb;
        bf16x8 o0, o1;
        #pragma unroll
        for (int j = 0; j < 8; ++j) o0[j] = (bf16_t)T[rb + j][cc];
        #pragma unroll
        for (int j = 0; j < 8; ++j) o1[j] = (bf16_t)T[rb + 8 + j][cc];
        *(bf16x8*)(o) = o0;
        *(bf16x8*)(o + 8) = o1;
    }
}

// ---------------------------------------------------------------- transpose + cvt f32 [R][C] -> bf16 [C][R]
__global__ __launch_bounds__(256) void t_cvt(const float* __restrict__ in, bf16_t* __restrict__ out,
    int R, int C)
{
    __shared__ float T[64][65];
    int r0 = blockIdx.y * 64, c0 = blockIdx.x * 64;
    int tid = threadIdx.x;
    {
        int rr = tid >> 2;
        int cb = (tid & 3) * 16;
        const float* p = in + (size_t)(r0 + rr) * C + c0 + cb;
        #pragma unroll
        for (int i = 0; i < 4; ++i) {
            float4 v = *(const float4*)(p + i * 4);
            *(float4*)&T[rr][cb + i * 4] = v;
        }
    }
    __syncthreads();
    {
        int cc = tid >> 2;
        int rb = (tid & 3) * 16;
        bf16_t* o = out + (size_t)(c0 + cc) * R + r0 + rb;
        bf16x8 o0, o1;
        #pragma unroll
        for (int j = 0; j < 8; ++j) o0[j] = (bf16_t)T[rb + j][cc];
        #pragma unroll
        for (int j = 0; j < 8; ++j) o1[j] = (bf16_t)T[rb + 8 + j][cc];
        *(bf16x8*)(o) = o0;
        *(bf16x8*)(o + 8) = o1;
    }
}

// ---------------------------------------------------------------- WzT' = g_z-folded weights bf16 [48][128]; Kv[48] = b_z-fold
__global__ __launch_bounds__(256) void k_wz2(const float* __restrict__ Wb, const float* __restrict__ Wdz,
    const float* __restrict__ gz, const float* __restrict__ bz,
    bf16_t* __restrict__ WzT, float* __restrict__ Kv)
{
    int i = blockIdx.x * 256 + threadIdx.x;   // 6144 total
    if (i < 6144) {
        int j = i >> 7, c = i & 127;
        float w = (j < 16) ? Wb[c * 16 + j] : Wdz[c * 32 + (j - 16)];
        WzT[i] = (bf16_t)(gz[c] * w);
    }
    if (blockIdx.x == 0 && threadIdx.x < 48) {
        int j = threadIdx.x;
        float acc = 0.f;
        for (int c = 0; c < 128; ++c) {
            float w = (j < 16) ? Wb[c * 16 + j] : Wdz[c * 32 + (j - 16)];
            acc += bz[c] * w;
        }
        Kv[j] = acc;
    }
}

// ---------------------------------------------------------------- LN of s -> bf16
__global__ __launch_bounds__(64) void k_ln_s(const float* __restrict__ s, const float* __restrict__ g,
    const float* __restrict__ b, bf16_t* __restrict__ out)
{
    int row = blockIdx.x;
    int lane = threadIdx.x;
    const float4* p = (const float4*)(s + (size_t)row * 512);
    float4 v0 = p[lane];
    float4 v1 = p[lane + 64];
    float sum = v0.x + v0.y + v0.z + v0.w + v1.x + v1.y + v1.z + v1.w;
    float sq  = v0.x*v0.x + v0.y*v0.y + v0.z*v0.z + v0.w*v0.w
              + v1.x*v1.x + v1.y*v1.y + v1.z*v1.z + v1.w*v1.w;
    #pragma unroll
    for (int off = 1; off < 64; off <<= 1) {
        sum += __shfl_xor(sum, off);
        sq  += __shfl_xor(sq, off);
    }
    float m = sum * (1.0f / 512.0f);
    float var = sq * (1.0f / 512.0f) - m * m;
    float rs = rsqrtf(var + 1e-5f);
    int c = lane * 4;
    int c2 = 256 + lane * 4;
    bf16x4 r0, r1;
    r0[0] = (bf16_t)((v0.x - m) * rs * g[c+0] + b[c+0]);
    r0[1] = (bf16_t)((v0.y - m) * rs * g[c+1] + b[c+1]);
    r0[2] = (bf16_t)((v0.z - m) * rs * g[c+2] + b[c+2]);
    r0[3] = (bf16_t)((v0.w - m) * rs * g[c+3] + b[c+3]);
    r1[0] = (bf16_t)((v1.x - m) * rs * g[c2+0] + b[c2+0]);
    r1[1] = (bf16_t)((v1.y - m) * rs * g[c2+1] + b[c2+1]);
    r1[2] = (bf16_t)((v1.z - m) * rs * g[c2+2] + b[c2+2]);
    r1[3] = (bf16_t)((v1.w - m) * rs * g[c2+3] + b[c2+3]);
    *(bf16x4*)(out + (size_t)row * 512 + c)  = r0;
    *(bf16x4*)(out + (size_t)row * 512 + c2) = r1;
}

// ---------------------------------------------------------------- MFMA GEMM 128x128: proj split output (bf16 qkv / f32 pts)
__global__ __launch_bounds__(256) void gemm_proj(const bf16_t* __restrict__ A, const bf16_t* __restrict__ BT,
    bf16_t* __restrict__ projb, float* __restrict__ projp, int K)
{
    __shared__ bf16_t As[128][40];
    __shared__ bf16_t Bs[128][40];
    const int tid = threadIdx.x, lane = tid & 63, w = tid >> 6;
    const int row0 = blockIdx.y * 128, col0 = blockIdx.x * 128;
    const int wr = (w >> 1) * 64, wc = (w & 1) * 64;
    const int srow = tid >> 1, skoff = (tid & 1) * 16;
    const bf16_t* Ap = A + (size_t)(row0 + srow) * K + skoff;
    const bf16_t* Bp = BT + (size_t)(col0 + srow) * K + skoff;
    f32x4 acc[4][4];
    #pragma unroll
    for (int m = 0; m < 4; ++m)
        #pragma unroll
        for (int n = 0; n < 4; ++n) acc[m][n] = (f32x4){0.f,0.f,0.f,0.f};
    for (int k0 = 0; k0 < K; k0 += 32) {
        uint4 a0 = *(const uint4*)(Ap + k0);
        uint4 a1 = *(const uint4*)(Ap + k0 + 8);
        uint4 b0 = *(const uint4*)(Bp + k0);
        uint4 b1 = *(const uint4*)(Bp + k0 + 8);
        __syncthreads();
        *(uint4*)&As[srow][skoff]     = a0;
        *(uint4*)&As[srow][skoff + 8] = a1;
        *(uint4*)&Bs[srow][skoff]     = b0;
        *(uint4*)&Bs[srow][skoff + 8] = b1;
        __syncthreads();
        bf16x8 af[4], bfr[4];
        #pragma unroll
        for (int m = 0; m < 4; ++m) af[m]  = *(const bf16x8*)&As[wr + m*16 + (lane & 15)][(lane >> 4) * 8];
        #pragma unroll
        for (int n = 0; n < 4; ++n) bfr[n] = *(const bf16x8*)&Bs[wc + n*16 + (lane & 15)][(lane >> 4) * 8];
        #pragma unroll
        for (int m = 0; m < 4; ++m)
            #pragma unroll
            for (int n = 0; n < 4; ++n)
                acc[m][n] = __builtin_amdgcn_mfma_f32_16x16x32_bf16(af[m], bfr[n], acc[m][n], 0, 0, 0);
    }
    if (col0 < 3072) {
        #pragma unroll
        for (int m = 0; m < 4; ++m)
            #pragma unroll
            for (int n = 0; n < 4; ++n)
                #pragma unroll
                for (int i = 0; i < 4; ++i)
                    projb[(size_t)(row0 + wr + m*16 + (lane >> 4)*4 + i) * PBW + col0 + wc + n*16 + (lane & 15)]
                        = (bf16_t)acc[m][n][i];
    } else {
        #pragma unroll
        for (int m = 0; m < 4; ++m)
            #pragma unroll
            for (int n = 0; n < 4; ++n)
                #pragma unroll
                for (int i = 0; i < 4; ++i)
                    projp[(size_t)(row0 + wr + m*16 + (lane >> 4)*4 + i) * PPW + col0 - 3072 + wc + n*16 + (lane & 15)]
                        = acc[m][n][i];
    }
}

// ---------------------------------------------------------------- MFMA GEMM 128x64 (out GEMM)
__global__ __launch_bounds__(256) void gemm_bf64(const bf16_t* __restrict__ A, const bf16_t* __restrict__ BT,
    float* __restrict__ C, int M, int N, int K)
{
    __shared__ bf16_t As[128][40];
    __shared__ bf16_t Bs[64][40];
    const int tid = threadIdx.x, lane = tid & 63, w = tid >> 6;
    const int row0 = blockIdx.y * 128, col0 = blockIdx.x * 64;
    const int wr = w * 32;
    const int srow = tid >> 1, skoff = (tid & 1) * 16;
    const int brow = tid >> 2, bkoff = (tid & 3) * 8;
    const bf16_t* Ap = A + (size_t)(row0 + srow) * K + skoff;
    const bf16_t* Bp = BT + (size_t)(col0 + brow) * K + bkoff;
    f32x4 acc[2][4];
    #pragma unroll
    for (int m = 0; m < 2; ++m)
        #pragma unroll
        for (int n = 0; n < 4; ++n) acc[m][n] = (f32x4){0.f,0.f,0.f,0.f};
    for (int k0 = 0; k0 < K; k0 += 32) {
        uint4 a0 = *(const uint4*)(Ap + k0);
        uint4 a1 = *(const uint4*)(Ap + k0 + 8);
        uint4 b0 = *(const uint4*)(Bp + k0);
        __syncthreads();
        *(uint4*)&As[srow][skoff]     = a0;
        *(uint4*)&As[srow][skoff + 8] = a1;
        *(uint4*)&Bs[brow][bkoff]     = b0;
        __syncthreads();
        bf16x8 af[2], bfr[4];
        #pragma unroll
        for (int m = 0; m < 2; ++m) af[m]  = *(const bf16x8*)&As[wr + m*16 + (lane & 15)][(lane >> 4) * 8];
        #pragma unroll
        for (int n = 0; n < 4; ++n) bfr[n] = *(const bf16x8*)&Bs[n*16 + (lane & 15)][(lane >> 4) * 8];
        #pragma unroll
        for (int m = 0; m < 2; ++m)
            #pragma unroll
            for (int n = 0; n < 4; ++n)
                acc[m][n] = __builtin_amdgcn_mfma_f32_16x16x32_bf16(af[m], bfr[n], acc[m][n], 0, 0, 0);
    }
    #pragma unroll
    for (int m = 0; m < 2; ++m)
        #pragma unroll
        for (int n = 0; n < 4; ++n)
            #pragma unroll
            for (int i = 0; i < 4; ++i)
                C[(size_t)(row0 + wr + m*16 + (lane >> 4)*4 + i) * N + col0 + n*16 + (lane & 15)] = acc[m][n][i];
}

// ---------------------------------------------------------------- rotate+translate projected points (projp in place)
__global__ __launch_bounds__(256) void k_rot(float* __restrict__ projp, const float* __restrict__ rots,
    const float* __restrict__ trans)
{
    int row = blockIdx.x;
    int tid = threadIdx.x;
    const float* R = rots + (size_t)row * 9;
    const float* t = trans + (size_t)row * 3;
    float* base = projp + (size_t)row * PPW + tid * 3;
    float x = base[0], y = base[1], z = base[2];
    base[0] = R[0] * x + R[1] * y + R[2] * z + t[0];
    base[1] = R[3] * x + R[4] * y + R[5] * z + t[1];
    base[2] = R[6] * x + R[7] * y + R[8] * z + t[2];
}

// ---------------------------------------------------------------- z LN + projection, global_load_lds pipelined
// grid 2048 x 256; each wave: 4 contiguous 16-row tiles, per-wave dbuf, no barriers
__global__ __launch_bounds__(256) void k_zbias3(const float* __restrict__ z,
    const bf16_t* __restrict__ WzT, const float* __restrict__ Kv,
    float* __restrict__ biasT, bf16_t* __restrict__ pzT)
{
    __shared__ __align__(16) float zbuf[2][64][128];
    const int tid = threadIdx.x, lane = tid & 63, w = tid >> 6;
    const int r16 = lane & 15, kg = lane >> 4;
    bf16x8 bfz[3][4];
    #pragma unroll
    for (int nt = 0; nt < 3; ++nt)
        #pragma unroll
        for (int kc = 0; kc < 4; ++kc)
            bfz[nt][kc] = *(const bf16x8*)(WzT + (size_t)(nt * 16 + r16) * 128 + kc * 32 + kg * 8);
    float K0 = Kv[r16], K1 = Kv[16 + r16], K2 = Kv[32 + r16];
    asm volatile("s_waitcnt vmcnt(0)" ::: "memory");

    const int gid = blockIdx.x * 4 + w;
    const char* zb = (const char*)z + (size_t)gid * 64 * 512;
    char* lb0 = (char*)&zbuf[0][w * 16][0];
    char* lb1 = (char*)&zbuf[1][w * 16][0];

#define STAGE(i, lb) { \
    const char* gp_ = zb + (size_t)(i) * 8192 + lane * 16; \
    _Pragma("unroll") \
    for (int c_ = 0; c_ < 8; ++c_) gld16(gp_ + c_ * 1024, (lb) + c_ * 1024); }

#define PROCESS(i, b) { \
    const float* rp = &zbuf[b][w * 16 + r16][kg * 8]; \
    float4 za[4], zc[4]; \
    float sum = 0.f, sq = 0.f; \
    _Pragma("unroll") \
    for (int kc = 0; kc < 4; ++kc) { \
        float4 a_ = *(const float4*)(rp + kc * 32); \
        float4 b_ = *(const float4*)(rp + kc * 32 + 4); \
        za[kc] = a_; zc[kc] = b_; \
        sum += a_.x + a_.y + a_.z + a_.w + b_.x + b_.y + b_.z + b_.w; \
        sq  += a_.x*a_.x + a_.y*a_.y + a_.z*a_.z + a_.w*a_.w + b_.x*b_.x + b_.y*b_.y + b_.z*b_.z + b_.w*b_.w; \
    } \
    sum += __shfl_xor(sum, 16); sq += __shfl_xor(sq, 16); \
    sum += __shfl_xor(sum, 32); sq += __shfl_xor(sq, 32); \
    float m_ = sum * (1.0f / 128.0f); \
    float rs_ = rsqrtf(sq * (1.0f / 128.0f) - m_ * m_ + 1e-5f); \
    bf16x8 af[4]; \
    _Pragma("unroll") \
    for (int kc = 0; kc < 4; ++kc) { \
        af[kc][0] = (bf16_t)((za[kc].x - m_) * rs_); \
        af[kc][1] = (bf16_t)((za[kc].y - m_) * rs_); \
        af[kc][2] = (bf16_t)((za[kc].z - m_) * rs_); \
        af[kc][3] = (bf16_t)((za[kc].w - m_) * rs_); \
        af[kc][4] = (bf16_t)((zc[kc].x - m_) * rs_); \
        af[kc][5] = (bf16_t)((zc[kc].y - m_) * rs_); \
        af[kc][6] = (bf16_t)((zc[kc].z - m_) * rs_); \
        af[kc][7] = (bf16_t)((zc[kc].w - m_) * rs_); \
    } \
    f32x4 acc0 = (f32x4){0.f,0.f,0.f,0.f}; \
    f32x4 acc1 = (f32x4){0.f,0.f,0.f,0.f}; \
    f32x4 acc2 = (f32x4){0.f,0.f,0.f,0.f}; \
    _Pragma("unroll") \
    for (int kc = 0; kc < 4; ++kc) { \
        acc0 = __builtin_amdgcn_mfma_f32_16x16x32_bf16(af[kc], bfz[0][kc], acc0, 0, 0, 0); \
        acc1 = __builtin_amdgcn_mfma_f32_16x16x32_bf16(af[kc], bfz[1][kc], acc1, 0, 0, 0); \
        acc2 = __builtin_amdgcn_mfma_f32_16x16x32_bf16(af[kc], bfz[2][kc], acc2, 0, 0, 0); \
    } \
    const int t_ = gid * 4 + (i); \
    const int rowq_ = t_ >> 3; \
    const int k0_ = ((t_ & 7) << 4) + kg * 4; \
    float4 bw = {acc0[0] + K0, acc0[1] + K0, acc0[2] + K0, acc0[3] + K0}; \
    *(float4*)&biasT[((size_t)rowq_ * 16 + r16) * 128 + k0_] = bw; \
    bf16x4 p1, p2; \
    _Pragma("unroll") \
    for (int i2 = 0; i2 < 4; ++i2) { p1[i2] = (bf16_t)(acc1[i2] + K1); p2[i2] = (bf16_t)(acc2[i2] + K2); } \
    *(bf16x4*)&pzT[((size_t)rowq_ * 32 + r16) * 128 + k0_] = p1; \
    *(bf16x4*)&pzT[((size_t)rowq_ * 32 + 16 + r16) * 128 + k0_] = p2; }

    STAGE(0, lb0);
    STAGE(1, lb1);
    asm volatile("s_waitcnt vmcnt(8)" ::: "memory");
    PROCESS(0, 0);
    STAGE(2, lb0);
    asm volatile("s_waitcnt vmcnt(11)" ::: "memory");
    PROCESS(1, 1);
    STAGE(3, lb1);
    asm volatile("s_waitcnt vmcnt(11)" ::: "memory");
    PROCESS(2, 0);
    asm volatile("s_waitcnt vmcnt(3)" ::: "memory");
    PROCESS(3, 1);
#undef STAGE
#undef PROCESS
}

// ---------------------------------------------------------------- attention: one wg per (nblk, head)
__global__ __launch_bounds__(256) void k_attn3(
    const bf16_t* __restrict__ projb, const float* __restrict__ projp,
    const float* __restrict__ biasT, const float* __restrict__ rots,
    const float* __restrict__ trans, const float* __restrict__ smask,
    const int* __restrict__ kidx, const float* __restrict__ hwraw,
    bf16_t* __restrict__ catb, bf16_t* __restrict__ Pbf)
{
    __shared__ __align__(16) char uni[26112];          // Qs[32][72]b + Ks[128][72]b  OR  Vt[96][136]b
    __shared__ float att[32][132];
    __shared__ float kp_s[128][12];
    __shared__ float qp_s[32][12];
    __shared__ bf16_t Ps[32][136];
    __shared__ float optmp[32][33];
    __shared__ float km_s[128];
    __shared__ float qm_s[32];
    __shared__ int   rows_s[128];

    bf16_t (*Qs)[72]  = (bf16_t(*)[72])uni;
    bf16_t (*Ks)[72]  = (bf16_t(*)[72])(uni + 32 * 72 * 2);
    bf16_t (*Vt)[136] = (bf16_t(*)[136])uni;

    const int nblk = blockIdx.x;
    const int h = blockIdx.y;
    const int tid = threadIdx.x;
    const int lane = tid & 63;
    const int w = tid >> 6;
    const int rowq0 = nblk * 32;
    const float hw = log1pf(__expf(hwraw[h])) * 0.13608276348795434f;

    if (tid < 128) {
        int ki = kidx[nblk * 128 + tid];
        int valid = (ki >= 0 && ki < D_N);
        int rr = ki < 0 ? 0 : (ki > D_N - 1 ? D_N - 1 : ki);
        rows_s[tid] = rr;
        km_s[tid] = valid ? smask[rr] : 0.0f;
    } else if (tid < 160) {
        qm_s[tid - 128] = smask[rowq0 + tid - 128];
    }
    __syncthreads();
    // ---- Phase A: stage Q, qp, K, kp
    {
        int q = tid >> 3, cg = (tid & 7) * 8;
        *(bf16x8*)&Qs[q][cg] = *(const bf16x8*)(projb + (size_t)(rowq0 + q) * PBW + h * 64 + cg);
    }
    if (tid < 128) {
        int q = tid >> 2, dg = (tid & 3) * 3;
        const float* p = projp + (size_t)(rowq0 + q) * PPW + h * 12 + dg;
        qp_s[q][dg + 0] = p[0]; qp_s[q][dg + 1] = p[1]; qp_s[q][dg + 2] = p[2];
    }
    {
        int krow = tid >> 1, cg = (tid & 1) * 32;
        const bf16_t* p = projb + (size_t)rows_s[krow] * PBW + OFFK + h * 64 + cg;
        #pragma unroll
        for (int u = 0; u < 4; ++u)
            *(bf16x8*)&Ks[krow][cg + u * 8] = *(const bf16x8*)(p + u * 8);
        const float* pk = projp + (size_t)rows_s[krow] * PPW + 192 + h * 36 + (tid & 1) * 6;
        int dg = (tid & 1) * 6;
        #pragma unroll
        for (int u = 0; u < 6; ++u) kp_s[krow][dg + u] = pk[u];
    }
    __syncthreads();
    // ---- Phase B: QK^T MFMA
    {
        #pragma unroll
        for (int j = 0; j < 4; ++j) {
            int T = w * 4 + j;
            int m = T & 1, n = T >> 1;
            f32x4 acc = (f32x4){0.f,0.f,0.f,0.f};
            #pragma unroll
            for (int kc = 0; kc < 2; ++kc) {
                bf16x8 a = *(const bf16x8*)&Qs[m*16 + (lane & 15)][kc*32 + (lane >> 4) * 8];
                bf16x8 b = *(const bf16x8*)&Ks[n*16 + (lane & 15)][kc*32 + (lane >> 4) * 8];
                acc = __builtin_amdgcn_mfma_f32_16x16x32_bf16(a, b, acc, 0, 0, 0);
            }
            #pragma unroll
            for (int i = 0; i < 4; ++i)
                att[m*16 + (lane >> 4)*4 + i][n*16 + (lane & 15)] = acc[i];
        }
    }
    __syncthreads();
    // ---- Phase C: stage V^T + vpts^T (overwrites Qs/Ks) and f32 logit assembly
    {
        int krow = tid >> 1, cg = (tid & 1) * 32;
        const bf16_t* p = projb + (size_t)rows_s[krow] * PBW + OFFV + h * 64 + cg;
        #pragma unroll
        for (int u4 = 0; u4 < 4; ++u4) {
            bf16x8 v = *(const bf16x8*)(p + u4 * 8);
            #pragma unroll
            for (int j = 0; j < 8; ++j) Vt[cg + u4 * 8 + j][krow] = v[j];
        }
        const float* pv = projp + (size_t)rows_s[krow] * PPW + 192 + h * 36 + 12 + (tid & 1) * 12;
        #pragma unroll
        for (int u = 0; u < 3; ++u) {
            float4 v = *(const float4*)(pv + u * 4);
            int rb = 64 + (tid & 1) * 12 + u * 4;
            Vt[rb + 0][krow] = (bf16_t)v.x;
            Vt[rb + 1][krow] = (bf16_t)v.y;
            Vt[rb + 2][krow] = (bf16_t)v.z;
            Vt[rb + 3][krow] = (bf16_t)v.w;
        }
        {   // zero-pad rows 88..95
            int r = 88 + (tid >> 5), c = (tid & 31) * 4;
            bf16x4 zz; zz[0]=(bf16_t)0.f; zz[1]=(bf16_t)0.f; zz[2]=(bf16_t)0.f; zz[3]=(bf16_t)0.f;
            *(bf16x4*)&Vt[r][c] = zz;
        }
        // logits
        int q = tid >> 3, kg = tid & 7;
        float qp[12];
        #pragma unroll
        for (int e = 0; e < 12; ++e) qp[e] = qp_s[q][e];
        float qm = qm_s[q];
        const float* bT = biasT + ((size_t)(rowq0 + q) * 16 + h) * 128;
        #pragma unroll
        for (int j2 = 0; j2 < 16; ++j2) {
            int k = kg + j2 * 8;
            float4 k0 = *(const float4*)&kp_s[k][0];
            float4 k1 = *(const float4*)&kp_s[k][4];
            float4 k2 = *(const float4*)&kp_s[k][8];
            float d0 = qp[0]-k0.x, d1 = qp[1]-k0.y, d2_ = qp[2]-k0.z, d3 = qp[3]-k0.w;
            float d4 = qp[4]-k1.x, d5 = qp[5]-k1.y, d6 = qp[6]-k1.z, d7 = qp[7]-k1.w;
            float d8 = qp[8]-k2.x, d9 = qp[9]-k2.y, d10 = qp[10]-k2.z, d11 = qp[11]-k2.w;
            float dd = d0*d0+d1*d1+d2_*d2_+d3*d3+d4*d4+d5*d5+d6*d6+d7*d7+d8*d8+d9*d9+d10*d10+d11*d11;
            float val = att[q][k] * 0.07216878364870323f
                      + 0.5773502691896258f * bT[k]
                      + 100000.0f * (qm * km_s[k] - 1.0f)
                      - 0.5f * hw * dd;
            att[q][k] = val;
        }
    }
    __syncthreads();
    // ---- Phase D: softmax + P -> bf16
    {
        int q = tid >> 3, kg = tid & 7;
        float l[16];
        #pragma unroll
        for (int j2 = 0; j2 < 16; ++j2) l[j2] = att[q][kg + j2 * 8];
        float mx = l[0];
        #pragma unroll
        for (int j2 = 1; j2 < 16; ++j2) mx = fmaxf(mx, l[j2]);
        mx = fmaxf(mx, __shfl_xor(mx, 1));
        mx = fmaxf(mx, __shfl_xor(mx, 2));
        mx = fmaxf(mx, __shfl_xor(mx, 4));
        float se = 0.f;
        #pragma unroll
        for (int j2 = 0; j2 < 16; ++j2) { l[j2] = __expf(l[j2] - mx); se += l[j2]; }
        se += __shfl_xor(se, 1);
        se += __shfl_xor(se, 2);
        se += __shfl_xor(se, 4);
        float inv = 1.0f / se;
        bf16_t* pg = Pbf + ((size_t)(rowq0 + q) * 16 + h) * 128;
        #pragma unroll
        for (int j2 = 0; j2 < 16; ++j2) {
            bf16_t pb = (bf16_t)(l[j2] * inv);
            Ps[q][kg + j2 * 8] = pb;
            pg[kg + j2 * 8] = pb;
        }
    }
    __syncthreads();
    // ---- Phase E: PV MFMA
    {
        #pragma unroll
        for (int j = 0; j < 3; ++j) {
            int T = w * 3 + j;
            int m = T & 1, n = T >> 1;
            f32x4 acc = (f32x4){0.f,0.f,0.f,0.f};
            #pragma unroll
            for (int kc = 0; kc < 4; ++kc) {
                bf16x8 a = *(const bf16x8*)&Ps[m*16 + (lane & 15)][kc*32 + (lane >> 4) * 8];
                bf16x8 b = *(const bf16x8*)&Vt[n*16 + (lane & 15)][kc*32 + (lane >> 4) * 8];
                acc = __builtin_amdgcn_mfma_f32_16x16x32_bf16(a, b, acc, 0, 0, 0);
            }
            int rowb = m * 16 + (lane >> 4) * 4;
            int col = lane & 15;
            if (n < 4) {
                #pragma unroll
                for (int i = 0; i < 4; ++i)
                    catb[(size_t)(rowq0 + rowb + i) * CATW + h * 64 + n * 16 + col] = (bf16_t)acc[i];
            } else {
                #pragma unroll
                for (int i = 0; i < 4; ++i)
                    optmp[rowb + i][(n - 4) * 16 + col] = acc[i];
            }
        }
    }
    __syncthreads();
    // ---- Phase F: o_pt inverse transform + norm
    {
        int q = tid >> 3, pp = tid & 7;
        float sx = optmp[q][pp * 3 + 0];
        float sy = optmp[q][pp * 3 + 1];
        float sz = optmp[q][pp * 3 + 2];
        const float* R = rots + (size_t)(rowq0 + q) * 9;
        const float* t = trans + (size_t)(rowq0 + q) * 3;
        float x = sx - t[0], y = sy - t[1], z2 = sz - t[2];
        float ox = R[0] * x + R[3] * y + R[6] * z2;
        float oy = R[1] * x + R[4] * y + R[7] * z2;
        float oz = R[2] * x + R[5] * y + R[8] * z2;
        bf16_t* cp = catb + (size_t)(rowq0 + q) * CATW;
        cp[1024 + h * 24 + pp * 3 + 0] = (bf16_t)ox;
        cp[1024 + h * 24 + pp * 3 + 1] = (bf16_t)oy;
        cp[1024 + h * 24 + pp * 3 + 2] = (bf16_t)oz;
        cp[1408 + h * 8 + pp] = (bf16_t)sqrtf(ox * ox + oy * oy + oz * oz + 1e-8f);
    }
}

// ---------------------------------------------------------------- o_pair: per rowq MFMA [16h x 128k] x [128k x 32c]
__global__ __launch_bounds__(256) void k_opair(const bf16_t* __restrict__ Pbf,
    const bf16_t* __restrict__ pzT, bf16_t* __restrict__ catb)
{
    int tid = threadIdx.x, lane = tid & 63, w = tid >> 6;
    size_t rowq = (size_t)blockIdx.x * 4 + w;
    const bf16_t* Pp = Pbf + rowq * 2048;
    const bf16_t* zp = pzT + rowq * 4096;
    bf16x8 pa[4];
    #pragma unroll
    for (int kc = 0; kc < 4; ++kc)
        pa[kc] = *(const bf16x8*)(Pp + (size_t)(lane & 15) * 128 + kc * 32 + (lane >> 4) * 8);
    #pragma unroll
    for (int ct = 0; ct < 2; ++ct) {
        f32x4 acc = (f32x4){0.f,0.f,0.f,0.f};
        #pragma unroll
        for (int kc = 0; kc < 4; ++kc) {
            bf16x8 b = *(const bf16x8*)(zp + (size_t)(ct * 16 + (lane & 15)) * 128 + kc * 32 + (lane >> 4) * 8);
            acc = __builtin_amdgcn_mfma_f32_16x16x32_bf16(pa[kc], b, acc, 0, 0, 0);
        }
        #pragma unroll
        for (int i = 0; i < 4; ++i) {
            int hh = (lane >> 4) * 4 + i;
            catb[rowq * CATW + 1536 + hh * 32 + ct * 16 + (lane & 15)] = (bf16_t)acc[i];
        }
    }
}

// ---------------------------------------------------------------- launcher
extern "C" void kernel_launch(void* const* d_in, const int* in_sizes, int n_in,
                              void* d_out, int out_size, void* d_ws, size_t ws_size,
                              hipStream_t stream)
{
    (void)in_sizes; (void)n_in; (void)out_size;
    const float* s     = (const float*)d_in[0];
    const float* z     = (const float*)d_in[1];
    const float* trans = (const float*)d_in[2];
    const float* rots  = (const float*)d_in[3];
    const float* smask = (const float*)d_in[4];
    const int*   kidx  = (const int*)d_in[5];
    const float* Wq    = (const float*)d_in[6];
    const float* Wk    = (const float*)d_in[7];
    const float* Wv    = (const float*)d_in[8];
    const float* Wqp   = (const float*)d_in[9];
    const float* Wkvp  = (const float*)d_in[10];
    const float* Wb    = (const float*)d_in[11];
    const float* Wdz   = (const float*)d_in[12];
    const float* hw    = (const float*)d_in[13];
    const float* Wout  = (const float*)d_in[14];
    const float* g_s   = (const float*)d_in[15];
    const float* b_s   = (const float*)d_in[16];
    const float* g_z   = (const float*)d_in[17];
    const float* b_z   = (const float*)d_in[18];

    char* ws = (char*)d_ws;
    bf16_t* projb = (bf16_t*)(ws);                      // 25,165,824
    float*  projp = (float*)(ws + 25165824);            // 12,582,912
    float*  biasT = (float*)(ws + 37748736);            // 33,554,432
    bf16_t* wcatT = (bf16_t*)(ws + 71303168);           //  3,932,160
    bf16_t* s_nb  = (bf16_t*)(ws + 75235328);           //  4,194,304
    bf16_t* pzT   = (bf16_t*)(ws + 79429632);           // 33,554,432
    bf16_t* Pbf   = (bf16_t*)(ws + 112984064);          // 16,777,216
    bf16_t* catb  = (bf16_t*)(ws + 129761280);          // 16,777,216
    bf16_t* WoutT = (bf16_t*)(ws + 146538496);          //  2,097,152
    bf16_t* WzT   = (bf16_t*)(ws + 148635648);          //     12,288
    float*  Kv    = (float*)(ws + 148647936);           //        192
    if (ws_size < (size_t)148648128) return;
    float* out = (float*)d_out;

    k_wcatT<<<dim3(60, 8), 256, 0, stream>>>(Wq, Wk, Wv, Wqp, Wkvp, wcatT);
    t_cvt<<<dim3(8, 32), 256, 0, stream>>>(Wout, WoutT, 2048, 512);
    k_wz2<<<24, 256, 0, stream>>>(Wb, Wdz, g_z, b_z, WzT, Kv);
    k_ln_s<<<4096, 64, 0, stream>>>(s, g_s, b_s, s_nb);
    gemm_proj<<<dim3(30, 32), 256, 0, stream>>>(s_nb, wcatT, projb, projp, 512);
    k_rot<<<4096, 256, 0, stream>>>(projp, rots, trans);
    k_zbias3<<<2048, 256, 0, stream>>>(z, WzT, Kv, biasT, pzT);
    k_attn3<<<dim3(128, 16), 256, 0, stream>>>(projb, projp, biasT, rots, trans, smask, kidx, hw, catb, Pbf);
    k_opair<<<1024, 256, 0, stream>>>(Pbf, pzT, catb);
    gemm_bf64<<<dim3(8, 32), 256, 0, stream>>>(catb, WoutT, out, 4096, 512, 2048);
}

// Round 5
// 230.775 us; speedup vs baseline: 4.7786x; 1.0283x over previous
//
#include <hip/hip_runtime.h>
#include <math.h>

#define D_N 4096
#define PBW 3072
#define PPW 768
#define OFFK 1024
#define OFFV 2048
#define CATW 2048

typedef __bf16 bf16_t;
typedef __bf16 bf16x8 __attribute__((ext_vector_type(8)));
typedef __bf16 bf16x4 __attribute__((ext_vector_type(4)));
typedef float f32x4 __attribute__((ext_vector_type(4)));

__device__ __forceinline__ void gld16(const void* g, void* l) {
    __builtin_amdgcn_global_load_lds((const __attribute__((address_space(1))) unsigned int*)g,
                                     (__attribute__((address_space(3))) unsigned int*)l, 16, 0, 0);
}

// ---------------------------------------------------------------- merged prep:
// blocks [0,480): wcatT ; [480,736): WoutT ; 736: WzT+Kv ; [737,1761): ln_s
__global__ __launch_bounds__(256) void k_prep(
    const float* __restrict__ Wq, const float* __restrict__ Wk, const float* __restrict__ Wv,
    const float* __restrict__ Wqp, const float* __restrict__ Wkvp, const float* __restrict__ Wout,
    const float* __restrict__ Wb, const float* __restrict__ Wdz,
    const float* __restrict__ gz, const float* __restrict__ bz,
    const float* __restrict__ s, const float* __restrict__ g_s, const float* __restrict__ b_s,
    bf16_t* __restrict__ wcatT, bf16_t* __restrict__ WoutT,
    bf16_t* __restrict__ WzT, float* __restrict__ Kv, bf16_t* __restrict__ s_nb)
{
    __shared__ float T[64][65];
    const int bx = blockIdx.x;
    const int tid = threadIdx.x;
    if (bx < 736) {
        // transpose+cvt of one 64x64 tile
        const float* src; int ld, coff, r0;
        bf16_t* dst; int Rdst;
        if (bx < 480) {
            int c0 = (bx % 60) * 64;
            r0 = (bx / 60) * 64;
            if (c0 < 1024)      { src = Wq;   ld = 1024; coff = c0; }
            else if (c0 < 2048) { src = Wk;   ld = 1024; coff = c0 - 1024; }
            else if (c0 < 3072) { src = Wv;   ld = 1024; coff = c0 - 2048; }
            else if (c0 < 3264) { src = Wqp;  ld = 192;  coff = c0 - 3072; }
            else                { src = Wkvp; ld = 576;  coff = c0 - 3264; }
            dst = wcatT + (size_t)c0 * 512; Rdst = 512;
        } else {
            int b = bx - 480;
            int c0 = (b & 7) * 64;
            r0 = (b >> 3) * 64;
            src = Wout; ld = 512; coff = c0;
            dst = WoutT + (size_t)c0 * 2048; Rdst = 2048;
        }
        {
            int rr = tid >> 2, cb = (tid & 3) * 16;
            const float* p = src + (size_t)(r0 + rr) * ld + coff + cb;
            #pragma unroll
            for (int i = 0; i < 4; ++i)
                *(float4*)&T[rr][cb + i * 4] = *(const float4*)(p + i * 4);
        }
        __syncthreads();
        {
            int cc = tid >> 2, rb = (tid & 3) * 16;
            bf16_t* o = dst + (size_t)cc * Rdst + r0 + rb;
            bf16x8 o0, o1;
            #pragma unroll
            for (int j = 0; j < 8; ++j) o0[j] = (bf16_t)T[rb + j][cc];
            #pragma unroll
            for (int j = 0; j < 8; ++j) o1[j] = (bf16_t)T[rb + 8 + j][cc];
            *(bf16x8*)(o) = o0;
            *(bf16x8*)(o + 8) = o1;
        }
    } else if (bx == 736) {
        for (int i = tid; i < 6144; i += 256) {
            int j = i >> 7, c = i & 127;
            float w = (j < 16) ? Wb[c * 16 + j] : Wdz[c * 32 + (j - 16)];
            WzT[i] = (bf16_t)(gz[c] * w);
        }
        if (tid < 48) {
            int j = tid;
            float acc = 0.f;
            for (int c = 0; c < 128; ++c) {
                float w = (j < 16) ? Wb[c * 16 + j] : Wdz[c * 32 + (j - 16)];
                acc += bz[c] * w;
            }
            Kv[j] = acc;
        }
    } else {
        int row = (bx - 737) * 4 + (tid >> 6);
        int lane = tid & 63;
        const float4* p = (const float4*)(s + (size_t)row * 512);
        float4 v0 = p[lane];
        float4 v1 = p[lane + 64];
        float sum = v0.x + v0.y + v0.z + v0.w + v1.x + v1.y + v1.z + v1.w;
        float sq  = v0.x*v0.x + v0.y*v0.y + v0.z*v0.z + v0.w*v0.w
                  + v1.x*v1.x + v1.y*v1.y + v1.z*v1.z + v1.w*v1.w;
        #pragma unroll
        for (int off = 1; off < 64; off <<= 1) {
            sum += __shfl_xor(sum, off);
            sq  += __shfl_xor(sq, off);
        }
        float m = sum * (1.0f / 512.0f);
        float var = sq * (1.0f / 512.0f) - m * m;
        float rs = rsqrtf(var + 1e-5f);
        int c = lane * 4;
        int c2 = 256 + lane * 4;
        bf16x4 r0, r1;
        r0[0] = (bf16_t)((v0.x - m) * rs * g_s[c+0] + b_s[c+0]);
        r0[1] = (bf16_t)((v0.y - m) * rs * g_s[c+1] + b_s[c+1]);
        r0[2] = (bf16_t)((v0.z - m) * rs * g_s[c+2] + b_s[c+2]);
        r0[3] = (bf16_t)((v0.w - m) * rs * g_s[c+3] + b_s[c+3]);
        r1[0] = (bf16_t)((v1.x - m) * rs * g_s[c2+0] + b_s[c2+0]);
        r1[1] = (bf16_t)((v1.y - m) * rs * g_s[c2+1] + b_s[c2+1]);
        r1[2] = (bf16_t)((v1.z - m) * rs * g_s[c2+2] + b_s[c2+2]);
        r1[3] = (bf16_t)((v1.w - m) * rs * g_s[c2+3] + b_s[c2+3]);
        *(bf16x4*)(s_nb + (size_t)row * 512 + c)  = r0;
        *(bf16x4*)(s_nb + (size_t)row * 512 + c2) = r1;
    }
}

// ---------------------------------------------------------------- proj GEMM, gld16 staging (m97 structure)
// C[4096 x 3840] = A[4096 x 512] * BT[3840 x 512]^T ; split outputs
__global__ __launch_bounds__(256) void gemm_proj(const bf16_t* __restrict__ A, const bf16_t* __restrict__ BT,
    bf16_t* __restrict__ projb, float* __restrict__ projp)
{
    __shared__ bf16_t Asl[128][32];
    __shared__ bf16_t Bsl[128][32];
    const int tid = threadIdx.x, lane = tid & 63, w = tid >> 6;
    const int row0 = blockIdx.y * 128, col0 = blockIdx.x * 128;
    const int wr = (w >> 1) * 64, wc = (w & 1) * 64;
    const int K = 512;
    const int sr = lane >> 2, k8 = (lane & 3) * 8;
    const bf16_t* Ab = A + (size_t)(row0 + w * 32 + sr) * K + k8;
    const bf16_t* Bb = BT + (size_t)(col0 + w * 32 + sr) * K + k8;
    f32x4 acc[4][4];
    #pragma unroll
    for (int m = 0; m < 4; ++m)
        #pragma unroll
        for (int n = 0; n < 4; ++n) acc[m][n] = (f32x4){0.f,0.f,0.f,0.f};
    for (int k0 = 0; k0 < K; k0 += 32) {
        __syncthreads();
        gld16(Ab + k0,          &Asl[w * 32][0]);
        gld16(Ab + k0 + 16 * K, &Asl[w * 32 + 16][0]);
        gld16(Bb + k0,          &Bsl[w * 32][0]);
        gld16(Bb + k0 + 16 * K, &Bsl[w * 32 + 16][0]);
        __syncthreads();
        bf16x8 af[4], bfr[4];
        #pragma unroll
        for (int m = 0; m < 4; ++m) af[m]  = *(const bf16x8*)&Asl[wr + m*16 + (lane & 15)][(lane >> 4) * 8];
        #pragma unroll
        for (int n = 0; n < 4; ++n) bfr[n] = *(const bf16x8*)&Bsl[wc + n*16 + (lane & 15)][(lane >> 4) * 8];
        #pragma unroll
        for (int m = 0; m < 4; ++m)
            #pragma unroll
            for (int n = 0; n < 4; ++n)
                acc[m][n] = __builtin_amdgcn_mfma_f32_16x16x32_bf16(af[m], bfr[n], acc[m][n], 0, 0, 0);
    }
    if (col0 < 3072) {
        #pragma unroll
        for (int m = 0; m < 4; ++m)
            #pragma unroll
            for (int n = 0; n < 4; ++n)
                #pragma unroll
                for (int i = 0; i < 4; ++i)
                    projb[(size_t)(row0 + wr + m*16 + (lane >> 4)*4 + i) * PBW + col0 + wc + n*16 + (lane & 15)]
                        = (bf16_t)acc[m][n][i];
    } else {
        #pragma unroll
        for (int m = 0; m < 4; ++m)
            #pragma unroll
            for (int n = 0; n < 4; ++n)
                #pragma unroll
                for (int i = 0; i < 4; ++i)
                    projp[(size_t)(row0 + wr + m*16 + (lane >> 4)*4 + i) * PPW + col0 - 3072 + wc + n*16 + (lane & 15)]
                        = acc[m][n][i];
    }
}

// ---------------------------------------------------------------- out GEMM, 128x128 tile, gld16 staging
// out[4096 x 512] = catb[4096 x 2048] * WoutT[512 x 2048]^T
__global__ __launch_bounds__(256) void gemm_out(const bf16_t* __restrict__ A, const bf16_t* __restrict__ BT,
    float* __restrict__ C)
{
    __shared__ bf16_t Asl[128][32];
    __shared__ bf16_t Bsl[128][32];
    const int tid = threadIdx.x, lane = tid & 63, w = tid >> 6;
    const int row0 = blockIdx.y * 128, col0 = blockIdx.x * 128;
    const int wr = (w >> 1) * 64, wc = (w & 1) * 64;
    const int K = 2048;
    const int sr = lane >> 2, k8 = (lane & 3) * 8;
    const bf16_t* Ab = A + (size_t)(row0 + w * 32 + sr) * K + k8;
    const bf16_t* Bb = BT + (size_t)(col0 + w * 32 + sr) * K + k8;
    f32x4 acc[4][4];
    #pragma unroll
    for (int m = 0; m < 4; ++m)
        #pragma unroll
        for (int n = 0; n < 4; ++n) acc[m][n] = (f32x4){0.f,0.f,0.f,0.f};
    for (int k0 = 0; k0 < K; k0 += 32) {
        __syncthreads();
        gld16(Ab + k0,          &Asl[w * 32][0]);
        gld16(Ab + k0 + 16 * K, &Asl[w * 32 + 16][0]);
        gld16(Bb + k0,          &Bsl[w * 32][0]);
        gld16(Bb + k0 + 16 * K, &Bsl[w * 32 + 16][0]);
        __syncthreads();
        bf16x8 af[4], bfr[4];
        #pragma unroll
        for (int m = 0; m < 4; ++m) af[m]  = *(const bf16x8*)&Asl[wr + m*16 + (lane & 15)][(lane >> 4) * 8];
        #pragma unroll
        for (int n = 0; n < 4; ++n) bfr[n] = *(const bf16x8*)&Bsl[wc + n*16 + (lane & 15)][(lane >> 4) * 8];
        #pragma unroll
        for (int m = 0; m < 4; ++m)
            #pragma unroll
            for (int n = 0; n < 4; ++n)
                acc[m][n] = __builtin_amdgcn_mfma_f32_16x16x32_bf16(af[m], bfr[n], acc[m][n], 0, 0, 0);
    }
    #pragma unroll
    for (int m = 0; m < 4; ++m)
        #pragma unroll
        for (int n = 0; n < 4; ++n)
            #pragma unroll
            for (int i = 0; i < 4; ++i)
                C[(size_t)(row0 + wr + m*16 + (lane >> 4)*4 + i) * 512 + col0 + wc + n*16 + (lane & 15)] = acc[m][n][i];
}

// ---------------------------------------------------------------- z LN+proj (blocks 0..2047) + point rot (2048..3071)
__global__ __launch_bounds__(256) void k_zrot(const float* __restrict__ z,
    const bf16_t* __restrict__ WzT, const float* __restrict__ Kv,
    float* __restrict__ biasT, bf16_t* __restrict__ pzT,
    float* __restrict__ projp, const float* __restrict__ rots, const float* __restrict__ trans)
{
    __shared__ __align__(16) float zbuf[2][64][128];
    const int tid = threadIdx.x, lane = tid & 63, w = tid >> 6;
    if (blockIdx.x >= 2048) {
        // point rotation: 4 rows per block, 4 points per lane
        int row = (blockIdx.x - 2048) * 4 + (tid >> 6);
        const float* R = rots + (size_t)row * 9;
        const float* t = trans + (size_t)row * 3;
        float R0=R[0],R1=R[1],R2=R[2],R3=R[3],R4=R[4],R5=R[5],R6=R[6],R7=R[7],R8=R[8];
        float t0=t[0],t1=t[1],t2=t[2];
        float* base = projp + (size_t)row * PPW + lane * 12;
        float4 a = *(const float4*)(base);
        float4 b = *(const float4*)(base + 4);
        float4 c = *(const float4*)(base + 8);
        float x0=a.x,y0=a.y,z0=a.z, x1=a.w,y1=b.x,z1=b.y, x2=b.z,y2=b.w,z2=c.x, x3=c.y,y3=c.z,z3=c.w;
        a.x = R0*x0+R1*y0+R2*z0+t0; a.y = R3*x0+R4*y0+R5*z0+t1; a.z = R6*x0+R7*y0+R8*z0+t2;
        a.w = R0*x1+R1*y1+R2*z1+t0; b.x = R3*x1+R4*y1+R5*z1+t1; b.y = R6*x1+R7*y1+R8*z1+t2;
        b.z = R0*x2+R1*y2+R2*z2+t0; b.w = R3*x2+R4*y2+R5*z2+t1; c.x = R6*x2+R7*y2+R8*z2+t2;
        c.y = R0*x3+R1*y3+R2*z3+t0; c.z = R3*x3+R4*y3+R5*z3+t1; c.w = R6*x3+R7*y3+R8*z3+t2;
        *(float4*)(base) = a;
        *(float4*)(base + 4) = b;
        *(float4*)(base + 8) = c;
        return;
    }
    const int r16 = lane & 15, kg = lane >> 4;
    bf16x8 bfz[3][4];
    #pragma unroll
    for (int nt = 0; nt < 3; ++nt)
        #pragma unroll
        for (int kc = 0; kc < 4; ++kc)
            bfz[nt][kc] = *(const bf16x8*)(WzT + (size_t)(nt * 16 + r16) * 128 + kc * 32 + kg * 8);
    float K0 = Kv[r16], K1 = Kv[16 + r16], K2 = Kv[32 + r16];
    asm volatile("s_waitcnt vmcnt(0)" ::: "memory");

    const int gid = blockIdx.x * 4 + w;
    const char* zb = (const char*)z + (size_t)gid * 64 * 512;
    char* lb0 = (char*)&zbuf[0][w * 16][0];
    char* lb1 = (char*)&zbuf[1][w * 16][0];

#define STAGE(i, lb) { \
    const char* gp_ = zb + (size_t)(i) * 8192 + lane * 16; \
    _Pragma("unroll") \
    for (int c_ = 0; c_ < 8; ++c_) gld16(gp_ + c_ * 1024, (lb) + c_ * 1024); }

#define PROCESS(i, b) { \
    const float* rp = &zbuf[b][w * 16 + r16][kg * 8]; \
    float4 za[4], zc[4]; \
    float sum = 0.f, sq = 0.f; \
    _Pragma("unroll") \
    for (int kc = 0; kc < 4; ++kc) { \
        float4 a_ = *(const float4*)(rp + kc * 32); \
        float4 b_ = *(const float4*)(rp + kc * 32 + 4); \
        za[kc] = a_; zc[kc] = b_; \
        sum += a_.x + a_.y + a_.z + a_.w + b_.x + b_.y + b_.z + b_.w; \
        sq  += a_.x*a_.x + a_.y*a_.y + a_.z*a_.z + a_.w*a_.w + b_.x*b_.x + b_.y*b_.y + b_.z*b_.z + b_.w*b_.w; \
    } \
    sum += __shfl_xor(sum, 16); sq += __shfl_xor(sq, 16); \
    sum += __shfl_xor(sum, 32); sq += __shfl_xor(sq, 32); \
    float m_ = sum * (1.0f / 128.0f); \
    float rs_ = rsqrtf(sq * (1.0f / 128.0f) - m_ * m_ + 1e-5f); \
    bf16x8 af[4]; \
    _Pragma("unroll") \
    for (int kc = 0; kc < 4; ++kc) { \
        af[kc][0] = (bf16_t)((za[kc].x - m_) * rs_); \
        af[kc][1] = (bf16_t)((za[kc].y - m_) * rs_); \
        af[kc][2] = (bf16_t)((za[kc].z - m_) * rs_); \
        af[kc][3] = (bf16_t)((za[kc].w - m_) * rs_); \
        af[kc][4] = (bf16_t)((zc[kc].x - m_) * rs_); \
        af[kc][5] = (bf16_t)((zc[kc].y - m_) * rs_); \
        af[kc][6] = (bf16_t)((zc[kc].z - m_) * rs_); \
        af[kc][7] = (bf16_t)((zc[kc].w - m_) * rs_); \
    } \
    f32x4 acc0 = (f32x4){0.f,0.f,0.f,0.f}; \
    f32x4 acc1 = (f32x4){0.f,0.f,0.f,0.f}; \
    f32x4 acc2 = (f32x4){0.f,0.f,0.f,0.f}; \
    _Pragma("unroll") \
    for (int kc = 0; kc < 4; ++kc) { \
        acc0 = __builtin_amdgcn_mfma_f32_16x16x32_bf16(af[kc], bfz[0][kc], acc0, 0, 0, 0); \
        acc1 = __builtin_amdgcn_mfma_f32_16x16x32_bf16(af[kc], bfz[1][kc], acc1, 0, 0, 0); \
        acc2 = __builtin_amdgcn_mfma_f32_16x16x32_bf16(af[kc], bfz[2][kc], acc2, 0, 0, 0); \
    } \
    const int t_ = gid * 4 + (i); \
    const int rowq_ = t_ >> 3; \
    const int k0_ = ((t_ & 7) << 4) + kg * 4; \
    float4 bw = {acc0[0] + K0, acc0[1] + K0, acc0[2] + K0, acc0[3] + K0}; \
    *(float4*)&biasT[((size_t)rowq_ * 16 + r16) * 128 + k0_] = bw; \
    bf16x4 p1, p2; \
    _Pragma("unroll") \
    for (int i2 = 0; i2 < 4; ++i2) { p1[i2] = (bf16_t)(acc1[i2] + K1); p2[i2] = (bf16_t)(acc2[i2] + K2); } \
    *(bf16x4*)&pzT[((size_t)rowq_ * 32 + r16) * 128 + k0_] = p1; \
    *(bf16x4*)&pzT[((size_t)rowq_ * 32 + 16 + r16) * 128 + k0_] = p2; }

    STAGE(0, lb0);
    STAGE(1, lb1);
    asm volatile("s_waitcnt vmcnt(8)" ::: "memory");
    PROCESS(0, 0);
    STAGE(2, lb0);
    asm volatile("s_waitcnt vmcnt(11)" ::: "memory");
    PROCESS(1, 1);
    STAGE(3, lb1);
    asm volatile("s_waitcnt vmcnt(11)" ::: "memory");
    PROCESS(2, 0);
    asm volatile("s_waitcnt vmcnt(3)" ::: "memory");
    PROCESS(3, 1);
#undef STAGE
#undef PROCESS
}

// ---------------------------------------------------------------- attention: one wg per (nblk, head), XCD-swizzled
__global__ __launch_bounds__(256) void k_attn3(
    const bf16_t* __restrict__ projb, const float* __restrict__ projp,
    const float* __restrict__ biasT, const float* __restrict__ rots,
    const float* __restrict__ trans, const float* __restrict__ smask,
    const int* __restrict__ kidx, const float* __restrict__ hwraw,
    bf16_t* __restrict__ catb, bf16_t* __restrict__ Pbf)
{
    __shared__ __align__(16) char uni[26112];          // Qs[32][72]b + Ks[128][72]b  OR  Vt[96][136]b
    __shared__ float att[32][132];
    __shared__ float kp_s[128][12];
    __shared__ float qp_s[32][12];
    __shared__ bf16_t Ps[32][136];
    __shared__ float optmp[32][33];
    __shared__ float km_s[128];
    __shared__ float qm_s[32];
    __shared__ int   rows_s[128];

    bf16_t (*Qs)[72]  = (bf16_t(*)[72])uni;
    bf16_t (*Ks)[72]  = (bf16_t(*)[72])(uni + 32 * 72 * 2);
    bf16_t (*Vt)[136] = (bf16_t(*)[136])uni;

    // XCD-bijective swizzle: each XCD owns 2 heads x all 128 nblks
    const int wgid = blockIdx.x;
    const int swz = (wgid & 7) * 256 + (wgid >> 3);
    const int h = swz >> 7;
    const int nblk = swz & 127;
    const int tid = threadIdx.x;
    const int lane = tid & 63;
    const int w = tid >> 6;
    const int rowq0 = nblk * 32;
    const float hw = log1pf(__expf(hwraw[h])) * 0.13608276348795434f;

    if (tid < 128) {
        int ki = kidx[nblk * 128 + tid];
        int valid = (ki >= 0 && ki < D_N);
        int rr = ki < 0 ? 0 : (ki > D_N - 1 ? D_N - 1 : ki);
        rows_s[tid] = rr;
        km_s[tid] = valid ? smask[rr] : 0.0f;
    } else if (tid < 160) {
        qm_s[tid - 128] = smask[rowq0 + tid - 128];
    }
    __syncthreads();
    // ---- Phase A: stage Q, qp, K, kp
    {
        int q = tid >> 3, cg = (tid & 7) * 8;
        *(bf16x8*)&Qs[q][cg] = *(const bf16x8*)(projb + (size_t)(rowq0 + q) * PBW + h * 64 + cg);
    }
    if (tid < 128) {
        int q = tid >> 2, dg = (tid & 3) * 3;
        const float* p = projp + (size_t)(rowq0 + q) * PPW + h * 12 + dg;
        qp_s[q][dg + 0] = p[0]; qp_s[q][dg + 1] = p[1]; qp_s[q][dg + 2] = p[2];
    }
    {
        int krow = tid >> 1, cg = (tid & 1) * 32;
        const bf16_t* p = projb + (size_t)rows_s[krow] * PBW + OFFK + h * 64 + cg;
        #pragma unroll
        for (int u = 0; u < 4; ++u)
            *(bf16x8*)&Ks[krow][cg + u * 8] = *(const bf16x8*)(p + u * 8);
        const float* pk = projp + (size_t)rows_s[krow] * PPW + 192 + h * 36 + (tid & 1) * 6;
        int dg = (tid & 1) * 6;
        #pragma unroll
        for (int u = 0; u < 6; ++u) kp_s[krow][dg + u] = pk[u];
    }
    __syncthreads();
    // ---- Phase B: QK^T MFMA
    {
        #pragma unroll
        for (int j = 0; j < 4; ++j) {
            int T = w * 4 + j;
            int m = T & 1, n = T >> 1;
            f32x4 acc = (f32x4){0.f,0.f,0.f,0.f};
            #pragma unroll
            for (int kc = 0; kc < 2; ++kc) {
                bf16x8 a = *(const bf16x8*)&Qs[m*16 + (lane & 15)][kc*32 + (lane >> 4) * 8];
                bf16x8 b = *(const bf16x8*)&Ks[n*16 + (lane & 15)][kc*32 + (lane >> 4) * 8];
                acc = __builtin_amdgcn_mfma_f32_16x16x32_bf16(a, b, acc, 0, 0, 0);
            }
            #pragma unroll
            for (int i = 0; i < 4; ++i)
                att[m*16 + (lane >> 4)*4 + i][n*16 + (lane & 15)] = acc[i];
        }
    }
    __syncthreads();
    // ---- Phase C: stage V^T + vpts^T (overwrites Qs/Ks) and f32 logit assembly
    {
        int krow = tid >> 1, cg = (tid & 1) * 32;
        const bf16_t* p = projb + (size_t)rows_s[krow] * PBW + OFFV + h * 64 + cg;
        #pragma unroll
        for (int u4 = 0; u4 < 4; ++u4) {
            bf16x8 v = *(const bf16x8*)(p + u4 * 8);
            #pragma unroll
            for (int j = 0; j < 8; ++j) Vt[cg + u4 * 8 + j][krow] = v[j];
        }
        const float* pv = projp + (size_t)rows_s[krow] * PPW + 192 + h * 36 + 12 + (tid & 1) * 12;
        #pragma unroll
        for (int u = 0; u < 3; ++u) {
            float4 v = *(const float4*)(pv + u * 4);
            int rb = 64 + (tid & 1) * 12 + u * 4;
            Vt[rb + 0][krow] = (bf16_t)v.x;
            Vt[rb + 1][krow] = (bf16_t)v.y;
            Vt[rb + 2][krow] = (bf16_t)v.z;
            Vt[rb + 3][krow] = (bf16_t)v.w;
        }
        {   // zero-pad rows 88..95
            int r = 88 + (tid >> 5), c = (tid & 31) * 4;
            bf16x4 zz; zz[0]=(bf16_t)0.f; zz[1]=(bf16_t)0.f; zz[2]=(bf16_t)0.f; zz[3]=(bf16_t)0.f;
            *(bf16x4*)&Vt[r][c] = zz;
        }
        // logits
        int q = tid >> 3, kg = tid & 7;
        float qp[12];
        #pragma unroll
        for (int e = 0; e < 12; ++e) qp[e] = qp_s[q][e];
        float qm = qm_s[q];
        const float* bT = biasT + ((size_t)(rowq0 + q) * 16 + h) * 128;
        #pragma unroll
        for (int j2 = 0; j2 < 16; ++j2) {
            int k = kg + j2 * 8;
            float4 k0 = *(const float4*)&kp_s[k][0];
            float4 k1 = *(const float4*)&kp_s[k][4];
            float4 k2 = *(const float4*)&kp_s[k][8];
            float d0 = qp[0]-k0.x, d1 = qp[1]-k0.y, d2_ = qp[2]-k0.z, d3 = qp[3]-k0.w;
            float d4 = qp[4]-k1.x, d5 = qp[5]-k1.y, d6 = qp[6]-k1.z, d7 = qp[7]-k1.w;
            float d8 = qp[8]-k2.x, d9 = qp[9]-k2.y, d10 = qp[10]-k2.z, d11 = qp[11]-k2.w;
            float dd = d0*d0+d1*d1+d2_*d2_+d3*d3+d4*d4+d5*d5+d6*d6+d7*d7+d8*d8+d9*d9+d10*d10+d11*d11;
            float val = att[q][k] * 0.07216878364870323f
                      + 0.5773502691896258f * bT[k]
                      + 100000.0f * (qm * km_s[k] - 1.0f)
                      - 0.5f * hw * dd;
            att[q][k] = val;
        }
    }
    __syncthreads();
    // ---- Phase D: softmax + P -> bf16
    {
        int q = tid >> 3, kg = tid & 7;
        float l[16];
        #pragma unroll
        for (int j2 = 0; j2 < 16; ++j2) l[j2] = att[q][kg + j2 * 8];
        float mx = l[0];
        #pragma unroll
        for (int j2 = 1; j2 < 16; ++j2) mx = fmaxf(mx, l[j2]);
        mx = fmaxf(mx, __shfl_xor(mx, 1));
        mx = fmaxf(mx, __shfl_xor(mx, 2));
        mx = fmaxf(mx, __shfl_xor(mx, 4));
        float se = 0.f;
        #pragma unroll
        for (int j2 = 0; j2 < 16; ++j2) { l[j2] = __expf(l[j2] - mx); se += l[j2]; }
        se += __shfl_xor(se, 1);
        se += __shfl_xor(se, 2);
        se += __shfl_xor(se, 4);
        float inv = 1.0f / se;
        bf16_t* pg = Pbf + ((size_t)(rowq0 + q) * 16 + h) * 128;
        #pragma unroll
        for (int j2 = 0; j2 < 16; ++j2) {
            bf16_t pb = (bf16_t)(l[j2] * inv);
            Ps[q][kg + j2 * 8] = pb;
            pg[kg + j2 * 8] = pb;
        }
    }
    __syncthreads();
    // ---- Phase E: PV MFMA
    {
        #pragma unroll
        for (int j = 0; j < 3; ++j) {
            int T = w * 3 + j;
            int m = T & 1, n = T >> 1;
            f32x4 acc = (f32x4){0.f,0.f,0.f,0.f};
            #pragma unroll
            for (int kc = 0; kc < 4; ++kc) {
                bf16x8 a = *(const bf16x8*)&Ps[m*16 + (lane & 15)][kc*32 + (lane >> 4) * 8];
                bf16x8 b = *(const bf16x8*)&Vt[n*16 + (lane & 15)][kc*32 + (lane >> 4) * 8];
                acc = __builtin_amdgcn_mfma_f32_16x16x32_bf16(a, b, acc, 0, 0, 0);
            }
            int rowb = m * 16 + (lane >> 4) * 4;
            int col = lane & 15;
            if (n < 4) {
                #pragma unroll
                for (int i = 0; i < 4; ++i)
                    catb[(size_t)(rowq0 + rowb + i) * CATW + h * 64 + n * 16 + col] = (bf16_t)acc[i];
            } else {
                #pragma unroll
                for (int i = 0; i < 4; ++i)
                    optmp[rowb + i][(n - 4) * 16 + col] = acc[i];
            }
        }
    }
    __syncthreads();
    // ---- Phase F: o_pt inverse transform + norm
    {
        int q = tid >> 3, pp = tid & 7;
        float sx = optmp[q][pp * 3 + 0];
        float sy = optmp[q][pp * 3 + 1];
        float sz = optmp[q][pp * 3 + 2];
        const float* R = rots + (size_t)(rowq0 + q) * 9;
        const float* t = trans + (size_t)(rowq0 + q) * 3;
        float x = sx - t[0], y = sy - t[1], z2 = sz - t[2];
        float ox = R[0] * x + R[3] * y + R[6] * z2;
        float oy = R[1] * x + R[4] * y + R[7] * z2;
        float oz = R[2] * x + R[5] * y + R[8] * z2;
        bf16_t* cp = catb + (size_t)(rowq0 + q) * CATW;
        cp[1024 + h * 24 + pp * 3 + 0] = (bf16_t)ox;
        cp[1024 + h * 24 + pp * 3 + 1] = (bf16_t)oy;
        cp[1024 + h * 24 + pp * 3 + 2] = (bf16_t)oz;
        cp[1408 + h * 8 + pp] = (bf16_t)sqrtf(ox * ox + oy * oy + oz * oz + 1e-8f);
    }
}

// ---------------------------------------------------------------- o_pair: per rowq MFMA [16h x 128k] x [128k x 32c]
__global__ __launch_bounds__(256) void k_opair(const bf16_t* __restrict__ Pbf,
    const bf16_t* __restrict__ pzT, bf16_t* __restrict__ catb)
{
    int tid = threadIdx.x, lane = tid & 63, w = tid >> 6;
    size_t rowq = (size_t)blockIdx.x * 4 + w;
    const bf16_t* Pp = Pbf + rowq * 2048;
    const bf16_t* zp = pzT + rowq * 4096;
    bf16x8 pa[4];
    #pragma unroll
    for (int kc = 0; kc < 4; ++kc)
        pa[kc] = *(const bf16x8*)(Pp + (size_t)(lane & 15) * 128 + kc * 32 + (lane >> 4) * 8);
    #pragma unroll
    for (int ct = 0; ct < 2; ++ct) {
        f32x4 acc = (f32x4){0.f,0.f,0.f,0.f};
        #pragma unroll
        for (int kc = 0; kc < 4; ++kc) {
            bf16x8 b = *(const bf16x8*)(zp + (size_t)(ct * 16 + (lane & 15)) * 128 + kc * 32 + (lane >> 4) * 8);
            acc = __builtin_amdgcn_mfma_f32_16x16x32_bf16(pa[kc], b, acc, 0, 0, 0);
        }
        #pragma unroll
        for (int i = 0; i < 4; ++i) {
            int hh = (lane >> 4) * 4 + i;
            catb[rowq * CATW + 1536 + hh * 32 + ct * 16 + (lane & 15)] = (bf16_t)acc[i];
        }
    }
}

// ---------------------------------------------------------------- launcher
extern "C" void kernel_launch(void* const* d_in, const int* in_sizes, int n_in,
                              void* d_out, int out_size, void* d_ws, size_t ws_size,
                              hipStream_t stream)
{
    (void)in_sizes; (void)n_in; (void)out_size;
    const float* s     = (const float*)d_in[0];
    const float* z     = (const float*)d_in[1];
    const float* trans = (const float*)d_in[2];
    const float* rots  = (const float*)d_in[3];
    const float* smask = (const float*)d_in[4];
    const int*   kidx  = (const int*)d_in[5];
    const float* Wq    = (const float*)d_in[6];
    const float* Wk    = (const float*)d_in[7];
    const float* Wv    = (const float*)d_in[8];
    const float* Wqp   = (const float*)d_in[9];
    const float* Wkvp  = (const float*)d_in[10];
    const float* Wb    = (const float*)d_in[11];
    const float* Wdz   = (const float*)d_in[12];
    const float* hw    = (const float*)d_in[13];
    const float* Wout  = (const float*)d_in[14];
    const float* g_s   = (const float*)d_in[15];
    const float* b_s   = (const float*)d_in[16];
    const float* g_z   = (const float*)d_in[17];
    const float* b_z   = (const float*)d_in[18];

    char* ws = (char*)d_ws;
    bf16_t* projb = (bf16_t*)(ws);                      // 25,165,824
    float*  projp = (float*)(ws + 25165824);            // 12,582,912
    float*  biasT = (float*)(ws + 37748736);            // 33,554,432
    bf16_t* wcatT = (bf16_t*)(ws + 71303168);           //  3,932,160
    bf16_t* s_nb  = (bf16_t*)(ws + 75235328);           //  4,194,304
    bf16_t* pzT   = (bf16_t*)(ws + 79429632);           // 33,554,432
    bf16_t* Pbf   = (bf16_t*)(ws + 112984064);          // 16,777,216
    bf16_t* catb  = (bf16_t*)(ws + 129761280);          // 16,777,216
    bf16_t* WoutT = (bf16_t*)(ws + 146538496);          //  2,097,152
    bf16_t* WzT   = (bf16_t*)(ws + 148635648);          //     12,288
    float*  Kv    = (float*)(ws + 148647936);           //        192
    if (ws_size < (size_t)148648128) return;
    float* out = (float*)d_out;

    k_prep<<<1761, 256, 0, stream>>>(Wq, Wk, Wv, Wqp, Wkvp, Wout, Wb, Wdz, g_z, b_z,
                                     s, g_s, b_s, wcatT, WoutT, WzT, Kv, s_nb);
    gemm_proj<<<dim3(30, 32), 256, 0, stream>>>(s_nb, wcatT, projb, projp);
    k_zrot<<<3072, 256, 0, stream>>>(z, WzT, Kv, biasT, pzT, projp, rots, trans);
    k_attn3<<<2048, 256, 0, stream>>>(projb, projp, biasT, rots, trans, smask, kidx, hw, catb, Pbf);
    k_opair<<<1024, 256, 0, stream>>>(Pbf, pzT, catb);
    gemm_out<<<dim3(4, 32), 256, 0, stream>>>(catb, WoutT, out);
}

// Round 7
// 221.573 us; speedup vs baseline: 4.9770x; 1.0415x over previous
//
#include <hip/hip_runtime.h>
#include <math.h>

#define D_N 4096
#define PBW 3072
#define PPW 768
#define OFFK 1024
#define OFFV 2048
#define CATW 2048

typedef __bf16 bf16_t;
typedef __bf16 bf16x8 __attribute__((ext_vector_type(8)));
typedef __bf16 bf16x4 __attribute__((ext_vector_type(4)));
typedef float f32x4 __attribute__((ext_vector_type(4)));

__device__ __forceinline__ void gld16(const void* g, void* l) {
    __builtin_amdgcn_global_load_lds((const __attribute__((address_space(1))) unsigned int*)g,
                                     (__attribute__((address_space(3))) unsigned int*)l, 16, 0, 0);
}

// ---------------------------------------------------------------- merged prep:
// blocks [0,480): wcatT ; [480,736): WoutT ; 736: WzT+Kv ; [737,1761): ln_s
__global__ __launch_bounds__(256) void k_prep(
    const float* __restrict__ Wq, const float* __restrict__ Wk, const float* __restrict__ Wv,
    const float* __restrict__ Wqp, const float* __restrict__ Wkvp, const float* __restrict__ Wout,
    const float* __restrict__ Wb, const float* __restrict__ Wdz,
    const float* __restrict__ gz, const float* __restrict__ bz,
    const float* __restrict__ s, const float* __restrict__ g_s, const float* __restrict__ b_s,
    bf16_t* __restrict__ wcatT, bf16_t* __restrict__ WoutT,
    bf16_t* __restrict__ WzT, float* __restrict__ Kv, bf16_t* __restrict__ s_nb)
{
    __shared__ float T[64][65];
    const int bx = blockIdx.x;
    const int tid = threadIdx.x;
    if (bx < 736) {
        const float* src; int ld, coff, r0;
        bf16_t* dst; int Rdst;
        if (bx < 480) {
            int c0 = (bx % 60) * 64;
            r0 = (bx / 60) * 64;
            if (c0 < 1024)      { src = Wq;   ld = 1024; coff = c0; }
            else if (c0 < 2048) { src = Wk;   ld = 1024; coff = c0 - 1024; }
            else if (c0 < 3072) { src = Wv;   ld = 1024; coff = c0 - 2048; }
            else if (c0 < 3264) { src = Wqp;  ld = 192;  coff = c0 - 3072; }
            else                { src = Wkvp; ld = 576;  coff = c0 - 3264; }
            dst = wcatT + (size_t)c0 * 512; Rdst = 512;
        } else {
            int b = bx - 480;
            int c0 = (b & 7) * 64;
            r0 = (b >> 3) * 64;
            src = Wout; ld = 512; coff = c0;
            dst = WoutT + (size_t)c0 * 2048; Rdst = 2048;
        }
        {
            int rr = tid >> 2, cb = (tid & 3) * 16;
            const float* p = src + (size_t)(r0 + rr) * ld + coff + cb;
            #pragma unroll
            for (int i = 0; i < 4; ++i)
                *(float4*)&T[rr][cb + i * 4] = *(const float4*)(p + i * 4);
        }
        __syncthreads();
        {
            int cc = tid >> 2, rb = (tid & 3) * 16;
            bf16_t* o = dst + (size_t)cc * Rdst + r0 + rb;
            bf16x8 o0, o1;
            #pragma unroll
            for (int j = 0; j < 8; ++j) o0[j] = (bf16_t)T[rb + j][cc];
            #pragma unroll
            for (int j = 0; j < 8; ++j) o1[j] = (bf16_t)T[rb + 8 + j][cc];
            *(bf16x8*)(o) = o0;
            *(bf16x8*)(o + 8) = o1;
        }
    } else if (bx == 736) {
        for (int i = tid; i < 6144; i += 256) {
            int j = i >> 7, c = i & 127;
            float w = (j < 16) ? Wb[c * 16 + j] : Wdz[c * 32 + (j - 16)];
            WzT[i] = (bf16_t)(gz[c] * w);
        }
        if (tid < 48) {
            int j = tid;
            float acc = 0.f;
            for (int c = 0; c < 128; ++c) {
                float w = (j < 16) ? Wb[c * 16 + j] : Wdz[c * 32 + (j - 16)];
                acc += bz[c] * w;
            }
            Kv[j] = acc;
        }
    } else {
        int row = (bx - 737) * 4 + (tid >> 6);
        int lane = tid & 63;
        const float4* p = (const float4*)(s + (size_t)row * 512);
        float4 v0 = p[lane];
        float4 v1 = p[lane + 64];
        float sum = v0.x + v0.y + v0.z + v0.w + v1.x + v1.y + v1.z + v1.w;
        float sq  = v0.x*v0.x + v0.y*v0.y + v0.z*v0.z + v0.w*v0.w
                  + v1.x*v1.x + v1.y*v1.y + v1.z*v1.z + v1.w*v1.w;
        #pragma unroll
        for (int off = 1; off < 64; off <<= 1) {
            sum += __shfl_xor(sum, off);
            sq  += __shfl_xor(sq, off);
        }
        float m = sum * (1.0f / 512.0f);
        float var = sq * (1.0f / 512.0f) - m * m;
        float rs = rsqrtf(var + 1e-5f);
        int c = lane * 4;
        int c2 = 256 + lane * 4;
        bf16x4 r0, r1;
        r0[0] = (bf16_t)((v0.x - m) * rs * g_s[c+0] + b_s[c+0]);
        r0[1] = (bf16_t)((v0.y - m) * rs * g_s[c+1] + b_s[c+1]);
        r0[2] = (bf16_t)((v0.z - m) * rs * g_s[c+2] + b_s[c+2]);
        r0[3] = (bf16_t)((v0.w - m) * rs * g_s[c+3] + b_s[c+3]);
        r1[0] = (bf16_t)((v1.x - m) * rs * g_s[c2+0] + b_s[c2+0]);
        r1[1] = (bf16_t)((v1.y - m) * rs * g_s[c2+1] + b_s[c2+1]);
        r1[2] = (bf16_t)((v1.z - m) * rs * g_s[c2+2] + b_s[c2+2]);
        r1[3] = (bf16_t)((v1.w - m) * rs * g_s[c2+3] + b_s[c2+3]);
        *(bf16x4*)(s_nb + (size_t)row * 512 + c)  = r0;
        *(bf16x4*)(s_nb + (size_t)row * 512 + c2) = r1;
    }
}

// ---------------------------------------------------------------- proj GEMM, gld16 staging (standalone, round-5 proven)
__global__ __launch_bounds__(256) void gemm_proj(const bf16_t* __restrict__ A, const bf16_t* __restrict__ BT,
    bf16_t* __restrict__ projb, float* __restrict__ projp)
{
    __shared__ bf16_t Asl[128][32];
    __shared__ bf16_t Bsl[128][32];
    const int tid = threadIdx.x, lane = tid & 63, w = tid >> 6;
    const int row0 = blockIdx.y * 128, col0 = blockIdx.x * 128;
    const int wr = (w >> 1) * 64, wc = (w & 1) * 64;
    const int K = 512;
    const int sr = lane >> 2, k8 = (lane & 3) * 8;
    const bf16_t* Ab = A + (size_t)(row0 + w * 32 + sr) * K + k8;
    const bf16_t* Bb = BT + (size_t)(col0 + w * 32 + sr) * K + k8;
    f32x4 acc[4][4];
    #pragma unroll
    for (int m = 0; m < 4; ++m)
        #pragma unroll
        for (int n = 0; n < 4; ++n) acc[m][n] = (f32x4){0.f,0.f,0.f,0.f};
    for (int k0 = 0; k0 < K; k0 += 32) {
        __syncthreads();
        gld16(Ab + k0,          &Asl[w * 32][0]);
        gld16(Ab + k0 + 16 * K, &Asl[w * 32 + 16][0]);
        gld16(Bb + k0,          &Bsl[w * 32][0]);
        gld16(Bb + k0 + 16 * K, &Bsl[w * 32 + 16][0]);
        __syncthreads();
        bf16x8 af[4], bfr[4];
        #pragma unroll
        for (int m = 0; m < 4; ++m) af[m]  = *(const bf16x8*)&Asl[wr + m*16 + (lane & 15)][(lane >> 4) * 8];
        #pragma unroll
        for (int n = 0; n < 4; ++n) bfr[n] = *(const bf16x8*)&Bsl[wc + n*16 + (lane & 15)][(lane >> 4) * 8];
        #pragma unroll
        for (int m = 0; m < 4; ++m)
            #pragma unroll
            for (int n = 0; n < 4; ++n)
                acc[m][n] = __builtin_amdgcn_mfma_f32_16x16x32_bf16(af[m], bfr[n], acc[m][n], 0, 0, 0);
    }
    if (col0 < 3072) {
        #pragma unroll
        for (int m = 0; m < 4; ++m)
            #pragma unroll
            for (int n = 0; n < 4; ++n)
                #pragma unroll
                for (int i = 0; i < 4; ++i)
                    projb[(size_t)(row0 + wr + m*16 + (lane >> 4)*4 + i) * PBW + col0 + wc + n*16 + (lane & 15)]
                        = (bf16_t)acc[m][n][i];
    } else {
        #pragma unroll
        for (int m = 0; m < 4; ++m)
            #pragma unroll
            for (int n = 0; n < 4; ++n)
                #pragma unroll
                for (int i = 0; i < 4; ++i)
                    projp[(size_t)(row0 + wr + m*16 + (lane >> 4)*4 + i) * PPW + col0 - 3072 + wc + n*16 + (lane & 15)]
                        = acc[m][n][i];
    }
}

// ---------------------------------------------------------------- z LN + projection, standalone, robust vmcnt pipeline
// grid 2048 x 256; each wave: 4 contiguous 16-row tiles, per-wave dbuf, no barriers
__global__ __launch_bounds__(256) void k_zbias4(const float* __restrict__ z,
    const bf16_t* __restrict__ WzT, const float* __restrict__ Kv,
    float* __restrict__ biasT, bf16_t* __restrict__ pzT)
{
    __shared__ __align__(16) float zbuf[2][64][128];
    const int tid = threadIdx.x, lane = tid & 63, w = tid >> 6;
    const int r16 = lane & 15, kg = lane >> 4;
    bf16x8 bfz[3][4];
    #pragma unroll
    for (int nt = 0; nt < 3; ++nt)
        #pragma unroll
        for (int kc = 0; kc < 4; ++kc)
            bfz[nt][kc] = *(const bf16x8*)(WzT + (size_t)(nt * 16 + r16) * 128 + kc * 32 + kg * 8);
    float K0 = Kv[r16], K1 = Kv[16 + r16], K2 = Kv[32 + r16];
    asm volatile("s_waitcnt vmcnt(0)" ::: "memory");
    __builtin_amdgcn_sched_barrier(0);

    const int gid = blockIdx.x * 4 + w;
    const char* zb = (const char*)z + (size_t)gid * 64 * 512;
    char* lb0 = (char*)&zbuf[0][w * 16][0];
    char* lb1 = (char*)&zbuf[1][w * 16][0];

#define STAGE(i, lb) { \
    const char* gp_ = zb + (size_t)(i) * 8192 + lane * 16; \
    _Pragma("unroll") \
    for (int c_ = 0; c_ < 8; ++c_) gld16(gp_ + c_ * 1024, (lb) + c_ * 1024); }

#define PROCESS(i, b) { \
    const float* rp = &zbuf[b][w * 16 + r16][kg * 8]; \
    float4 za[4], zc[4]; \
    float sum = 0.f, sq = 0.f; \
    _Pragma("unroll") \
    for (int kc = 0; kc < 4; ++kc) { \
        float4 a_ = *(const float4*)(rp + kc * 32); \
        float4 b_ = *(const float4*)(rp + kc * 32 + 4); \
        za[kc] = a_; zc[kc] = b_; \
        sum += a_.x + a_.y + a_.z + a_.w + b_.x + b_.y + b_.z + b_.w; \
        sq  += a_.x*a_.x + a_.y*a_.y + a_.z*a_.z + a_.w*a_.w + b_.x*b_.x + b_.y*b_.y + b_.z*b_.z + b_.w*b_.w; \
    } \
    sum += __shfl_xor(sum, 16); sq += __shfl_xor(sq, 16); \
    sum += __shfl_xor(sum, 32); sq += __shfl_xor(sq, 32); \
    float m_ = sum * (1.0f / 128.0f); \
    float rs_ = rsqrtf(sq * (1.0f / 128.0f) - m_ * m_ + 1e-5f); \
    bf16x8 af[4]; \
    _Pragma("unroll") \
    for (int kc = 0; kc < 4; ++kc) { \
        af[kc][0] = (bf16_t)((za[kc].x - m_) * rs_); \
        af[kc][1] = (bf16_t)((za[kc].y - m_) * rs_); \
        af[kc][2] = (bf16_t)((za[kc].z - m_) * rs_); \
        af[kc][3] = (bf16_t)((za[kc].w - m_) * rs_); \
        af[kc][4] = (bf16_t)((zc[kc].x - m_) * rs_); \
        af[kc][5] = (bf16_t)((zc[kc].y - m_) * rs_); \
        af[kc][6] = (bf16_t)((zc[kc].z - m_) * rs_); \
        af[kc][7] = (bf16_t)((zc[kc].w - m_) * rs_); \
    } \
    f32x4 acc0 = (f32x4){0.f,0.f,0.f,0.f}; \
    f32x4 acc1 = (f32x4){0.f,0.f,0.f,0.f}; \
    f32x4 acc2 = (f32x4){0.f,0.f,0.f,0.f}; \
    _Pragma("unroll") \
    for (int kc = 0; kc < 4; ++kc) { \
        acc0 = __builtin_amdgcn_mfma_f32_16x16x32_bf16(af[kc], bfz[0][kc], acc0, 0, 0, 0); \
        acc1 = __builtin_amdgcn_mfma_f32_16x16x32_bf16(af[kc], bfz[1][kc], acc1, 0, 0, 0); \
        acc2 = __builtin_amdgcn_mfma_f32_16x16x32_bf16(af[kc], bfz[2][kc], acc2, 0, 0, 0); \
    } \
    const int t_ = gid * 4 + (i); \
    const int rowq_ = t_ >> 3; \
    const int k0_ = ((t_ & 7) << 4) + kg * 4; \
    float4 bw = {acc0[0] + K0, acc0[1] + K0, acc0[2] + K0, acc0[3] + K0}; \
    *(float4*)&biasT[((size_t)rowq_ * 16 + r16) * 128 + k0_] = bw; \
    bf16x4 p1, p2; \
    _Pragma("unroll") \
    for (int i2 = 0; i2 < 4; ++i2) { p1[i2] = (bf16_t)(acc1[i2] + K1); p2[i2] = (bf16_t)(acc2[i2] + K2); } \
    *(bf16x4*)&pzT[((size_t)rowq_ * 32 + r16) * 128 + k0_] = p1; \
    *(bf16x4*)&pzT[((size_t)rowq_ * 32 + 16 + r16) * 128 + k0_] = p2; }

    STAGE(0, lb0);
    STAGE(1, lb1);
    // robust: only the newest 8 ops (STAGE(1)) may remain in flight -> STAGE(0) complete
    asm volatile("s_waitcnt vmcnt(8)" ::: "memory");
    __builtin_amdgcn_sched_barrier(0);
    PROCESS(0, 0);
    STAGE(2, lb0);
    asm volatile("s_waitcnt vmcnt(8)" ::: "memory");   // everything older than STAGE(2) drained (incl. stores)
    __builtin_amdgcn_sched_barrier(0);
    PROCESS(1, 1);
    STAGE(3, lb1);
    asm volatile("s_waitcnt vmcnt(8)" ::: "memory");
    __builtin_amdgcn_sched_barrier(0);
    PROCESS(2, 0);
    asm volatile("s_waitcnt vmcnt(0)" ::: "memory");
    __builtin_amdgcn_sched_barrier(0);
    PROCESS(3, 1);
#undef STAGE
#undef PROCESS
}

// ---------------------------------------------------------------- attention: one wg per (nblk, head), XCD-swizzled,
// rotates q/k/v points on the fly (projp holds RAW projected points)
__global__ __launch_bounds__(256) void k_attn3(
    const bf16_t* __restrict__ projb, const float* __restrict__ projp,
    const float* __restrict__ biasT, const float* __restrict__ rots,
    const float* __restrict__ trans, const float* __restrict__ smask,
    const int* __restrict__ kidx, const float* __restrict__ hwraw,
    bf16_t* __restrict__ catb, bf16_t* __restrict__ Pbf)
{
    __shared__ __align__(16) char uni[26112];          // Qs[32][72]b + Ks[128][72]b  OR  Vt[96][136]b
    __shared__ float att[32][132];
    __shared__ float kp_s[128][12];
    __shared__ float qp_s[32][12];
    __shared__ bf16_t Ps[32][136];
    __shared__ float optmp[32][33];
    __shared__ float km_s[128];
    __shared__ float qm_s[32];
    __shared__ int   rows_s[128];

    bf16_t (*Qs)[72]  = (bf16_t(*)[72])uni;
    bf16_t (*Ks)[72]  = (bf16_t(*)[72])(uni + 32 * 72 * 2);
    bf16_t (*Vt)[136] = (bf16_t(*)[136])uni;

    const int wgid = blockIdx.x;
    const int swz = (wgid & 7) * 256 + (wgid >> 3);
    const int h = swz >> 7;
    const int nblk = swz & 127;
    const int tid = threadIdx.x;
    const int lane = tid & 63;
    const int w = tid >> 6;
    const int rowq0 = nblk * 32;
    const float hw = log1pf(__expf(hwraw[h])) * 0.13608276348795434f;

    if (tid < 128) {
        int ki = kidx[nblk * 128 + tid];
        int valid = (ki >= 0 && ki < D_N);
        int rr = ki < 0 ? 0 : (ki > D_N - 1 ? D_N - 1 : ki);
        rows_s[tid] = rr;
        km_s[tid] = valid ? smask[rr] : 0.0f;
    } else if (tid < 160) {
        qm_s[tid - 128] = smask[rowq0 + tid - 128];
    }
    __syncthreads();
    // ---- Phase A: stage Q (all), k-points+rot (tid<128), qp-rot + K (tid>=128)
    {
        int q = tid >> 3, cg = (tid & 7) * 8;
        *(bf16x8*)&Qs[q][cg] = *(const bf16x8*)(projb + (size_t)(rowq0 + q) * PBW + h * 64 + cg);
    }
    float Rk[9], tk0 = 0.f, tk1 = 0.f, tk2 = 0.f;
    if (tid < 128) {
        int rr = rows_s[tid];
        const float* Rp = rots + (size_t)rr * 9;
        const float* tp = trans + (size_t)rr * 3;
        #pragma unroll
        for (int e = 0; e < 9; ++e) Rk[e] = Rp[e];
        tk0 = tp[0]; tk1 = tp[1]; tk2 = tp[2];
        const float* kp = projp + (size_t)rr * PPW + 192 + h * 36;
        float4 p0 = *(const float4*)kp;
        float4 p1 = *(const float4*)(kp + 4);
        float4 p2 = *(const float4*)(kp + 8);
        float xs[4] = {p0.x, p0.w, p1.z, p2.y};
        float ys[4] = {p0.y, p1.x, p1.w, p2.z};
        float zs[4] = {p0.z, p1.y, p2.x, p2.w};
        #pragma unroll
        for (int p = 0; p < 4; ++p) {
            kp_s[tid][p*3+0] = Rk[0]*xs[p] + Rk[1]*ys[p] + Rk[2]*zs[p] + tk0;
            kp_s[tid][p*3+1] = Rk[3]*xs[p] + Rk[4]*ys[p] + Rk[5]*zs[p] + tk1;
            kp_s[tid][p*3+2] = Rk[6]*xs[p] + Rk[7]*ys[p] + Rk[8]*zs[p] + tk2;
        }
    } else {
        int j = tid - 128;
        {   // qp rotate: 4 threads per q-row
            int q = j >> 2, p = j & 3;
            const float* Rp = rots + (size_t)(rowq0 + q) * 9;
            const float* tp = trans + (size_t)(rowq0 + q) * 3;
            const float* qp = projp + (size_t)(rowq0 + q) * PPW + h * 12 + p * 3;
            float x = qp[0], y = qp[1], zc = qp[2];
            qp_s[q][p*3+0] = Rp[0]*x + Rp[1]*y + Rp[2]*zc + tp[0];
            qp_s[q][p*3+1] = Rp[3]*x + Rp[4]*y + Rp[5]*zc + tp[1];
            qp_s[q][p*3+2] = Rp[6]*x + Rp[7]*y + Rp[8]*zc + tp[2];
        }
        {   // K staging: one row per thread
            const bf16_t* pK = projb + (size_t)rows_s[j] * PBW + OFFK + h * 64;
            #pragma unroll
            for (int u = 0; u < 8; ++u)
                *(bf16x8*)&Ks[j][u * 8] = *(const bf16x8*)(pK + u * 8);
        }
    }
    __syncthreads();
    // ---- Phase B: QK^T MFMA
    {
        #pragma unroll
        for (int j = 0; j < 4; ++j) {
            int T = w * 4 + j;
            int m = T & 1, n = T >> 1;
            f32x4 acc = (f32x4){0.f,0.f,0.f,0.f};
            #pragma unroll
            for (int kc = 0; kc < 2; ++kc) {
                bf16x8 a = *(const bf16x8*)&Qs[m*16 + (lane & 15)][kc*32 + (lane >> 4) * 8];
                bf16x8 b = *(const bf16x8*)&Ks[n*16 + (lane & 15)][kc*32 + (lane >> 4) * 8];
                acc = __builtin_amdgcn_mfma_f32_16x16x32_bf16(a, b, acc, 0, 0, 0);
            }
            #pragma unroll
            for (int i = 0; i < 4; ++i)
                att[m*16 + (lane >> 4)*4 + i][n*16 + (lane & 15)] = acc[i];
        }
    }
    __syncthreads();
    // ---- Phase C: stage V^T (tid>=128) + v-points rot->Vt (tid<128, reuse Rk/tk) + logit assembly
    if (tid < 128) {
        const float* vp = projp + (size_t)rows_s[tid] * PPW + 192 + h * 36 + 12;
        float4 a0 = *(const float4*)(vp);
        float4 a1 = *(const float4*)(vp + 4);
        float4 a2 = *(const float4*)(vp + 8);
        float4 a3 = *(const float4*)(vp + 12);
        float4 a4 = *(const float4*)(vp + 16);
        float4 a5 = *(const float4*)(vp + 20);
        float xs[8] = {a0.x, a0.w, a1.z, a2.y, a3.x, a3.w, a4.z, a5.y};
        float ys[8] = {a0.y, a1.x, a1.w, a2.z, a3.y, a4.x, a4.w, a5.z};
        float zs[8] = {a0.z, a1.y, a2.x, a2.w, a3.z, a4.y, a5.x, a5.w};
        #pragma unroll
        for (int p = 0; p < 8; ++p) {
            Vt[64 + p*3 + 0][tid] = (bf16_t)(Rk[0]*xs[p] + Rk[1]*ys[p] + Rk[2]*zs[p] + tk0);
            Vt[64 + p*3 + 1][tid] = (bf16_t)(Rk[3]*xs[p] + Rk[4]*ys[p] + Rk[5]*zs[p] + tk1);
            Vt[64 + p*3 + 2][tid] = (bf16_t)(Rk[6]*xs[p] + Rk[7]*ys[p] + Rk[8]*zs[p] + tk2);
        }
        {   // zero-pad rows 88..95
            bf16x8 zz = {};
            *(bf16x8*)&Vt[88 + (tid & 7)][(tid >> 3) * 8] = zz;
        }
    } else {
        int krow = tid - 128;
        const bf16_t* p = projb + (size_t)rows_s[krow] * PBW + OFFV + h * 64;
        #pragma unroll
        for (int u4 = 0; u4 < 8; ++u4) {
            bf16x8 v = *(const bf16x8*)(p + u4 * 8);
            #pragma unroll
            for (int jj = 0; jj < 8; ++jj) Vt[u4 * 8 + jj][krow] = v[jj];
        }
    }
    {   // logits (all threads)
        int q = tid >> 3, kg = tid & 7;
        float qp[12];
        #pragma unroll
        for (int e = 0; e < 12; ++e) qp[e] = qp_s[q][e];
        float qm = qm_s[q];
        const float* bT = biasT + ((size_t)(rowq0 + q) * 16 + h) * 128;
        #pragma unroll
        for (int j2 = 0; j2 < 16; ++j2) {
            int k = kg + j2 * 8;
            float4 k0 = *(const float4*)&kp_s[k][0];
            float4 k1 = *(const float4*)&kp_s[k][4];
            float4 k2 = *(const float4*)&kp_s[k][8];
            float d0 = qp[0]-k0.x, d1 = qp[1]-k0.y, d2_ = qp[2]-k0.z, d3 = qp[3]-k0.w;
            float d4 = qp[4]-k1.x, d5 = qp[5]-k1.y, d6 = qp[6]-k1.z, d7 = qp[7]-k1.w;
            float d8 = qp[8]-k2.x, d9 = qp[9]-k2.y, d10 = qp[10]-k2.z, d11 = qp[11]-k2.w;
            float dd = d0*d0+d1*d1+d2_*d2_+d3*d3+d4*d4+d5*d5+d6*d6+d7*d7+d8*d8+d9*d9+d10*d10+d11*d11;
            float val = att[q][k] * 0.07216878364870323f
                      + 0.5773502691896258f * bT[k]
                      + 100000.0f * (qm * km_s[k] - 1.0f)
                      - 0.5f * hw * dd;
            att[q][k] = val;
        }
    }
    __syncthreads();
    // ---- Phase D: softmax + P -> bf16
    {
        int q = tid >> 3, kg = tid & 7;
        float l[16];
        #pragma unroll
        for (int j2 = 0; j2 < 16; ++j2) l[j2] = att[q][kg + j2 * 8];
        float mx = l[0];
        #pragma unroll
        for (int j2 = 1; j2 < 16; ++j2) mx = fmaxf(mx, l[j2]);
        mx = fmaxf(mx, __shfl_xor(mx, 1));
        mx = fmaxf(mx, __shfl_xor(mx, 2));
        mx = fmaxf(mx, __shfl_xor(mx, 4));
        float se = 0.f;
        #pragma unroll
        for (int j2 = 0; j2 < 16; ++j2) { l[j2] = __expf(l[j2] - mx); se += l[j2]; }
        se += __shfl_xor(se, 1);
        se += __shfl_xor(se, 2);
        se += __shfl_xor(se, 4);
        float inv = 1.0f / se;
        bf16_t* pg = Pbf + ((size_t)(rowq0 + q) * 16 + h) * 128;
        #pragma unroll
        for (int j2 = 0; j2 < 16; ++j2) {
            bf16_t pb = (bf16_t)(l[j2] * inv);
            Ps[q][kg + j2 * 8] = pb;
            pg[kg + j2 * 8] = pb;
        }
    }
    __syncthreads();
    // ---- Phase E: PV MFMA
    {
        #pragma unroll
        for (int j = 0; j < 3; ++j) {
            int T = w * 3 + j;
            int m = T & 1, n = T >> 1;
            f32x4 acc = (f32x4){0.f,0.f,0.f,0.f};
            #pragma unroll
            for (int kc = 0; kc < 4; ++kc) {
                bf16x8 a = *(const bf16x8*)&Ps[m*16 + (lane & 15)][kc*32 + (lane >> 4) * 8];
                bf16x8 b = *(const bf16x8*)&Vt[n*16 + (lane & 15)][kc*32 + (lane >> 4) * 8];
                acc = __builtin_amdgcn_mfma_f32_16x16x32_bf16(a, b, acc, 0, 0, 0);
            }
            int rowb = m * 16 + (lane >> 4) * 4;
            int col = lane & 15;
            if (n < 4) {
                #pragma unroll
                for (int i = 0; i < 4; ++i)
                    catb[(size_t)(rowq0 + rowb + i) * CATW + h * 64 + n * 16 + col] = (bf16_t)acc[i];
            } else {
                #pragma unroll
                for (int i = 0; i < 4; ++i)
                    optmp[rowb + i][(n - 4) * 16 + col] = acc[i];
            }
        }
    }
    __syncthreads();
    // ---- Phase F: o_pt inverse transform + norm
    {
        int q = tid >> 3, pp = tid & 7;
        float sx = optmp[q][pp * 3 + 0];
        float sy = optmp[q][pp * 3 + 1];
        float sz = optmp[q][pp * 3 + 2];
        const float* R = rots + (size_t)(rowq0 + q) * 9;
        const float* t = trans + (size_t)(rowq0 + q) * 3;
        float x = sx - t[0], y = sy - t[1], z2 = sz - t[2];
        float ox = R[0] * x + R[3] * y + R[6] * z2;
        float oy = R[1] * x + R[4] * y + R[7] * z2;
        float oz = R[2] * x + R[5] * y + R[8] * z2;
        bf16_t* cp = catb + (size_t)(rowq0 + q) * CATW;
        cp[1024 + h * 24 + pp * 3 + 0] = (bf16_t)ox;
        cp[1024 + h * 24 + pp * 3 + 1] = (bf16_t)oy;
        cp[1024 + h * 24 + pp * 3 + 2] = (bf16_t)oz;
        cp[1408 + h * 8 + pp] = (bf16_t)sqrtf(ox * ox + oy * oy + oz * oz + 1e-8f);
    }
}

// ---------------------------------------------------------------- o_pair: per rowq MFMA [16h x 128k] x [128k x 32c]
__global__ __launch_bounds__(256) void k_opair(const bf16_t* __restrict__ Pbf,
    const bf16_t* __restrict__ pzT, bf16_t* __restrict__ catb)
{
    int tid = threadIdx.x, lane = tid & 63, w = tid >> 6;
    size_t rowq = (size_t)blockIdx.x * 4 + w;
    const bf16_t* Pp = Pbf + rowq * 2048;
    const bf16_t* zp = pzT + rowq * 4096;
    bf16x8 pa[4];
    #pragma unroll
    for (int kc = 0; kc < 4; ++kc)
        pa[kc] = *(const bf16x8*)(Pp + (size_t)(lane & 15) * 128 + kc * 32 + (lane >> 4) * 8);
    #pragma unroll
    for (int ct = 0; ct < 2; ++ct) {
        f32x4 acc = (f32x4){0.f,0.f,0.f,0.f};
        #pragma unroll
        for (int kc = 0; kc < 4; ++kc) {
            bf16x8 b = *(const bf16x8*)(zp + (size_t)(ct * 16 + (lane & 15)) * 128 + kc * 32 + (lane >> 4) * 8);
            acc = __builtin_amdgcn_mfma_f32_16x16x32_bf16(pa[kc], b, acc, 0, 0, 0);
        }
        #pragma unroll
        for (int i = 0; i < 4; ++i) {
            int hh = (lane >> 4) * 4 + i;
            catb[rowq * CATW + 1536 + hh * 32 + ct * 16 + (lane & 15)] = (bf16_t)acc[i];
        }
    }
}

// ---------------------------------------------------------------- out GEMM, 64x128 tile (256 wgs), gld16 staging
__global__ __launch_bounds__(256) void gemm_out(const bf16_t* __restrict__ A, const bf16_t* __restrict__ BT,
    float* __restrict__ C)
{
    __shared__ bf16_t Asl[64][32];
    __shared__ bf16_t Bsl[128][32];
    const int tid = threadIdx.x, lane = tid & 63, w = tid >> 6;
    const int row0 = blockIdx.y * 64, col0 = blockIdx.x * 128;
    const int wr = (w >> 1) * 32, wc = (w & 1) * 64;
    const int K = 2048;
    const int sr = lane >> 2, k8 = (lane & 3) * 8;
    const bf16_t* Ab = A + (size_t)(row0 + w * 16 + sr) * K + k8;
    const bf16_t* Bb = BT + (size_t)(col0 + w * 32 + sr) * K + k8;
    f32x4 acc[2][4];
    #pragma unroll
    for (int m = 0; m < 2; ++m)
        #pragma unroll
        for (int n = 0; n < 4; ++n) acc[m][n] = (f32x4){0.f,0.f,0.f,0.f};
    for (int k0 = 0; k0 < K; k0 += 32) {
        __syncthreads();
        gld16(Ab + k0,          &Asl[w * 16][0]);
        gld16(Bb + k0,          &Bsl[w * 32][0]);
        gld16(Bb + k0 + 16 * K, &Bsl[w * 32 + 16][0]);
        __syncthreads();
        bf16x8 af[2], bfr[4];
        #pragma unroll
        for (int m = 0; m < 2; ++m) af[m]  = *(const bf16x8*)&Asl[wr + m*16 + (lane & 15)][(lane >> 4) * 8];
        #pragma unroll
        for (int n = 0; n < 4; ++n) bfr[n] = *(const bf16x8*)&Bsl[wc + n*16 + (lane & 15)][(lane >> 4) * 8];
        #pragma unroll
        for (int m = 0; m < 2; ++m)
            #pragma unroll
            for (int n = 0; n < 4; ++n)
                acc[m][n] = __builtin_amdgcn_mfma_f32_16x16x32_bf16(af[m], bfr[n], acc[m][n], 0, 0, 0);
    }
    #pragma unroll
    for (int m = 0; m < 2; ++m)
        #pragma unroll
        for (int n = 0; n < 4; ++n)
            #pragma unroll
            for (int i = 0; i < 4; ++i)
                C[(size_t)(row0 + wr + m*16 + (lane >> 4)*4 + i) * 512 + col0 + wc + n*16 + (lane & 15)] = acc[m][n][i];
}

// ---------------------------------------------------------------- launcher
extern "C" void kernel_launch(void* const* d_in, const int* in_sizes, int n_in,
                              void* d_out, int out_size, void* d_ws, size_t ws_size,
                              hipStream_t stream)
{
    (void)in_sizes; (void)n_in; (void)out_size;
    const float* s     = (const float*)d_in[0];
    const float* z     = (const float*)d_in[1];
    const float* trans = (const float*)d_in[2];
    const float* rots  = (const float*)d_in[3];
    const float* smask = (const float*)d_in[4];
    const int*   kidx  = (const int*)d_in[5];
    const float* Wq    = (const float*)d_in[6];
    const float* Wk    = (const float*)d_in[7];
    const float* Wv    = (const float*)d_in[8];
    const float* Wqp   = (const float*)d_in[9];
    const float* Wkvp  = (const float*)d_in[10];
    const float* Wb    = (const float*)d_in[11];
    const float* Wdz   = (const float*)d_in[12];
    const float* hw    = (const float*)d_in[13];
    const float* Wout  = (const float*)d_in[14];
    const float* g_s   = (const float*)d_in[15];
    const float* b_s   = (const float*)d_in[16];
    const float* g_z   = (const float*)d_in[17];
    const float* b_z   = (const float*)d_in[18];

    char* ws = (char*)d_ws;
    bf16_t* projb = (bf16_t*)(ws);                      // 25,165,824
    float*  projp = (float*)(ws + 25165824);            // 12,582,912
    float*  biasT = (float*)(ws + 37748736);            // 33,554,432
    bf16_t* wcatT = (bf16_t*)(ws + 71303168);           //  3,932,160
    bf16_t* s_nb  = (bf16_t*)(ws + 75235328);           //  4,194,304
    bf16_t* pzT   = (bf16_t*)(ws + 79429632);           // 33,554,432
    bf16_t* Pbf   = (bf16_t*)(ws + 112984064);          // 16,777,216
    bf16_t* catb  = (bf16_t*)(ws + 129761280);          // 16,777,216
    bf16_t* WoutT = (bf16_t*)(ws + 146538496);          //  2,097,152
    bf16_t* WzT   = (bf16_t*)(ws + 148635648);          //     12,288
    float*  Kv    = (float*)(ws + 148647936);           //        192
    if (ws_size < (size_t)148648128) return;
    float* out = (float*)d_out;

    k_prep<<<1761, 256, 0, stream>>>(Wq, Wk, Wv, Wqp, Wkvp, Wout, Wb, Wdz, g_z, b_z,
                                     s, g_s, b_s, wcatT, WoutT, WzT, Kv, s_nb);
    gemm_proj<<<dim3(30, 32), 256, 0, stream>>>(s_nb, wcatT, projb, projp);
    k_zbias4<<<2048, 256, 0, stream>>>(z, WzT, Kv, biasT, pzT);
    k_attn3<<<2048, 256, 0, stream>>>(projb, projp, biasT, rots, trans, smask, kidx, hw, catb, Pbf);
    k_opair<<<1024, 256, 0, stream>>>(Pbf, pzT, catb);
    gemm_out<<<dim3(4, 64), 256, 0, stream>>>(catb, WoutT, out);
}

// Round 9
// 216.745 us; speedup vs baseline: 5.0879x; 1.0223x over previous
//
#include <hip/hip_runtime.h>
#include <math.h>

#define D_N 4096
#define PBW 3072
#define PPW 768
#define OFFK 1024
#define OFFV 2048
#define CATW 2048

typedef __bf16 bf16_t;
typedef __bf16 bf16x8 __attribute__((ext_vector_type(8)));
typedef __bf16 bf16x4 __attribute__((ext_vector_type(4)));
typedef float f32x4 __attribute__((ext_vector_type(4)));

__device__ __forceinline__ void gld16(const void* g, void* l) {
    __builtin_amdgcn_global_load_lds((const __attribute__((address_space(1))) unsigned int*)g,
                                     (__attribute__((address_space(3))) unsigned int*)l, 16, 0, 0);
}

// ---------------------------------------------------------------- merged prep:
// blocks [0,480): wcatT ; [480,736): WoutT ; 736: WzT+Kv ; [737,1761): ln_s
__global__ __launch_bounds__(256) void k_prep(
    const float* __restrict__ Wq, const float* __restrict__ Wk, const float* __restrict__ Wv,
    const float* __restrict__ Wqp, const float* __restrict__ Wkvp, const float* __restrict__ Wout,
    const float* __restrict__ Wb, const float* __restrict__ Wdz,
    const float* __restrict__ gz, const float* __restrict__ bz,
    const float* __restrict__ s, const float* __restrict__ g_s, const float* __restrict__ b_s,
    bf16_t* __restrict__ wcatT, bf16_t* __restrict__ WoutT,
    bf16_t* __restrict__ WzT, float* __restrict__ Kv, bf16_t* __restrict__ s_nb)
{
    __shared__ float T[64][65];
    const int bx = blockIdx.x;
    const int tid = threadIdx.x;
    if (bx < 736) {
        const float* src; int ld, coff, r0;
        bf16_t* dst; int Rdst;
        if (bx < 480) {
            int c0 = (bx % 60) * 64;
            r0 = (bx / 60) * 64;
            if (c0 < 1024)      { src = Wq;   ld = 1024; coff = c0; }
            else if (c0 < 2048) { src = Wk;   ld = 1024; coff = c0 - 1024; }
            else if (c0 < 3072) { src = Wv;   ld = 1024; coff = c0 - 2048; }
            else if (c0 < 3264) { src = Wqp;  ld = 192;  coff = c0 - 3072; }
            else                { src = Wkvp; ld = 576;  coff = c0 - 3264; }
            dst = wcatT + (size_t)c0 * 512; Rdst = 512;
        } else {
            int b = bx - 480;
            int c0 = (b & 7) * 64;
            r0 = (b >> 3) * 64;
            src = Wout; ld = 512; coff = c0;
            dst = WoutT + (size_t)c0 * 2048; Rdst = 2048;
        }
        {
            int rr = tid >> 2, cb = (tid & 3) * 16;
            const float* p = src + (size_t)(r0 + rr) * ld + coff + cb;
            #pragma unroll
            for (int i = 0; i < 4; ++i)
                *(float4*)&T[rr][cb + i * 4] = *(const float4*)(p + i * 4);
        }
        __syncthreads();
        {
            int cc = tid >> 2, rb = (tid & 3) * 16;
            bf16_t* o = dst + (size_t)cc * Rdst + r0 + rb;
            bf16x8 o0, o1;
            #pragma unroll
            for (int j = 0; j < 8; ++j) o0[j] = (bf16_t)T[rb + j][cc];
            #pragma unroll
            for (int j = 0; j < 8; ++j) o1[j] = (bf16_t)T[rb + 8 + j][cc];
            *(bf16x8*)(o) = o0;
            *(bf16x8*)(o + 8) = o1;
        }
    } else if (bx == 736) {
        for (int i = tid; i < 6144; i += 256) {
            int j = i >> 7, c = i & 127;
            float w = (j < 16) ? Wb[c * 16 + j] : Wdz[c * 32 + (j - 16)];
            WzT[i] = (bf16_t)(gz[c] * w);
        }
        if (tid < 48) {
            int j = tid;
            float acc = 0.f;
            for (int c = 0; c < 128; ++c) {
                float w = (j < 16) ? Wb[c * 16 + j] : Wdz[c * 32 + (j - 16)];
                acc += bz[c] * w;
            }
            Kv[j] = acc;
        }
    } else {
        int row = (bx - 737) * 4 + (tid >> 6);
        int lane = tid & 63;
        const float4* p = (const float4*)(s + (size_t)row * 512);
        float4 v0 = p[lane];
        float4 v1 = p[lane + 64];
        float sum = v0.x + v0.y + v0.z + v0.w + v1.x + v1.y + v1.z + v1.w;
        float sq  = v0.x*v0.x + v0.y*v0.y + v0.z*v0.z + v0.w*v0.w
                  + v1.x*v1.x + v1.y*v1.y + v1.z*v1.z + v1.w*v1.w;
        #pragma unroll
        for (int off = 1; off < 64; off <<= 1) {
            sum += __shfl_xor(sum, off);
            sq  += __shfl_xor(sq, off);
        }
        float m = sum * (1.0f / 512.0f);
        float var = sq * (1.0f / 512.0f) - m * m;
        float rs = rsqrtf(var + 1e-5f);
        int c = lane * 4;
        int c2 = 256 + lane * 4;
        bf16x4 r0, r1;
        r0[0] = (bf16_t)((v0.x - m) * rs * g_s[c+0] + b_s[c+0]);
        r0[1] = (bf16_t)((v0.y - m) * rs * g_s[c+1] + b_s[c+1]);
        r0[2] = (bf16_t)((v0.z - m) * rs * g_s[c+2] + b_s[c+2]);
        r0[3] = (bf16_t)((v0.w - m) * rs * g_s[c+3] + b_s[c+3]);
        r1[0] = (bf16_t)((v1.x - m) * rs * g_s[c2+0] + b_s[c2+0]);
        r1[1] = (bf16_t)((v1.y - m) * rs * g_s[c2+1] + b_s[c2+1]);
        r1[2] = (bf16_t)((v1.z - m) * rs * g_s[c2+2] + b_s[c2+2]);
        r1[3] = (bf16_t)((v1.w - m) * rs * g_s[c2+3] + b_s[c2+3]);
        *(bf16x4*)(s_nb + (size_t)row * 512 + c)  = r0;
        *(bf16x4*)(s_nb + (size_t)row * 512 + c2) = r1;
    }
}

// ---------------------------------------------------------------- proj GEMM, gld16 staging (standalone, round-5/7 proven)
__global__ __launch_bounds__(256) void gemm_proj(const bf16_t* __restrict__ A, const bf16_t* __restrict__ BT,
    bf16_t* __restrict__ projb, float* __restrict__ projp)
{
    __shared__ bf16_t Asl[128][32];
    __shared__ bf16_t Bsl[128][32];
    const int tid = threadIdx.x, lane = tid & 63, w = tid >> 6;
    const int row0 = blockIdx.y * 128, col0 = blockIdx.x * 128;
    const int wr = (w >> 1) * 64, wc = (w & 1) * 64;
    const int K = 512;
    const int sr = lane >> 2, k8 = (lane & 3) * 8;
    const bf16_t* Ab = A + (size_t)(row0 + w * 32 + sr) * K + k8;
    const bf16_t* Bb = BT + (size_t)(col0 + w * 32 + sr) * K + k8;
    f32x4 acc[4][4];
    #pragma unroll
    for (int m = 0; m < 4; ++m)
        #pragma unroll
        for (int n = 0; n < 4; ++n) acc[m][n] = (f32x4){0.f,0.f,0.f,0.f};
    for (int k0 = 0; k0 < K; k0 += 32) {
        __syncthreads();
        gld16(Ab + k0,          &Asl[w * 32][0]);
        gld16(Ab + k0 + 16 * K, &Asl[w * 32 + 16][0]);
        gld16(Bb + k0,          &Bsl[w * 32][0]);
        gld16(Bb + k0 + 16 * K, &Bsl[w * 32 + 16][0]);
        __syncthreads();
        bf16x8 af[4], bfr[4];
        #pragma unroll
        for (int m = 0; m < 4; ++m) af[m]  = *(const bf16x8*)&Asl[wr + m*16 + (lane & 15)][(lane >> 4) * 8];
        #pragma unroll
        for (int n = 0; n < 4; ++n) bfr[n] = *(const bf16x8*)&Bsl[wc + n*16 + (lane & 15)][(lane >> 4) * 8];
        #pragma unroll
        for (int m = 0; m < 4; ++m)
            #pragma unroll
            for (int n = 0; n < 4; ++n)
                acc[m][n] = __builtin_amdgcn_mfma_f32_16x16x32_bf16(af[m], bfr[n], acc[m][n], 0, 0, 0);
    }
    if (col0 < 3072) {
        #pragma unroll
        for (int m = 0; m < 4; ++m)
            #pragma unroll
            for (int n = 0; n < 4; ++n)
                #pragma unroll
                for (int i = 0; i < 4; ++i)
                    projb[(size_t)(row0 + wr + m*16 + (lane >> 4)*4 + i) * PBW + col0 + wc + n*16 + (lane & 15)]
                        = (bf16_t)acc[m][n][i];
    } else {
        #pragma unroll
        for (int m = 0; m < 4; ++m)
            #pragma unroll
            for (int n = 0; n < 4; ++n)
                #pragma unroll
                for (int i = 0; i < 4; ++i)
                    projp[(size_t)(row0 + wr + m*16 + (lane >> 4)*4 + i) * PPW + col0 - 3072 + wc + n*16 + (lane & 15)]
                        = acc[m][n][i];
    }
}

// ---------------------------------------------------------------- z LN + projection, WAR-hardened vmcnt pipeline
// grid 2048 x 256; each wave: 4 contiguous 16-row tiles, per-wave dbuf, no barriers
__global__ __launch_bounds__(256) void k_zbias4(const float* __restrict__ z,
    const bf16_t* __restrict__ WzT, const float* __restrict__ Kv,
    float* __restrict__ biasT, bf16_t* __restrict__ pzT)
{
    __shared__ __align__(16) float zbuf[2][64][128];
    const int tid = threadIdx.x, lane = tid & 63, w = tid >> 6;
    const int r16 = lane & 15, kg = lane >> 4;
    bf16x8 bfz[3][4];
    #pragma unroll
    for (int nt = 0; nt < 3; ++nt)
        #pragma unroll
        for (int kc = 0; kc < 4; ++kc)
            bfz[nt][kc] = *(const bf16x8*)(WzT + (size_t)(nt * 16 + r16) * 128 + kc * 32 + kg * 8);
    float K0 = Kv[r16], K1 = Kv[16 + r16], K2 = Kv[32 + r16];
    asm volatile("s_waitcnt vmcnt(0)" ::: "memory");
    __builtin_amdgcn_sched_barrier(0);

    const int gid = blockIdx.x * 4 + w;
    const char* zb = (const char*)z + (size_t)gid * 64 * 512;
    char* lb0 = (char*)&zbuf[0][w * 16][0];
    char* lb1 = (char*)&zbuf[1][w * 16][0];

#define STAGE(i, lb) { \
    const char* gp_ = zb + (size_t)(i) * 8192 + lane * 16; \
    _Pragma("unroll") \
    for (int c_ = 0; c_ < 8; ++c_) gld16(gp_ + c_ * 1024, (lb) + c_ * 1024); }

#define PROCESS(i, b) { \
    const float* rp = &zbuf[b][w * 16 + r16][kg * 8]; \
    float4 za[4], zc[4]; \
    float sum = 0.f, sq = 0.f; \
    _Pragma("unroll") \
    for (int kc = 0; kc < 4; ++kc) { \
        float4 a_ = *(const float4*)(rp + kc * 32); \
        float4 b_ = *(const float4*)(rp + kc * 32 + 4); \
        za[kc] = a_; zc[kc] = b_; \
        sum += a_.x + a_.y + a_.z + a_.w + b_.x + b_.y + b_.z + b_.w; \
        sq  += a_.x*a_.x + a_.y*a_.y + a_.z*a_.z + a_.w*a_.w + b_.x*b_.x + b_.y*b_.y + b_.z*b_.z + b_.w*b_.w; \
    } \
    sum += __shfl_xor(sum, 16); sq += __shfl_xor(sq, 16); \
    sum += __shfl_xor(sum, 32); sq += __shfl_xor(sq, 32); \
    float m_ = sum * (1.0f / 128.0f); \
    float rs_ = rsqrtf(sq * (1.0f / 128.0f) - m_ * m_ + 1e-5f); \
    bf16x8 af[4]; \
    _Pragma("unroll") \
    for (int kc = 0; kc < 4; ++kc) { \
        af[kc][0] = (bf16_t)((za[kc].x - m_) * rs_); \
        af[kc][1] = (bf16_t)((za[kc].y - m_) * rs_); \
        af[kc][2] = (bf16_t)((za[kc].z - m_) * rs_); \
        af[kc][3] = (bf16_t)((za[kc].w - m_) * rs_); \
        af[kc][4] = (bf16_t)((zc[kc].x - m_) * rs_); \
        af[kc][5] = (bf16_t)((zc[kc].y - m_) * rs_); \
        af[kc][6] = (bf16_t)((zc[kc].z - m_) * rs_); \
        af[kc][7] = (bf16_t)((zc[kc].w - m_) * rs_); \
    } \
    f32x4 acc0 = (f32x4){0.f,0.f,0.f,0.f}; \
    f32x4 acc1 = (f32x4){0.f,0.f,0.f,0.f}; \
    f32x4 acc2 = (f32x4){0.f,0.f,0.f,0.f}; \
    _Pragma("unroll") \
    for (int kc = 0; kc < 4; ++kc) { \
        acc0 = __builtin_amdgcn_mfma_f32_16x16x32_bf16(af[kc], bfz[0][kc], acc0, 0, 0, 0); \
        acc1 = __builtin_amdgcn_mfma_f32_16x16x32_bf16(af[kc], bfz[1][kc], acc1, 0, 0, 0); \
        acc2 = __builtin_amdgcn_mfma_f32_16x16x32_bf16(af[kc], bfz[2][kc], acc2, 0, 0, 0); \
    } \
    const int t_ = gid * 4 + (i); \
    const int rowq_ = t_ >> 3; \
    const int k0_ = ((t_ & 7) << 4) + kg * 4; \
    float4 bw = {acc0[0] + K0, acc0[1] + K0, acc0[2] + K0, acc0[3] + K0}; \
    *(float4*)&biasT[((size_t)rowq_ * 16 + r16) * 128 + k0_] = bw; \
    bf16x4 p1, p2; \
    _Pragma("unroll") \
    for (int i2 = 0; i2 < 4; ++i2) { p1[i2] = (bf16_t)(acc1[i2] + K1); p2[i2] = (bf16_t)(acc2[i2] + K2); } \
    *(bf16x4*)&pzT[((size_t)rowq_ * 32 + r16) * 128 + k0_] = p1; \
    *(bf16x4*)&pzT[((size_t)rowq_ * 32 + 16 + r16) * 128 + k0_] = p2; }

// WAR fence: all prior LDS reads must have returned before the overwriting gld16s issue
#define LDS_DRAIN asm volatile("s_waitcnt lgkmcnt(0)" ::: "memory"); __builtin_amdgcn_sched_barrier(0);

    STAGE(0, lb0);
    STAGE(1, lb1);
    asm volatile("s_waitcnt vmcnt(8)" ::: "memory");
    __builtin_amdgcn_sched_barrier(0);
    PROCESS(0, 0);
    LDS_DRAIN
    STAGE(2, lb0);
    asm volatile("s_waitcnt vmcnt(8)" ::: "memory");
    __builtin_amdgcn_sched_barrier(0);
    PROCESS(1, 1);
    LDS_DRAIN
    STAGE(3, lb1);
    asm volatile("s_waitcnt vmcnt(8)" ::: "memory");
    __builtin_amdgcn_sched_barrier(0);
    PROCESS(2, 0);
    asm volatile("s_waitcnt vmcnt(0)" ::: "memory");
    __builtin_amdgcn_sched_barrier(0);
    PROCESS(3, 1);
#undef STAGE
#undef PROCESS
#undef LDS_DRAIN
}

// ---------------------------------------------------------------- attention: one wg per (nblk, head), XCD-swizzled,
// on-the-fly point rotation; manual LDS pool with region overlays (51.8 KB -> 3 blocks/CU)
__global__ __launch_bounds__(256) void k_attn4(
    const bf16_t* __restrict__ projb, const float* __restrict__ projp,
    const float* __restrict__ biasT, const float* __restrict__ rots,
    const float* __restrict__ trans, const float* __restrict__ smask,
    const int* __restrict__ kidx, const float* __restrict__ hwraw,
    bf16_t* __restrict__ catb, bf16_t* __restrict__ Pbf)
{
    __shared__ __align__(16) char pool[51840];
    // region map (byte offsets):
    //   [0, 26112)      uni: Qs[32][72]+Ks[128][72] (phases A-B) | Vt[96][136] (C-E)
    //   [26112, 43008)  att f32[32][132] (B-D) | Ps bf16[32][136] (D-E) | optmp f32[32][33] at +8704 (E-F)
    //   [43008, 49152)  kp_s f32[128][12] (A-C)
    //   [49152, 50688)  qp_s f32[32][12]  (A-C)
    //   [50688, 51200)  km_s f32[128]
    //   [51200, 51328)  qm_s f32[32]
    //   [51328, 51840)  rows_s int[128]
    bf16_t (*Qs)[72]   = (bf16_t(*)[72])pool;
    bf16_t (*Ks)[72]   = (bf16_t(*)[72])(pool + 32 * 72 * 2);
    bf16_t (*Vt)[136]  = (bf16_t(*)[136])pool;
    float  (*att)[132] = (float(*)[132])(pool + 26112);
    bf16_t (*Ps)[136]  = (bf16_t(*)[136])(pool + 26112);
    float  (*optmp)[33]= (float(*)[33])(pool + 26112 + 8704);
    float  (*kp_s)[12] = (float(*)[12])(pool + 43008);
    float  (*qp_s)[12] = (float(*)[12])(pool + 49152);
    float*  km_s       = (float*)(pool + 50688);
    float*  qm_s       = (float*)(pool + 51200);
    int*    rows_s     = (int*)(pool + 51328);

    const int wgid = blockIdx.x;
    const int swz = (wgid & 7) * 256 + (wgid >> 3);
    const int h = swz >> 7;
    const int nblk = swz & 127;
    const int tid = threadIdx.x;
    const int lane = tid & 63;
    const int w = tid >> 6;
    const int rowq0 = nblk * 32;
    const float hw = log1pf(__expf(hwraw[h])) * 0.13608276348795434f;

    if (tid < 128) {
        int ki = kidx[nblk * 128 + tid];
        int valid = (ki >= 0 && ki < D_N);
        int rr = ki < 0 ? 0 : (ki > D_N - 1 ? D_N - 1 : ki);
        rows_s[tid] = rr;
        km_s[tid] = valid ? smask[rr] : 0.0f;
    } else if (tid < 160) {
        qm_s[tid - 128] = smask[rowq0 + tid - 128];
    }
    __syncthreads();
    // ---- Phase A: stage Q (all), k-points+rot (tid<128), qp-rot + K (tid>=128)
    {
        int q = tid >> 3, cg = (tid & 7) * 8;
        *(bf16x8*)&Qs[q][cg] = *(const bf16x8*)(projb + (size_t)(rowq0 + q) * PBW + h * 64 + cg);
    }
    float Rk[9], tk0 = 0.f, tk1 = 0.f, tk2 = 0.f;
    if (tid < 128) {
        int rr = rows_s[tid];
        const float* Rp = rots + (size_t)rr * 9;
        const float* tp = trans + (size_t)rr * 3;
        #pragma unroll
        for (int e = 0; e < 9; ++e) Rk[e] = Rp[e];
        tk0 = tp[0]; tk1 = tp[1]; tk2 = tp[2];
        const float* kp = projp + (size_t)rr * PPW + 192 + h * 36;
        float4 p0 = *(const float4*)kp;
        float4 p1 = *(const float4*)(kp + 4);
        float4 p2 = *(const float4*)(kp + 8);
        float xs[4] = {p0.x, p0.w, p1.z, p2.y};
        float ys[4] = {p0.y, p1.x, p1.w, p2.z};
        float zs[4] = {p0.z, p1.y, p2.x, p2.w};
        #pragma unroll
        for (int p = 0; p < 4; ++p) {
            kp_s[tid][p*3+0] = Rk[0]*xs[p] + Rk[1]*ys[p] + Rk[2]*zs[p] + tk0;
            kp_s[tid][p*3+1] = Rk[3]*xs[p] + Rk[4]*ys[p] + Rk[5]*zs[p] + tk1;
            kp_s[tid][p*3+2] = Rk[6]*xs[p] + Rk[7]*ys[p] + Rk[8]*zs[p] + tk2;
        }
    } else {
        int j = tid - 128;
        {   // qp rotate: 4 threads per q-row
            int q = j >> 2, p = j & 3;
            const float* Rp = rots + (size_t)(rowq0 + q) * 9;
            const float* tp = trans + (size_t)(rowq0 + q) * 3;
            const float* qp = projp + (size_t)(rowq0 + q) * PPW + h * 12 + p * 3;
            float x = qp[0], y = qp[1], zc = qp[2];
            qp_s[q][p*3+0] = Rp[0]*x + Rp[1]*y + Rp[2]*zc + tp[0];
            qp_s[q][p*3+1] = Rp[3]*x + Rp[4]*y + Rp[5]*zc + tp[1];
            qp_s[q][p*3+2] = Rp[6]*x + Rp[7]*y + Rp[8]*zc + tp[2];
        }
        {   // K staging: one row per thread
            const bf16_t* pK = projb + (size_t)rows_s[j] * PBW + OFFK + h * 64;
            #pragma unroll
            for (int u = 0; u < 8; ++u)
                *(bf16x8*)&Ks[j][u * 8] = *(const bf16x8*)(pK + u * 8);
        }
    }
    __syncthreads();
    // ---- Phase B: QK^T MFMA
    {
        #pragma unroll
        for (int j = 0; j < 4; ++j) {
            int T = w * 4 + j;
            int m = T & 1, n = T >> 1;
            f32x4 acc = (f32x4){0.f,0.f,0.f,0.f};
            #pragma unroll
            for (int kc = 0; kc < 2; ++kc) {
                bf16x8 a = *(const bf16x8*)&Qs[m*16 + (lane & 15)][kc*32 + (lane >> 4) * 8];
                bf16x8 b = *(const bf16x8*)&Ks[n*16 + (lane & 15)][kc*32 + (lane >> 4) * 8];
                acc = __builtin_amdgcn_mfma_f32_16x16x32_bf16(a, b, acc, 0, 0, 0);
            }
            #pragma unroll
            for (int i = 0; i < 4; ++i)
                att[m*16 + (lane >> 4)*4 + i][n*16 + (lane & 15)] = acc[i];
        }
    }
    __syncthreads();
    // ---- Phase C: stage V^T (tid>=128) + v-points rot->Vt (tid<128, reuse Rk/tk) + logit assembly
    if (tid < 128) {
        const float* vp = projp + (size_t)rows_s[tid] * PPW + 192 + h * 36 + 12;
        float4 a0 = *(const float4*)(vp);
        float4 a1 = *(const float4*)(vp + 4);
        float4 a2 = *(const float4*)(vp + 8);
        float4 a3 = *(const float4*)(vp + 12);
        float4 a4 = *(const float4*)(vp + 16);
        float4 a5 = *(const float4*)(vp + 20);
        float xs[8] = {a0.x, a0.w, a1.z, a2.y, a3.x, a3.w, a4.z, a5.y};
        float ys[8] = {a0.y, a1.x, a1.w, a2.z, a3.y, a4.x, a4.w, a5.z};
        float zs[8] = {a0.z, a1.y, a2.x, a2.w, a3.z, a4.y, a5.x, a5.w};
        #pragma unroll
        for (int p = 0; p < 8; ++p) {
            Vt[64 + p*3 + 0][tid] = (bf16_t)(Rk[0]*xs[p] + Rk[1]*ys[p] + Rk[2]*zs[p] + tk0);
            Vt[64 + p*3 + 1][tid] = (bf16_t)(Rk[3]*xs[p] + Rk[4]*ys[p] + Rk[5]*zs[p] + tk1);
            Vt[64 + p*3 + 2][tid] = (bf16_t)(Rk[6]*xs[p] + Rk[7]*ys[p] + Rk[8]*zs[p] + tk2);
        }
        {   // zero-pad rows 88..95
            bf16x8 zz = {};
            *(bf16x8*)&Vt[88 + (tid & 7)][(tid >> 3) * 8] = zz;
        }
    } else {
        int krow = tid - 128;
        const bf16_t* p = projb + (size_t)rows_s[krow] * PBW + OFFV + h * 64;
        #pragma unroll
        for (int u4 = 0; u4 < 8; ++u4) {
            bf16x8 v = *(const bf16x8*)(p + u4 * 8);
            #pragma unroll
            for (int jj = 0; jj < 8; ++jj) Vt[u4 * 8 + jj][krow] = v[jj];
        }
    }
    {   // logits (all threads)
        int q = tid >> 3, kg = tid & 7;
        float qp[12];
        #pragma unroll
        for (int e = 0; e < 12; ++e) qp[e] = qp_s[q][e];
        float qm = qm_s[q];
        const float* bT = biasT + ((size_t)(rowq0 + q) * 16 + h) * 128;
        #pragma unroll
        for (int j2 = 0; j2 < 16; ++j2) {
            int k = kg + j2 * 8;
            float4 k0 = *(const float4*)&kp_s[k][0];
            float4 k1 = *(const float4*)&kp_s[k][4];
            float4 k2 = *(const float4*)&kp_s[k][8];
            float d0 = qp[0]-k0.x, d1 = qp[1]-k0.y, d2_ = qp[2]-k0.z, d3 = qp[3]-k0.w;
            float d4 = qp[4]-k1.x, d5 = qp[5]-k1.y, d6 = qp[6]-k1.z, d7 = qp[7]-k1.w;
            float d8 = qp[8]-k2.x, d9 = qp[9]-k2.y, d10 = qp[10]-k2.z, d11 = qp[11]-k2.w;
            float dd = d0*d0+d1*d1+d2_*d2_+d3*d3+d4*d4+d5*d5+d6*d6+d7*d7+d8*d8+d9*d9+d10*d10+d11*d11;
            float val = att[q][k] * 0.07216878364870323f
                      + 0.5773502691896258f * bT[k]
                      + 100000.0f * (qm * km_s[k] - 1.0f)
                      - 0.5f * hw * dd;
            att[q][k] = val;
        }
    }
    __syncthreads();
    // ---- Phase D: softmax; then (after barrier, att dead) write P into overlaid Ps region + global
    {
        int q = tid >> 3, kg = tid & 7;
        float l[16];
        #pragma unroll
        for (int j2 = 0; j2 < 16; ++j2) l[j2] = att[q][kg + j2 * 8];
        float mx = l[0];
        #pragma unroll
        for (int j2 = 1; j2 < 16; ++j2) mx = fmaxf(mx, l[j2]);
        mx = fmaxf(mx, __shfl_xor(mx, 1));
        mx = fmaxf(mx, __shfl_xor(mx, 2));
        mx = fmaxf(mx, __shfl_xor(mx, 4));
        float se = 0.f;
        #pragma unroll
        for (int j2 = 0; j2 < 16; ++j2) { l[j2] = __expf(l[j2] - mx); se += l[j2]; }
        se += __shfl_xor(se, 1);
        se += __shfl_xor(se, 2);
        se += __shfl_xor(se, 4);
        float inv = 1.0f / se;
        __syncthreads();   // all att reads complete before Ps (same bytes) is written
        bf16_t* pg = Pbf + ((size_t)(rowq0 + q) * 16 + h) * 128;
        #pragma unroll
        for (int j2 = 0; j2 < 16; ++j2) {
            bf16_t pb = (bf16_t)(l[j2] * inv);
            Ps[q][kg + j2 * 8] = pb;
            pg[kg + j2 * 8] = pb;
        }
    }
    __syncthreads();
    // ---- Phase E: PV MFMA
    {
        #pragma unroll
        for (int j = 0; j < 3; ++j) {
            int T = w * 3 + j;
            int m = T & 1, n = T >> 1;
            f32x4 acc = (f32x4){0.f,0.f,0.f,0.f};
            #pragma unroll
            for (int kc = 0; kc < 4; ++kc) {
                bf16x8 a = *(const bf16x8*)&Ps[m*16 + (lane & 15)][kc*32 + (lane >> 4) * 8];
                bf16x8 b = *(const bf16x8*)&Vt[n*16 + (lane & 15)][kc*32 + (lane >> 4) * 8];
                acc = __builtin_amdgcn_mfma_f32_16x16x32_bf16(a, b, acc, 0, 0, 0);
            }
            int rowb = m * 16 + (lane >> 4) * 4;
            int col = lane & 15;
            if (n < 4) {
                #pragma unroll
                for (int i = 0; i < 4; ++i)
                    catb[(size_t)(rowq0 + rowb + i) * CATW + h * 64 + n * 16 + col] = (bf16_t)acc[i];
            } else {
                #pragma unroll
                for (int i = 0; i < 4; ++i)
                    optmp[rowb + i][(n - 4) * 16 + col] = acc[i];
            }
        }
    }
    __syncthreads();
    // ---- Phase F: o_pt inverse transform + norm
    {
        int q = tid >> 3, pp = tid & 7;
        float sx = optmp[q][pp * 3 + 0];
        float sy = optmp[q][pp * 3 + 1];
        float sz = optmp[q][pp * 3 + 2];
        const float* R = rots + (size_t)(rowq0 + q) * 9;
        const float* t = trans + (size_t)(rowq0 + q) * 3;
        float x = sx - t[0], y = sy - t[1], z2 = sz - t[2];
        float ox = R[0] * x + R[3] * y + R[6] * z2;
        float oy = R[1] * x + R[4] * y + R[7] * z2;
        float oz = R[2] * x + R[5] * y + R[8] * z2;
        bf16_t* cp = catb + (size_t)(rowq0 + q) * CATW;
        cp[1024 + h * 24 + pp * 3 + 0] = (bf16_t)ox;
        cp[1024 + h * 24 + pp * 3 + 1] = (bf16_t)oy;
        cp[1024 + h * 24 + pp * 3 + 2] = (bf16_t)oz;
        cp[1408 + h * 8 + pp] = (bf16_t)sqrtf(ox * ox + oy * oy + oz * oz + 1e-8f);
    }
}

// ---------------------------------------------------------------- o_pair: per rowq MFMA [16h x 128k] x [128k x 32c]
__global__ __launch_bounds__(256) void k_opair(const bf16_t* __restrict__ Pbf,
    const bf16_t* __restrict__ pzT, bf16_t* __restrict__ catb)
{
    int tid = threadIdx.x, lane = tid & 63, w = tid >> 6;
    size_t rowq = (size_t)blockIdx.x * 4 + w;
    const bf16_t* Pp = Pbf + rowq * 2048;
    const bf16_t* zp = pzT + rowq * 4096;
    bf16x8 pa[4];
    #pragma unroll
    for (int kc = 0; kc < 4; ++kc)
        pa[kc] = *(const bf16x8*)(Pp + (size_t)(lane & 15) * 128 + kc * 32 + (lane >> 4) * 8);
    #pragma unroll
    for (int ct = 0; ct < 2; ++ct) {
        f32x4 acc = (f32x4){0.f,0.f,0.f,0.f};
        #pragma unroll
        for (int kc = 0; kc < 4; ++kc) {
            bf16x8 b = *(const bf16x8*)(zp + (size_t)(ct * 16 + (lane & 15)) * 128 + kc * 32 + (lane >> 4) * 8);
            acc = __builtin_amdgcn_mfma_f32_16x16x32_bf16(pa[kc], b, acc, 0, 0, 0);
        }
        #pragma unroll
        for (int i = 0; i < 4; ++i) {
            int hh = (lane >> 4) * 4 + i;
            catb[rowq * CATW + 1536 + hh * 32 + ct * 16 + (lane & 15)] = (bf16_t)acc[i];
        }
    }
}

// ---------------------------------------------------------------- out GEMM, 64x128 tile (256 wgs), gld16 staging
__global__ __launch_bounds__(256) void gemm_out(const bf16_t* __restrict__ A, const bf16_t* __restrict__ BT,
    float* __restrict__ C)
{
    __shared__ bf16_t Asl[64][32];
    __shared__ bf16_t Bsl[128][32];
    const int tid = threadIdx.x, lane = tid & 63, w = tid >> 6;
    const int row0 = blockIdx.y * 64, col0 = blockIdx.x * 128;
    const int wr = (w >> 1) * 32, wc = (w & 1) * 64;
    const int K = 2048;
    const int sr = lane >> 2, k8 = (lane & 3) * 8;
    const bf16_t* Ab = A + (size_t)(row0 + w * 16 + sr) * K + k8;
    const bf16_t* Bb = BT + (size_t)(col0 + w * 32 + sr) * K + k8;
    f32x4 acc[2][4];
    #pragma unroll
    for (int m = 0; m < 2; ++m)
        #pragma unroll
        for (int n = 0; n < 4; ++n) acc[m][n] = (f32x4){0.f,0.f,0.f,0.f};
    for (int k0 = 0; k0 < K; k0 += 32) {
        __syncthreads();
        gld16(Ab + k0,          &Asl[w * 16][0]);
        gld16(Bb + k0,          &Bsl[w * 32][0]);
        gld16(Bb + k0 + 16 * K, &Bsl[w * 32 + 16][0]);
        __syncthreads();
        bf16x8 af[2], bfr[4];
        #pragma unroll
        for (int m = 0; m < 2; ++m) af[m]  = *(const bf16x8*)&Asl[wr + m*16 + (lane & 15)][(lane >> 4) * 8];
        #pragma unroll
        for (int n = 0; n < 4; ++n) bfr[n] = *(const bf16x8*)&Bsl[wc + n*16 + (lane & 15)][(lane >> 4) * 8];
        #pragma unroll
        for (int m = 0; m < 2; ++m)
            #pragma unroll
            for (int n = 0; n < 4; ++n)
                acc[m][n] = __builtin_amdgcn_mfma_f32_16x16x32_bf16(af[m], bfr[n], acc[m][n], 0, 0, 0);
    }
    #pragma unroll
    for (int m = 0; m < 2; ++m)
        #pragma unroll
        for (int n = 0; n < 4; ++n)
            #pragma unroll
            for (int i = 0; i < 4; ++i)
                C[(size_t)(row0 + wr + m*16 + (lane >> 4)*4 + i) * 512 + col0 + wc + n*16 + (lane & 15)] = acc[m][n][i];
}

// ---------------------------------------------------------------- launcher
extern "C" void kernel_launch(void* const* d_in, const int* in_sizes, int n_in,
                              void* d_out, int out_size, void* d_ws, size_t ws_size,
                              hipStream_t stream)
{
    (void)in_sizes; (void)n_in; (void)out_size;
    const float* s     = (const float*)d_in[0];
    const float* z     = (const float*)d_in[1];
    const float* trans = (const float*)d_in[2];
    const float* rots  = (const float*)d_in[3];
    const float* smask = (const float*)d_in[4];
    const int*   kidx  = (const int*)d_in[5];
    const float* Wq    = (const float*)d_in[6];
    const float* Wk    = (const float*)d_in[7];
    const float* Wv    = (const float*)d_in[8];
    const float* Wqp   = (const float*)d_in[9];
    const float* Wkvp  = (const float*)d_in[10];
    const float* Wb    = (const float*)d_in[11];
    const float* Wdz   = (const float*)d_in[12];
    const float* hw    = (const float*)d_in[13];
    const float* Wout  = (const float*)d_in[14];
    const float* g_s   = (const float*)d_in[15];
    const float* b_s   = (const float*)d_in[16];
    const float* g_z   = (const float*)d_in[17];
    const float* b_z   = (const float*)d_in[18];

    char* ws = (char*)d_ws;
    bf16_t* projb = (bf16_t*)(ws);                      // 25,165,824
    float*  projp = (float*)(ws + 25165824);            // 12,582,912
    float*  biasT = (float*)(ws + 37748736);            // 33,554,432
    bf16_t* wcatT = (bf16_t*)(ws + 71303168);           //  3,932,160
    bf16_t* s_nb  = (bf16_t*)(ws + 75235328);           //  4,194,304
    bf16_t* pzT   = (bf16_t*)(ws + 79429632);           // 33,554,432
    bf16_t* Pbf   = (bf16_t*)(ws + 112984064);          // 16,777,216
    bf16_t* catb  = (bf16_t*)(ws + 129761280);          // 16,777,216
    bf16_t* WoutT = (bf16_t*)(ws + 146538496);          //  2,097,152
    bf16_t* WzT   = (bf16_t*)(ws + 148635648);          //     12,288
    float*  Kv    = (float*)(ws + 148647936);           //        192
    if (ws_size < (size_t)148648128) return;
    float* out = (float*)d_out;

    k_prep<<<1761, 256, 0, stream>>>(Wq, Wk, Wv, Wqp, Wkvp, Wout, Wb, Wdz, g_z, b_z,
                                     s, g_s, b_s, wcatT, WoutT, WzT, Kv, s_nb);
    gemm_proj<<<dim3(30, 32), 256, 0, stream>>>(s_nb, wcatT, projb, projp);
    k_zbias4<<<2048, 256, 0, stream>>>(z, WzT, Kv, biasT, pzT);
    k_attn4<<<2048, 256, 0, stream>>>(projb, projp, biasT, rots, trans, smask, kidx, hw, catb, Pbf);
    k_opair<<<1024, 256, 0, stream>>>(Pbf, pzT, catb);
    gemm_out<<<dim3(4, 64), 256, 0, stream>>>(catb, WoutT, out);
}